// Round 5
// baseline (89722.504 us; speedup 1.0000x reference)
//
#include <hip/hip_runtime.h>
#include <math.h>

constexpr int NB = 32, NT = 512, NH = 256, NS = 50, NV = 10000;
constexpr int NWG = 128, BLK = 512;

typedef _Float16 h2 __attribute__((ext_vector_type(2)));
typedef _Float16 h8 __attribute__((ext_vector_type(8)));

#define FMA4(acc, Wv, Xv) acc += (Wv).x*(Xv).x + (Wv).y*(Xv).y + (Wv).z*(Xv).z + (Wv).w*(Xv).w

#if __has_builtin(__builtin_amdgcn_fdot2)
__device__ __forceinline__ float dot2f(h2 a, h2 b, float c) { return __builtin_amdgcn_fdot2(a, b, c, false); }
#else
__device__ __forceinline__ float dot2f(h2 a, h2 b, float c) { return c + (float)a[0]*(float)b[0] + (float)a[1]*(float)b[1]; }
#endif
__device__ __forceinline__ float dot8(h8 w, h8 x, float acc) {
  const h2* wp = (const h2*)&w; const h2* xp = (const h2*)&x;
  acc = dot2f(wp[0], xp[0], acc); acc = dot2f(wp[1], xp[1], acc);
  acc = dot2f(wp[2], xp[2], acc); acc = dot2f(wp[3], xp[3], acc);
  return acc;
}
__device__ __forceinline__ float sigm(float x) { return 1.f / (1.f + __expf(-x)); }

// ---------- ws layout ----------
// halves (from (_Float16*)ws)
constexpr size_t H_W0  = 0;        // [1024][768] {Wf | Wih0 | Whh0}, row = g*256+cell
constexpr size_t H_W1  = 786432;   // [1024][512] {Wih1 | Whh1}
constexpr size_t H_SW1 = 1310720;  // [256][512]
constexpr size_t H_VW  = 1441792;  // [256][512] {stack | out}
constexpr size_t H_GW  = 1572864;  // [512]
constexpr size_t H_ZG  = 1573376;  // [32][256]
constexpr size_t H_H0G = 1581568;  // [2][32][256]
constexpr size_t H_H1G = 1597952;  // [2][32][256]
constexpr size_t H_STKH= 1614336;  // [2][32][50][256]
constexpr size_t H_END = 2433536;
// floats (from (float*)ws)
constexpr size_t F_WF   = H_END / 2;        // [1024][256] fp32 scratch (Wf)
constexpr size_t F_BC0  = F_WF + 262144;    // [1024] b_ih0+b_hh0
constexpr size_t F_BID  = F_BC0 + 1024;     // [1024] bc0 + Wih0*st_b2
constexpr size_t F_BC1  = F_BID + 1024;     // [1024]
constexpr size_t F_STK32= F_BC1 + 1024;     // [2][32][50][256]
constexpr size_t F_BAR  = F_STK32 + 819200; // barrier counters (1024 u32)

struct Args4 {
  const int* tokens; const int* scope_idx; const int* is_id; const int* umask; const int* lengths;
  const float* emb; const float* stb1; const float* valb; const float* gateb;
  const float* h0; const float* c0;
  float* ws; float* out;
};

// ---------- prologue: Wf = Wih0 @ SW2  (fp32) ----------
__global__ __launch_bounds__(256) void wf_kernel(const float* __restrict__ wih0,
                                                 const float* __restrict__ stw2, float* ws) {
  __shared__ float srow[256];
  const int i = blockIdx.x, tid = threadIdx.x;
  srow[tid] = wih0[i * 256 + tid];
  __syncthreads();
  float acc = 0.f;
  #pragma unroll 8
  for (int e = 0; e < 256; ++e) acc += srow[e] * stw2[e * 256 + tid];
  ws[F_WF + (size_t)i * 256 + tid] = acc;
}

// ---------- prologue: pack f16 arenas + fused biases ----------
__global__ __launch_bounds__(256) void pack_kernel(
    const float* wih0, const float* whh0, const float* bih0, const float* bhh0,
    const float* wih1, const float* whh1, const float* bih1, const float* bhh1,
    const float* stw1, const float* valw, const float* gatew, const float* stb2,
    float* ws) {
  _Float16* hw = (_Float16*)ws;
  const float* wf32 = ws + F_WF;
  const int gt = blockIdx.x * blockDim.x + threadIdx.x;
  const int np = gridDim.x * blockDim.x;
  for (int i = gt; i < 1024 * 768; i += np) {
    const int r = i / 768, c = i % 768;
    float v = (c < 256) ? wf32[(size_t)r * 256 + c]
            : (c < 512) ? wih0[(size_t)r * 256 + c - 256]
                        : whh0[(size_t)r * 256 + c - 512];
    hw[H_W0 + i] = (_Float16)v;
  }
  for (int i = gt; i < 1024 * 512; i += np) {
    const int r = i >> 9, c = i & 511;
    hw[H_W1 + i] = (_Float16)((c < 256) ? wih1[(size_t)r * 256 + c] : whh1[(size_t)r * 256 + c - 256]);
  }
  for (int i = gt; i < 256 * 512; i += np) hw[H_SW1 + i] = (_Float16)stw1[i];
  for (int i = gt; i < 256 * 512; i += np) hw[H_VW + i] = (_Float16)valw[i];
  for (int i = gt; i < 512; i += np) hw[H_GW + i] = (_Float16)gatew[i];
  for (int i = gt; i < 1024; i += np) {
    const float bc0 = bih0[i] + bhh0[i];
    ws[F_BC0 + i] = bc0;
    ws[F_BC1 + i] = bih1[i] + bhh1[i];
    float d = 0.f;
    for (int e = 0; e < 256; ++e) d += wih0[(size_t)i * 256 + e] * stb2[e];
    ws[F_BID + i] = bc0 + d;
  }
}

// ---------- grid barrier: 2-level tree (16 leaves x 8, root 16) ----------
__device__ __forceinline__ void gbar(unsigned int* bar) {
  __threadfence();
  __syncthreads();
  if (threadIdx.x == 0) {
    unsigned int* leaf = bar + (blockIdx.x & 15) * 32;
    unsigned int* root = bar + 512;
    unsigned int* gen  = bar + 544;
    const unsigned int g = __hip_atomic_load(gen, __ATOMIC_RELAXED, __HIP_MEMORY_SCOPE_AGENT);
    const unsigned int lv = __hip_atomic_fetch_add(leaf, 1u, __ATOMIC_ACQ_REL, __HIP_MEMORY_SCOPE_AGENT);
    bool done = false;
    if (((lv + 1) & 7) == 0) {
      const unsigned int rv = __hip_atomic_fetch_add(root, 1u, __ATOMIC_ACQ_REL, __HIP_MEMORY_SCOPE_AGENT);
      if (((rv + 1) & 15) == 0) {
        __hip_atomic_fetch_add(gen, 1u, __ATOMIC_RELEASE, __HIP_MEMORY_SCOPE_AGENT);
        done = true;
      }
    }
    if (!done) {
      while (__hip_atomic_load(gen, __ATOMIC_ACQUIRE, __HIP_MEMORY_SCOPE_AGENT) == g)
        __builtin_amdgcn_s_sleep(2);
    }
  }
  __syncthreads();
  __threadfence();
}

// ---------- main cooperative scan: 128 WGs x 512 thr, weights LDS-resident ----------
__global__ __launch_bounds__(BLK, 2) void rnn4_kernel(Args4 a) {
  const int wg = blockIdx.x, tid = threadIdx.x;
  const int cg = wg >> 2, bg = wg & 3;        // P2/P3: cells [cg*8,+8), batches [bg*8,+8)
  const int hg = wg >> 4, pg = wg & 15;       // P4: h rows [hg*32,+32), batches {2pg, 2pg+1}
  float* ws = a.ws;
  _Float16* hw = (_Float16*)ws;
  unsigned int* bar = (unsigned int*)(ws + F_BAR);
  _Float16* zg   = hw + H_ZG;
  _Float16* h0g0 = hw + H_H0G, *h0g1 = h0g0 + 8192;
  _Float16* h1g0 = hw + H_H1G, *h1g1 = h1g0 + 8192;
  _Float16* stkh0 = hw + H_STKH, *stkh1 = stkh0 + 409600;
  float* stk0 = ws + F_STK32, *stk1 = stk0 + 409600;

  // LDS (strides padded: 16B-aligned rows, ~4-way worst bank aliasing)
  __shared__ __align__(16) _Float16 s_Wd[32 * 776];   // [Wf|Wih0|Whh0] rows cell*4+g
  __shared__ __align__(16) _Float16 s_We[32 * 520];
  __shared__ __align__(16) _Float16 s_VWs[32 * 264];
  __shared__ __align__(16) _Float16 s_VWo[32 * 264];
  __shared__ __align__(16) _Float16 s_SW1[2 * 520];
  __shared__ __align__(16) _Float16 s_GW[512];
  __shared__ __align__(16) _Float16 s_scr[16640];     // x[32][520] | P4: stkS[50][256]+outs[2][264]
  __shared__ float s_cD[8][8], s_cE[8][8];
  __shared__ float s_bD0[32], s_bDi[32], s_bE[32], s_valb[32], s_stb1[2], s_gb;
  __shared__ float s_vp[64], s_gate[100];
  __shared__ int s_tok[32], s_sx[32], s_isid[32], s_len[32];
  __shared__ char s_act[32];

  // ---- one-time: stage weight slices ----
  for (int cid = tid; cid < 32 * 96; cid += BLK) {   // Wd
    const int rl = cid / 96, c8 = cid % 96;
    const int gr = (rl & 3) * 256 + cg * 8 + (rl >> 2);
    *(h8*)(s_Wd + rl * 776 + c8 * 8) = *(const h8*)(hw + H_W0 + (size_t)gr * 768 + c8 * 8);
  }
  for (int cid = tid; cid < 32 * 64; cid += BLK) {   // We
    const int rl = cid >> 6, c8 = cid & 63;
    const int gr = (rl & 3) * 256 + cg * 8 + (rl >> 2);
    *(h8*)(s_We + rl * 520 + c8 * 8) = *(const h8*)(hw + H_W1 + (size_t)gr * 512 + c8 * 8);
  }
  for (int cid = tid; cid < 32 * 32; cid += BLK) {   // VWs / VWo
    const int rl = cid >> 5, c8 = cid & 31;
    const int gh = hg * 32 + rl;
    *(h8*)(s_VWs + rl * 264 + c8 * 8) = *(const h8*)(hw + H_VW + (size_t)gh * 512 + c8 * 8);
    *(h8*)(s_VWo + rl * 264 + c8 * 8) = *(const h8*)(hw + H_VW + (size_t)gh * 512 + 256 + c8 * 8);
  }
  for (int cid = tid; cid < 2 * 64; cid += BLK) {    // SW1 slice
    const int rl = cid >> 6, c8 = cid & 63;
    *(h8*)(s_SW1 + rl * 520 + c8 * 8) = *(const h8*)(hw + H_SW1 + (size_t)(wg * 2 + rl) * 512 + c8 * 8);
  }
  if (tid < 64) *(h8*)(s_GW + tid * 8) = *(const h8*)(hw + H_GW + tid * 8);
  if (tid < 32) {
    const int gr = (tid & 3) * 256 + cg * 8 + (tid >> 2);
    s_bD0[tid] = ws[F_BC0 + gr]; s_bDi[tid] = ws[F_BID + gr]; s_bE[tid] = ws[F_BC1 + gr];
    s_valb[tid] = a.valb[hg * 32 + tid];
    s_len[tid] = a.lengths[tid];
  }
  if (tid < 2) s_stb1[tid] = a.stb1[wg * 2 + tid];
  if (tid == 0) s_gb = a.gateb[0];
  if (tid < 64) {
    const int cell = tid >> 3, bl = tid & 7;
    s_cD[cell][bl] = a.c0[(size_t)(bg * 8 + bl) * 256 + cg * 8 + cell];
    s_cE[cell][bl] = a.c0[8192 + (size_t)(bg * 8 + bl) * 256 + cg * 8 + cell];
  }
  // global state init
  const int gt = wg * BLK + tid, NTH = NWG * BLK;
  for (int i = gt; i < 8192; i += NTH) {
    const _Float16 v0 = (_Float16)a.h0[i], v1 = (_Float16)a.h0[8192 + i];
    h0g0[i] = v0; h0g1[i] = v0; h1g0[i] = v1; h1g1[i] = v1;
  }
  for (int i = gt; i < 819200; i += NTH) { stk0[i] = 0.f; stk1[i] = 0.f; stkh0[i] = (_Float16)0.f; stkh1[i] = (_Float16)0.f; }
  gbar(bar);

  for (int t = 0; t < NT; ++t) {
    const int par = t & 1;
    const _Float16* stkh_r = par ? stkh1 : stkh0;  _Float16* stkh_w = par ? stkh0 : stkh1;
    const float*    stk_r  = par ? stk1  : stk0;   float*    stk_w  = par ? stk0  : stk1;
    const _Float16* h0_r = par ? h0g1 : h0g0;  _Float16* h0_w = par ? h0g0 : h0g1;
    const _Float16* h1_r = par ? h1g1 : h1g0;  _Float16* h1_w = par ? h1g0 : h1g1;

    // ============ P1: scalars + x staging + z ============
    if (tid < 32) {
      s_tok[tid] = a.tokens[tid * NT + t];
      s_sx[tid]  = a.scope_idx[tid * NT + t];
      s_isid[tid]= a.is_id[tid * NT + t];
      s_act[tid] = (t < s_len[tid]) ? 1 : 0;
    }
    __syncthreads();
    for (int cid = tid; cid < 2048; cid += BLK) {   // x[b] = [stk_row(256) | emb(256)] f16
      const int b = cid >> 6, c = cid & 63;
      if (c < 32) {
        *(h8*)(s_scr + b * 520 + c * 8) = *(const h8*)(stkh_r + ((size_t)(b * 50 + s_sx[b])) * 256 + c * 8);
      } else {
        const float* ep = a.emb + (size_t)s_tok[b] * 256 + (c - 32) * 8;
        const float4 e0 = *(const float4*)ep, e1 = *(const float4*)(ep + 4);
        h8 v; v[0]=(_Float16)e0.x; v[1]=(_Float16)e0.y; v[2]=(_Float16)e0.z; v[3]=(_Float16)e0.w;
        v[4]=(_Float16)e1.x; v[5]=(_Float16)e1.y; v[6]=(_Float16)e1.z; v[7]=(_Float16)e1.w;
        *(h8*)(s_scr + b * 520 + c * 8) = v;
      }
    }
    __syncthreads();
    if (tid < 128) {
      const int d = tid >> 1, b = d >> 1, r = d & 1, p = tid & 1;
      if (s_isid[b] && s_act[b]) {
        const h8* wr = (const h8*)(s_SW1 + r * 520 + p * 256);
        const h8* xv = (const h8*)(s_scr + b * 520 + p * 256);
        float a0=0,a1=0,a2=0,a3=0;
        #pragma unroll
        for (int k = 0; k < 32; k += 4) {
          a0 = dot8(wr[k],xv[k],a0); a1 = dot8(wr[k+1],xv[k+1],a1);
          a2 = dot8(wr[k+2],xv[k+2],a2); a3 = dot8(wr[k+3],xv[k+3],a3);
        }
        float acc = (a0+a1)+(a2+a3);
        acc += __shfl_xor(acc, 1, 64);
        if (p == 0) zg[b * 256 + wg * 2 + r] = (_Float16)fmaxf(acc + s_stb1[r], 0.f);
      }
    }
    gbar(bar);

    // ============ P2: LSTM layer 0 ============
    {
      if (tid < 256) {            // stage z into x[b][0..256) for isid batches
        const int bl = tid >> 5, j = tid & 31, b = bg * 8 + bl;
        if (s_isid[b] && s_act[b])
          *(h8*)(s_scr + b * 520 + j * 8) = *(const h8*)(zg + b * 256 + j * 8);
      } else {                    // stage h0(t-1) into x[hr][0..256)
        const int bl = (tid - 256) >> 5, j = (tid - 256) & 31, b = bg * 8 + bl;
        const int hr = (bg * 8 + 8 + bl) & 31;
        *(h8*)(s_scr + hr * 520 + j * 8) = *(const h8*)(h0_r + b * 256 + j * 8);
      }
      __syncthreads();
      const int o = tid >> 1, part = tid & 1;
      const int bl = o >> 5, cell = (o >> 2) & 7, g = o & 3;
      const int b = bg * 8 + bl, rowL = cell * 4 + g;
      const bool act = s_act[b];
      float tot = 0.f;
      if (act) {
        const h8* wr; const h8* xv;
        if (part == 0) {
          const int cb = s_isid[b] ? 0 : 256;
          wr = (const h8*)(s_Wd + rowL * 776 + cb);
          xv = (const h8*)(s_scr + b * 520 + cb);
        } else {
          wr = (const h8*)(s_Wd + rowL * 776 + 512);
          xv = (const h8*)(s_scr + ((bg * 8 + 8 + bl) & 31) * 520);
        }
        float a0=0,a1=0,a2=0,a3=0;
        #pragma unroll
        for (int k = 0; k < 32; k += 4) {
          a0 = dot8(wr[k],xv[k],a0); a1 = dot8(wr[k+1],xv[k+1],a1);
          a2 = dot8(wr[k+2],xv[k+2],a2); a3 = dot8(wr[k+3],xv[k+3],a3);
        }
        tot = (a0+a1)+(a2+a3);
        if (part == 0) tot += s_isid[b] ? s_bDi[rowL] : s_bD0[rowL];
      }
      tot += __shfl_xor(tot, 1, 64);
      const float x1 = __shfl_xor(tot, 2, 64);
      const float x2 = __shfl_xor(tot, 4, 64);
      const float x3 = __shfl_xor(tot, 6, 64);
      if (g == 0 && part == 0) {
        const int jc = cg * 8 + cell;
        if (act) {
          const float c_ = sigm(x1) * s_cD[cell][bl] + sigm(tot) * tanhf(x2);
          s_cD[cell][bl] = c_;
          h0_w[b * 256 + jc] = (_Float16)(sigm(x3) * tanhf(c_));
        } else {
          h0_w[b * 256 + jc] = h0_r[b * 256 + jc];
        }
      }
    }
    gbar(bar);

    // ============ P3: LSTM layer 1 + feats ============
    {
      if (tid < 256) {            // stage h0(t) new
        const int bl = tid >> 5, j = tid & 31, b = bg * 8 + bl;
        *(h8*)(s_scr + b * 520 + j * 8) = *(const h8*)(h0_w + b * 256 + j * 8);
      } else {                    // stage h1(t-1)
        const int bl = (tid - 256) >> 5, j = (tid - 256) & 31, b = bg * 8 + bl;
        const int hr = (bg * 8 + 8 + bl) & 31;
        *(h8*)(s_scr + hr * 520 + j * 8) = *(const h8*)(h1_r + b * 256 + j * 8);
      }
      __syncthreads();
      const int o = tid >> 1, part = tid & 1;
      const int bl = o >> 5, cell = (o >> 2) & 7, g = o & 3;
      const int b = bg * 8 + bl, rowL = cell * 4 + g;
      const bool act = s_act[b];
      float tot = 0.f;
      if (act) {
        const h8* wr = (const h8*)(s_We + rowL * 520 + part * 256);
        const h8* xv = (part == 0) ? (const h8*)(s_scr + b * 520)
                                   : (const h8*)(s_scr + ((bg * 8 + 8 + bl) & 31) * 520);
        float a0=0,a1=0,a2=0,a3=0;
        #pragma unroll
        for (int k = 0; k < 32; k += 4) {
          a0 = dot8(wr[k],xv[k],a0); a1 = dot8(wr[k+1],xv[k+1],a1);
          a2 = dot8(wr[k+2],xv[k+2],a2); a3 = dot8(wr[k+3],xv[k+3],a3);
        }
        tot = (a0+a1)+(a2+a3);
        if (part == 0) tot += s_bE[rowL];
      }
      tot += __shfl_xor(tot, 1, 64);
      const float x1 = __shfl_xor(tot, 2, 64);
      const float x2 = __shfl_xor(tot, 4, 64);
      const float x3 = __shfl_xor(tot, 6, 64);
      if (g == 0 && part == 0) {
        const int jc = cg * 8 + cell;
        if (act) {
          const float c_ = sigm(x1) * s_cE[cell][bl] + sigm(tot) * tanhf(x2);
          s_cE[cell][bl] = c_;
          const float h_ = sigm(x3) * tanhf(c_);
          h1_w[b * 256 + jc] = (_Float16)h_;
          a.out[((size_t)b * NT + t) * NV + jc] = h_;   // feats
        } else {
          h1_w[b * 256 + jc] = h1_r[b * 256 + jc];
        }
      }
    }
    gbar(bar);

    // ============ P4: gates + vproj + stack GEMM/update ============
    {
      _Float16* s_stkS = s_scr;                 // [50][256]
      _Float16* s_outs = s_scr + 12800;         // [2][264]
      const int b0 = pg * 2;
      if (tid < 64) {
        const int bl = tid >> 5, j = tid & 31;
        *(h8*)(s_outs + bl * 264 + j * 8) = *(const h8*)(h1_w + (b0 + bl) * 256 + j * 8);
      }
      __syncthreads();
      {  // vproj: 64 dots x 8 threads
        const int d = tid >> 3, p = tid & 7, bl = d >> 5, r = d & 31;
        const h8* wr = (const h8*)(s_VWo + r * 264 + p * 32);
        const h8* ov = (const h8*)(s_outs + bl * 264 + p * 32);
        float acc = 0.f;
        #pragma unroll
        for (int k = 0; k < 4; ++k) acc = dot8(wr[k], ov[k], acc);
        acc += __shfl_xor(acc, 1, 64); acc += __shfl_xor(acc, 2, 64); acc += __shfl_xor(acc, 4, 64);
        if (p == 0) s_vp[bl * 32 + r] = acc + s_valb[r];
      }
      if (tid < 400) {  // gates: 100 pairs x 4 threads
        const int q = tid >> 2, p = tid & 3;
        const int bl = (q < 50) ? 0 : 1, s = q - bl * 50, b = b0 + bl;
        float acc = 0.f;
        if (p < 2) {
          const h8* gw = (const h8*)(s_GW + p * 128);
          const h8* sv = (const h8*)(stkh_r + ((size_t)(b * 50 + s)) * 256 + p * 128);
          #pragma unroll
          for (int k = 0; k < 16; ++k) acc = dot8(gw[k], sv[k], acc);
        } else {
          const h8* gw = (const h8*)(s_GW + 256 + (p - 2) * 128);
          const h8* ov = (const h8*)(s_outs + bl * 264 + (p - 2) * 128);
          #pragma unroll
          for (int k = 0; k < 16; ++k) acc = dot8(gw[k], ov[k], acc);
        }
        acc += __shfl_xor(acc, 1, 64); acc += __shfl_xor(acc, 2, 64);
        if (p == 0) {
          const int um = a.umask[((size_t)b * NT + t) * NS + s];
          s_gate[q] = (um > 0) ? -1.f : sigm(acc + s_gb);
        }
      }
      __syncthreads();
      for (int c = 0; c < 2; ++c) {
        const int b = b0 + c;
        const bool act = s_act[b];
        for (int cid = tid; cid < 1600; cid += BLK) {
          const int row = cid >> 5, c8 = cid & 31;
          *(h8*)(s_stkS + row * 256 + c8 * 8) = *(const h8*)(stkh_r + ((size_t)(b * 50 + row)) * 256 + c8 * 8);
        }
        __syncthreads();
        for (int i = tid; i < 1600; i += BLK) {
          const int s = i >> 5, r = i & 31;
          const size_t gi = ((size_t)(b * 50 + s)) * 256 + hg * 32 + r;
          if (act) {
            const h8* wr = (const h8*)(s_VWs + r * 264);
            const h8* sv = (const h8*)(s_stkS + s * 256);
            float a0=0,a1=0,a2=0,a3=0;
            #pragma unroll
            for (int k = 0; k < 32; k += 4) {
              a0 = dot8(wr[k],sv[k],a0); a1 = dot8(wr[k+1],sv[k+1],a1);
              a2 = dot8(wr[k+2],sv[k+2],a2); a3 = dot8(wr[k+3],sv[k+3],a3);
            }
            const float acc = (a0+a1)+(a2+a3);
            const float gv = s_gate[c * 50 + s];
            const float ns = (gv < 0.f) ? 0.f
                           : stk_r[gi] * (1.f - gv) + gv * tanhf(acc + s_vp[c * 32 + r]);
            stk_w[gi] = ns; stkh_w[gi] = (_Float16)ns;
          } else {
            stk_w[gi] = stk_r[gi]; stkh_w[gi] = stkh_r[gi];
          }
        }
        __syncthreads();
      }
    }
    gbar(bar);
  }
}

// ===================== logits epilogue (feats live in out[b][t][0:256]) =====================
constexpr int TBR = 32;
__global__ __launch_bounds__(256) void logits_kernel(
    const float* __restrict__ w1, const float* __restrict__ b1,
    const float* __restrict__ w2, const float* __restrict__ b2,
    const int* __restrict__ lengths, float* __restrict__ out) {
  const int blk = blockIdx.x;
  const int b = blk >> 4;
  const int t0 = (blk & 15) * TBR;
  const int tid = threadIdx.x;
  const int len = lengths[b];
  __shared__ __align__(16) float s_fe[TBR][NH];
  __shared__ __align__(16) float s_hid[TBR][NH];

  for (int r = 0; r < TBR; ++r) {
    const int t = t0 + r;
    s_fe[r][tid] = (t < len) ? out[((size_t)b * NT + t) * NV + tid] : 0.f;
  }
  __syncthreads();
  for (int r = 0; r < TBR; ++r) {
    float acc = b1[tid];
    const float4* fr = (const float4*)s_fe[r];
    const float4* wr = (const float4*)(w1 + (size_t)tid * NH);
    #pragma unroll 8
    for (int k = 0; k < NH / 4; ++k) { float4 wv = wr[k]; float4 fv = fr[k]; FMA4(acc, wv, fv); }
    s_hid[r][tid] = fmaxf(acc, 0.f);
  }
  __syncthreads();
  for (int r = 0; r < TBR; ++r) {
    const int t = t0 + r;
    if (t >= len) {
      float4* orow = (float4*)(out + ((size_t)b * NT + t) * NV);
      const float4 m1 = make_float4(-1.f, -1.f, -1.f, -1.f);
      for (int i = tid; i < NV / 4; i += 256) orow[i] = m1;
    }
  }
  if (t0 >= len) return;
  for (int pass = 0; pass < (NV + 511) / 512; ++pass) {
    const int v0 = pass * 512 + tid * 2;
    if (v0 >= NV) continue;
    float acc0[TBR], acc1[TBR];
    #pragma unroll
    for (int r = 0; r < TBR; ++r) { acc0[r] = 0.f; acc1[r] = 0.f; }
    const float4* wa = (const float4*)(w2 + (size_t)v0 * NH);
    const float4* wb = (const float4*)(w2 + (size_t)(v0 + 1) * NH);
    for (int k = 0; k < NH / 4; ++k) {
      const float4 w0 = wa[k], w1v = wb[k];
      #pragma unroll
      for (int r = 0; r < TBR; ++r) {
        const float4 hx = *(const float4*)&s_hid[r][k * 4];
        acc0[r] += w0.x * hx.x + w0.y * hx.y + w0.z * hx.z + w0.w * hx.w;
        acc1[r] += w1v.x * hx.x + w1v.y * hx.y + w1v.z * hx.z + w1v.w * hx.w;
      }
    }
    const float bb0 = b2[v0], bb1 = b2[v0 + 1];
    for (int r = 0; r < TBR; ++r) {
      const int t = t0 + r;
      if (t < len) {
        float2 st = make_float2(acc0[r] + bb0, acc1[r] + bb1);
        *(float2*)(out + ((size_t)b * NT + t) * NV + v0) = st;
      }
    }
  }
}

extern "C" void kernel_launch(void* const* d_in, const int* in_sizes, int n_in,
                              void* d_out, int out_size, void* d_ws, size_t ws_size,
                              hipStream_t stream) {
  (void)in_sizes; (void)n_in; (void)out_size; (void)ws_size;
  const int* tokens    = (const int*)d_in[0];
  const int* scope_idx = (const int*)d_in[1];
  const int* is_id     = (const int*)d_in[2];
  const int* umask     = (const int*)d_in[3];
  const int* lengths   = (const int*)d_in[4];
  const float* emb   = (const float*)d_in[5];
  const float* wih0  = (const float*)d_in[6];  const float* whh0 = (const float*)d_in[7];
  const float* bih0  = (const float*)d_in[8];  const float* bhh0 = (const float*)d_in[9];
  const float* wih1  = (const float*)d_in[10]; const float* whh1 = (const float*)d_in[11];
  const float* bih1  = (const float*)d_in[12]; const float* bhh1 = (const float*)d_in[13];
  const float* stw1  = (const float*)d_in[14]; const float* stb1 = (const float*)d_in[15];
  const float* stw2  = (const float*)d_in[16]; const float* stb2 = (const float*)d_in[17];
  const float* gatew = (const float*)d_in[18]; const float* gateb = (const float*)d_in[19];
  const float* valw  = (const float*)d_in[20]; const float* valb  = (const float*)d_in[21];
  const float* outw1 = (const float*)d_in[22]; const float* outb1 = (const float*)d_in[23];
  const float* outw2 = (const float*)d_in[24]; const float* outb2 = (const float*)d_in[25];
  const float* h0 = (const float*)d_in[26];
  const float* c0 = (const float*)d_in[27];
  float* ws = (float*)d_ws;
  float* out = (float*)d_out;

  (void)hipMemsetAsync(ws + F_BAR, 0, 4096, stream);
  wf_kernel<<<dim3(1024), dim3(256), 0, stream>>>(wih0, stw2, ws);
  pack_kernel<<<dim3(256), dim3(256), 0, stream>>>(
      wih0, whh0, bih0, bhh0, wih1, whh1, bih1, bhh1, stw1, valw, gatew, stb2, ws);

  Args4 a;
  a.tokens = tokens; a.scope_idx = scope_idx; a.is_id = is_id; a.umask = umask; a.lengths = lengths;
  a.emb = emb; a.stb1 = stb1; a.valb = valb; a.gateb = gateb; a.h0 = h0; a.c0 = c0;
  a.ws = ws; a.out = out;
  void* kargs[] = { (void*)&a };
  hipError_t e = hipLaunchCooperativeKernel((const void*)rnn4_kernel, dim3(NWG), dim3(BLK),
                                            kargs, 0, stream);
  if (e != hipSuccess) {
    rnn4_kernel<<<dim3(NWG), dim3(BLK), 0, stream>>>(a);  // 128 WGs trivially co-resident
  }

  logits_kernel<<<dim3(NB * 16), dim3(256), 0, stream>>>(
      outw1, outb1, outw2, outb2, lengths, out);
}

// Round 6
// 48079.373 us; speedup vs baseline: 1.8661x; 1.8661x over previous
//
#include <hip/hip_runtime.h>
#include <math.h>

// Problem constants
constexpr int NB = 32, NT = 512, NH = 256, NE = 256, NS = 50, NV = 10000;
constexpr int SPAD = 264;   // padded stack row (f16 elems): 132 dwords -> bank stride 4

typedef _Float16 h2 __attribute__((ext_vector_type(2)));
typedef _Float16 h4 __attribute__((ext_vector_type(4)));
typedef _Float16 h8 __attribute__((ext_vector_type(8)));
typedef float f32x4 __attribute__((ext_vector_type(4)));

#define FMA4(acc, Wv, Xv) acc += (Wv).x*(Xv).x + (Wv).y*(Xv).y + (Wv).z*(Xv).z + (Wv).w*(Xv).w

#if __has_builtin(__builtin_amdgcn_fdot2)
__device__ __forceinline__ float dot2f(h2 a, h2 b, float c) { return __builtin_amdgcn_fdot2(a, b, c, false); }
#else
__device__ __forceinline__ float dot2f(h2 a, h2 b, float c) { return c + (float)a[0]*(float)b[0] + (float)a[1]*(float)b[1]; }
#endif
__device__ __forceinline__ float dot8(h8 w, h8 x, float acc) {
  const h2* wp = (const h2*)&w; const h2* xp = (const h2*)&x;
  acc = dot2f(wp[0], xp[0], acc); acc = dot2f(wp[1], xp[1], acc);
  acc = dot2f(wp[2], xp[2], acc); acc = dot2f(wp[3], xp[3], acc);
  return acc;
}
__device__ __forceinline__ float sigm(float x) { return 1.f / (1.f + __expf(-x)); }
__device__ __forceinline__ float tanh_f(float x) { const float e = __expf(2.f * x); return 1.f - 2.f / (e + 1.f); }

// ---- f16 weight arena layout inside d_ws (offsets in halves) ----
constexpr size_t OFF_W0  = 0;        // [1024][512]  (w_ih0 row | w_hh0 row), row = g*256+cell
constexpr size_t OFF_W1  = 524288;   // [1024][512]
constexpr size_t OFF_SW1 = 1048576;  // [256][512]
constexpr size_t OFF_SW2 = 1179648;  // [256][256]
constexpr size_t OFF_VW  = 1245184;  // [256][512]  (cols 0..255 stack part, 256..511 out part)
constexpr size_t OFF_GW  = 1376256;  // [512]
constexpr size_t H_TOTAL = 1376768;
// fp32 region (offsets in floats from ws base)
constexpr size_t F_BC0   = H_TOTAL / 2;      // [1024] combined b_ih0+b_hh0
constexpr size_t F_BC1   = F_BC0 + 1024;     // [1024]

// ===================== weight cast / fuse prologue (unchanged from r4, passed) ============
__global__ __launch_bounds__(256) void prep_kernel(
    const float* wih0, const float* whh0, const float* bih0, const float* bhh0,
    const float* wih1, const float* whh1, const float* bih1, const float* bhh1,
    const float* stw1, const float* stw2, const float* valw, const float* gatew,
    float* ws) {
  _Float16* hw = (_Float16*)ws;
  const int gt = blockIdx.x * blockDim.x + threadIdx.x;
  const int np = gridDim.x * blockDim.x;
  for (int i = gt; i < 1024 * 512; i += np) {
    const int r = i >> 9, c = i & 511;
    hw[OFF_W0 + i] = (_Float16)(c < 256 ? wih0[r * 256 + c] : whh0[r * 256 + c - 256]);
    hw[OFF_W1 + i] = (_Float16)(c < 256 ? wih1[r * 256 + c] : whh1[r * 256 + c - 256]);
  }
  for (int i = gt; i < 256 * 512; i += np) hw[OFF_SW1 + i] = (_Float16)stw1[i];
  for (int i = gt; i < 256 * 256; i += np) hw[OFF_SW2 + i] = (_Float16)stw2[i];
  for (int i = gt; i < 256 * 512; i += np) hw[OFF_VW + i]  = (_Float16)valw[i];
  for (int i = gt; i < 512; i += np)       hw[OFF_GW + i]  = (_Float16)gatew[i];
  for (int i = gt; i < 1024; i += np) {
    ws[F_BC0 + i] = bih0[i] + bhh0[i];
    ws[F_BC1 + i] = bih1[i] + bhh1[i];
  }
}

// ===================== recurrent scan: 1 WG (1024 thr) per batch row =====================
// No grid sync. All state in LDS. F4 stack-GEMM on MFMA. feats -> d_out[b][t][0:256].
__global__ __launch_bounds__(1024) void rnn5_kernel(
    const int* __restrict__ tokens, const int* __restrict__ scope_idx,
    const int* __restrict__ is_id, const int* __restrict__ umask,
    const int* __restrict__ lengths, const float* __restrict__ emb,
    const float* __restrict__ stb1, const float* __restrict__ stb2,
    const float* __restrict__ gateb, const float* __restrict__ valb,
    const float* __restrict__ h0, const float* __restrict__ c0,
    const float* __restrict__ ws, float* __restrict__ out) {
  const int b = blockIdx.x, tid = threadIdx.x;
  const int len = lengths[b];
  const _Float16* hw = (const _Float16*)ws;

  __shared__ __align__(16) _Float16 s_stkh[64][SPAD];  // f16 stack (rows 50..63 zero), 33.8 KB
  __shared__ __align__(16) float    s_stk32[NS][NH];   // fp32 truth, 51.2 KB
  __shared__ __align__(16) float    s_c[2][NH];
  __shared__ __align__(16) _Float16 s_h0[2][NH], s_h1[2][NH];
  __shared__ __align__(16) _Float16 s_embh[NH], s_z[NH], s_xin[NH];
  __shared__ __align__(16) float    s_outf[NH];
  __shared__ __align__(16) float    s_vp[NH];
  __shared__ __align__(16) float    s_bc0[1024], s_bc1[1024];
  __shared__ __align__(16) float    s_vb[NH], s_b1[NH], s_b2[NH];
  __shared__ __align__(16) _Float16 s_gw[512];
  __shared__ float s_gate[NS];
  __shared__ int   s_um[NS];
  __shared__ float s_gb;

  // ---- one-time init (self-contained per launch)
  for (int i = tid; i < 64 * SPAD; i += 1024) ((_Float16*)s_stkh)[i] = (_Float16)0.f;
  for (int i = tid; i < NS * NH; i += 1024) ((float*)s_stk32)[i] = 0.f;
  s_bc0[tid] = ws[F_BC0 + tid];
  s_bc1[tid] = ws[F_BC1 + tid];
  if (tid < NH) {
    s_h0[0][tid] = (_Float16)h0[b * NH + tid];
    s_h1[0][tid] = (_Float16)h0[NB * NH + b * NH + tid];
    s_c[0][tid] = c0[b * NH + tid];
    s_c[1][tid] = c0[NB * NH + b * NH + tid];
    s_vb[tid] = valb[tid]; s_b1[tid] = stb1[tid]; s_b2[tid] = stb2[tid];
  }
  if (tid < 64) ((h8*)s_gw)[tid] = ((const h8*)(hw + OFF_GW))[tid];
  if (tid == 0) s_gb = gateb[0];
  __syncthreads();

  for (int t = 0; t < len; ++t) {
    const int p0 = t & 1, p1 = p0 ^ 1;
    const int tok  = tokens[b * NT + t];     // uniform -> scalar loads
    const int sx   = scope_idx[b * NT + t];
    const int isid = is_id[b * NT + t];

    // ---- A: stage emb (f16) + umask
    if (tid < 64) {
      const float4 e = ((const float4*)(emb + (size_t)tok * NE))[tid];
      h4 v = { (_Float16)e.x, (_Float16)e.y, (_Float16)e.z, (_Float16)e.w };
      ((h4*)s_embh)[tid] = v;
    } else if (tid >= 64 && tid < 64 + NS) {
      s_um[tid - 64] = umask[((size_t)b * NT + t) * NS + (tid - 64)];
    }
    __syncthreads();

    // ---- B: z = relu(SW1 . [stk_row(sx); emb] + b1)   (cell, quarter) k-split
    {
      const int o = tid >> 2, part = tid & 3;
      const _Float16* xb = (part < 2) ? &s_stkh[sx][part * 128]
                                      : (const _Float16*)s_embh + (part - 2) * 128;
      h8 xs[16];
      #pragma unroll
      for (int k = 0; k < 16; ++k) xs[k] = ((const h8*)xb)[k];
      const h8* wr = (const h8*)(hw + OFF_SW1 + (size_t)o * 512 + part * 128);
      float acc = 0.f;
      #pragma unroll
      for (int k = 0; k < 16; ++k) acc = dot8(wr[k], xs[k], acc);
      acc += __shfl_xor(acc, 1, 64); acc += __shfl_xor(acc, 2, 64);
      if (part == 0) s_z[o] = (_Float16)fmaxf(acc + s_b1[o], 0.f);
    }
    __syncthreads();

    // ---- C: xin = isid ? SW2 . z + b2 : emb
    if (isid) {
      const int o = tid >> 2, part = tid & 3;
      h8 xs[8];
      #pragma unroll
      for (int k = 0; k < 8; ++k) xs[k] = ((const h8*)s_z)[part * 8 + k];
      const h8* wr = (const h8*)(hw + OFF_SW2 + (size_t)o * 256 + part * 64);
      float acc = 0.f;
      #pragma unroll
      for (int k = 0; k < 8; ++k) acc = dot8(wr[k], xs[k], acc);
      acc += __shfl_xor(acc, 1, 64); acc += __shfl_xor(acc, 2, 64);
      if (part == 0) s_xin[o] = (_Float16)(acc + s_b2[o]);
    } else if (tid < 32) {
      ((h8*)s_xin)[tid] = ((const h8*)s_embh)[tid];
    }
    __syncthreads();

    // ---- D: LSTM layer 0. thread=(cell jc, quarter part); 4 gate-rows streamed
    {
      const int jc = tid >> 2, part = tid & 3;
      const _Float16* xb = (part < 2) ? (const _Float16*)s_xin + part * 128
                                      : (const _Float16*)s_h0[p0] + (part - 2) * 128;
      h8 xs[16];
      #pragma unroll
      for (int k = 0; k < 16; ++k) xs[k] = ((const h8*)xb)[k];
      const h8* w0p = (const h8*)(hw + OFF_W0 + (size_t)(0 * 256 + jc) * 512 + part * 128);
      const h8* w1p = (const h8*)(hw + OFF_W0 + (size_t)(1 * 256 + jc) * 512 + part * 128);
      const h8* w2p = (const h8*)(hw + OFF_W0 + (size_t)(2 * 256 + jc) * 512 + part * 128);
      const h8* w3p = (const h8*)(hw + OFF_W0 + (size_t)(3 * 256 + jc) * 512 + part * 128);
      float a0 = 0.f, a1 = 0.f, a2 = 0.f, a3 = 0.f;
      #pragma unroll
      for (int k = 0; k < 16; ++k) {
        a0 = dot8(w0p[k], xs[k], a0); a1 = dot8(w1p[k], xs[k], a1);
        a2 = dot8(w2p[k], xs[k], a2); a3 = dot8(w3p[k], xs[k], a3);
      }
      a0 += __shfl_xor(a0, 1, 64); a0 += __shfl_xor(a0, 2, 64);
      a1 += __shfl_xor(a1, 1, 64); a1 += __shfl_xor(a1, 2, 64);
      a2 += __shfl_xor(a2, 1, 64); a2 += __shfl_xor(a2, 2, 64);
      a3 += __shfl_xor(a3, 1, 64); a3 += __shfl_xor(a3, 2, 64);
      if (part == 0) {
        const float iv = a0 + s_bc0[jc],        fv = a1 + s_bc0[256 + jc];
        const float gv = a2 + s_bc0[512 + jc],  ov = a3 + s_bc0[768 + jc];
        const float c_ = sigm(fv) * s_c[0][jc] + sigm(iv) * tanh_f(gv);
        s_c[0][jc] = c_;
        s_h0[p1][jc] = (_Float16)(sigm(ov) * tanh_f(c_));
      }
    }
    __syncthreads();

    // ---- E: LSTM layer 1 (input = new h0, recurrent = old h1) + feats f32
    {
      const int jc = tid >> 2, part = tid & 3;
      const _Float16* xb = (part < 2) ? (const _Float16*)s_h0[p1] + part * 128
                                      : (const _Float16*)s_h1[p0] + (part - 2) * 128;
      h8 xs[16];
      #pragma unroll
      for (int k = 0; k < 16; ++k) xs[k] = ((const h8*)xb)[k];
      const h8* w0p = (const h8*)(hw + OFF_W1 + (size_t)(0 * 256 + jc) * 512 + part * 128);
      const h8* w1p = (const h8*)(hw + OFF_W1 + (size_t)(1 * 256 + jc) * 512 + part * 128);
      const h8* w2p = (const h8*)(hw + OFF_W1 + (size_t)(2 * 256 + jc) * 512 + part * 128);
      const h8* w3p = (const h8*)(hw + OFF_W1 + (size_t)(3 * 256 + jc) * 512 + part * 128);
      float a0 = 0.f, a1 = 0.f, a2 = 0.f, a3 = 0.f;
      #pragma unroll
      for (int k = 0; k < 16; ++k) {
        a0 = dot8(w0p[k], xs[k], a0); a1 = dot8(w1p[k], xs[k], a1);
        a2 = dot8(w2p[k], xs[k], a2); a3 = dot8(w3p[k], xs[k], a3);
      }
      a0 += __shfl_xor(a0, 1, 64); a0 += __shfl_xor(a0, 2, 64);
      a1 += __shfl_xor(a1, 1, 64); a1 += __shfl_xor(a1, 2, 64);
      a2 += __shfl_xor(a2, 1, 64); a2 += __shfl_xor(a2, 2, 64);
      a3 += __shfl_xor(a3, 1, 64); a3 += __shfl_xor(a3, 2, 64);
      if (part == 0) {
        const float iv = a0 + s_bc1[jc],        fv = a1 + s_bc1[256 + jc];
        const float gv = a2 + s_bc1[512 + jc],  ov = a3 + s_bc1[768 + jc];
        const float c_ = sigm(fv) * s_c[1][jc] + sigm(iv) * tanh_f(gv);
        s_c[1][jc] = c_;
        const float h_ = sigm(ov) * tanh_f(c_);
        s_h1[p1][jc] = (_Float16)h_;
        s_outf[jc] = h_;
      }
    }
    __syncthreads();

    // ---- F: vproj (waves 0-7) + feats store (wave 0) + slot gates (waves 8-15)
    if (tid < 512) {
      const int o = tid >> 1, part = tid & 1;
      const h8* wr = (const h8*)(hw + OFF_VW + (size_t)o * 512 + 256 + part * 128);
      const h8* ov = (const h8*)s_h1[p1] + part * 16;
      float acc = 0.f;
      #pragma unroll
      for (int k = 0; k < 16; ++k) acc = dot8(wr[k], ov[k], acc);
      acc += __shfl_xor(acc, 1, 64);
      if (part == 0) s_vp[o] = acc + s_vb[o];
      if (tid < 64) {  // feats -> out[b][t][0:256]
        ((float4*)(out + ((size_t)b * NT + t) * NV))[tid] = ((const float4*)s_outf)[tid];
      }
    } else {
      const int wp = (tid >> 6) - 8, l = tid & 63;
      const h2* gs = (const h2*)s_gw;
      const h2* go = (const h2*)(s_gw + 256);
      const h2* oh = (const h2*)s_h1[p1];
      float po = dot2f(go[2 * l], oh[2 * l], 0.f);
      po = dot2f(go[2 * l + 1], oh[2 * l + 1], po);
      for (int j = 0; j < 7; ++j) {
        const int s = wp + 8 * j;
        if (s < NS) {
          const h2* sr = (const h2*)s_stkh[s];
          float p = dot2f(gs[2 * l], sr[2 * l], po);
          p = dot2f(gs[2 * l + 1], sr[2 * l + 1], p);
          #pragma unroll
          for (int m = 1; m < 64; m <<= 1) p += __shfl_xor(p, m, 64);
          if (l == 0) s_gate[s] = (s_um[s] > 0) ? -1.f : sigm(p + s_gb);
        }
      }
    }
    __syncthreads();

    // ---- F4: stack GEMM on MFMA. wave = st(4 s-tiles of 16) x rq(4 r-quads)
    {
      const int w = tid >> 6, l = tid & 63;
      const int st = w >> 2, rq = w & 3;
      const int s0 = st * 16, lr = l & 15, lk = l >> 4;
      h8 af[8];  // A-frags: stkh[s0+lr][kt*32 + lk*8 ..+8]
      #pragma unroll
      for (int kt = 0; kt < 8; ++kt)
        af[kt] = *(const h8*)&s_stkh[s0 + lr][kt * 32 + lk * 8];
      __syncthreads();  // all A-frags in regs before any wave overwrites stack
      #pragma unroll
      for (int rt4 = 0; rt4 < 4; ++rt4) {
        const int r0 = (rq * 4 + rt4) * 16;
        f32x4 c = {0.f, 0.f, 0.f, 0.f};
        #pragma unroll
        for (int kt = 0; kt < 8; ++kt) {
          const h8 bf = *(const h8*)(hw + OFF_VW + (size_t)(r0 + lr) * 512 + kt * 32 + lk * 8);
          c = __builtin_amdgcn_mfma_f32_16x16x32_f16(af[kt], bf, c, 0, 0, 0);
        }
        const int r = r0 + lr;
        #pragma unroll
        for (int i = 0; i < 4; ++i) {
          const int s = s0 + lk * 4 + i;
          if (s < NS) {
            const float gv = s_gate[s];
            float nsv = 0.f;
            if (gv >= 0.f)
              nsv = s_stk32[s][r] * (1.f - gv) + gv * tanh_f(c[i] + s_vp[r]);
            s_stk32[s][r] = nsv;
            s_stkh[s][r]  = (_Float16)nsv;
          }
        }
      }
    }
    __syncthreads();
  }
}

// ===================== logits epilogue (feats live in out[b][t][0:256]) =====================
constexpr int TBR = 32;
__global__ __launch_bounds__(256) void logits_kernel(
    const float* __restrict__ w1, const float* __restrict__ b1,
    const float* __restrict__ w2, const float* __restrict__ b2,
    const int* __restrict__ lengths, float* __restrict__ out) {
  const int blk = blockIdx.x;
  const int b = blk >> 4;
  const int t0 = (blk & 15) * TBR;
  const int tid = threadIdx.x;
  const int len = lengths[b];
  __shared__ __align__(16) float s_fe[TBR][NH];
  __shared__ __align__(16) float s_hid[TBR][NH];

  for (int r = 0; r < TBR; ++r) {
    const int t = t0 + r;
    s_fe[r][tid] = (t < len) ? out[((size_t)b * NT + t) * NV + tid] : 0.f;
  }
  __syncthreads();
  for (int r = 0; r < TBR; ++r) {
    float acc = b1[tid];
    const float4* fr = (const float4*)s_fe[r];
    const float4* wr = (const float4*)(w1 + (size_t)tid * NH);
    #pragma unroll 8
    for (int k = 0; k < NH / 4; ++k) { float4 wv = wr[k]; float4 fv = fr[k]; FMA4(acc, wv, fv); }
    s_hid[r][tid] = fmaxf(acc, 0.f);
  }
  __syncthreads();
  for (int r = 0; r < TBR; ++r) {
    const int t = t0 + r;
    if (t >= len) {
      float4* orow = (float4*)(out + ((size_t)b * NT + t) * NV);
      const float4 m1 = make_float4(-1.f, -1.f, -1.f, -1.f);
      for (int i = tid; i < NV / 4; i += 256) orow[i] = m1;
    }
  }
  if (t0 >= len) return;
  for (int pass = 0; pass < (NV + 511) / 512; ++pass) {
    const int v0 = pass * 512 + tid * 2;
    if (v0 >= NV) continue;
    float acc0[TBR], acc1[TBR];
    #pragma unroll
    for (int r = 0; r < TBR; ++r) { acc0[r] = 0.f; acc1[r] = 0.f; }
    const float4* wa = (const float4*)(w2 + (size_t)v0 * NH);
    const float4* wb = (const float4*)(w2 + (size_t)(v0 + 1) * NH);
    for (int k = 0; k < NH / 4; ++k) {
      const float4 w0 = wa[k], w1v = wb[k];
      #pragma unroll
      for (int r = 0; r < TBR; ++r) {
        const float4 hx = *(const float4*)&s_hid[r][k * 4];
        acc0[r] += w0.x * hx.x + w0.y * hx.y + w0.z * hx.z + w0.w * hx.w;
        acc1[r] += w1v.x * hx.x + w1v.y * hx.y + w1v.z * hx.z + w1v.w * hx.w;
      }
    }
    const float bb0 = b2[v0], bb1 = b2[v0 + 1];
    for (int r = 0; r < TBR; ++r) {
      const int t = t0 + r;
      if (t < len) {
        float2 st = make_float2(acc0[r] + bb0, acc1[r] + bb1);
        *(float2*)(out + ((size_t)b * NT + t) * NV + v0) = st;
      }
    }
  }
}

extern "C" void kernel_launch(void* const* d_in, const int* in_sizes, int n_in,
                              void* d_out, int out_size, void* d_ws, size_t ws_size,
                              hipStream_t stream) {
  (void)in_sizes; (void)n_in; (void)out_size; (void)ws_size;
  const int* tokens    = (const int*)d_in[0];
  const int* scope_idx = (const int*)d_in[1];
  const int* is_id     = (const int*)d_in[2];
  const int* umask     = (const int*)d_in[3];
  const int* lengths   = (const int*)d_in[4];
  const float* emb   = (const float*)d_in[5];
  const float* wih0  = (const float*)d_in[6];  const float* whh0 = (const float*)d_in[7];
  const float* bih0  = (const float*)d_in[8];  const float* bhh0 = (const float*)d_in[9];
  const float* wih1  = (const float*)d_in[10]; const float* whh1 = (const float*)d_in[11];
  const float* bih1  = (const float*)d_in[12]; const float* bhh1 = (const float*)d_in[13];
  const float* stw1  = (const float*)d_in[14]; const float* stb1 = (const float*)d_in[15];
  const float* stw2  = (const float*)d_in[16]; const float* stb2 = (const float*)d_in[17];
  const float* gatew = (const float*)d_in[18]; const float* gateb = (const float*)d_in[19];
  const float* valw  = (const float*)d_in[20]; const float* valb  = (const float*)d_in[21];
  const float* outw1 = (const float*)d_in[22]; const float* outb1 = (const float*)d_in[23];
  const float* outw2 = (const float*)d_in[24]; const float* outb2 = (const float*)d_in[25];
  const float* h0 = (const float*)d_in[26];
  const float* c0 = (const float*)d_in[27];
  float* ws = (float*)d_ws;
  float* out = (float*)d_out;

  prep_kernel<<<dim3(256), dim3(256), 0, stream>>>(
      wih0, whh0, bih0, bhh0, wih1, whh1, bih1, bhh1, stw1, stw2, valw, gatew, ws);

  rnn5_kernel<<<dim3(NB), dim3(1024), 0, stream>>>(
      tokens, scope_idx, is_id, umask, lengths, emb,
      stb1, stb2, gateb, valb, h0, c0, ws, out);

  logits_kernel<<<dim3(NB * 16), dim3(256), 0, stream>>>(
      outw1, outb1, outw2, outb2, lengths, out);
}

// Round 7
// 47125.101 us; speedup vs baseline: 1.9039x; 1.0202x over previous
//
#include <hip/hip_runtime.h>
#include <math.h>

// Problem constants
constexpr int NB = 32, NT = 512, NH = 256, NE = 256, NS = 50, NV = 10000;
constexpr int SPAD = 264;   // padded stack row (f16 elems)

typedef _Float16 h2 __attribute__((ext_vector_type(2)));
typedef _Float16 h4 __attribute__((ext_vector_type(4)));
typedef _Float16 h8 __attribute__((ext_vector_type(8)));
typedef float f32x4 __attribute__((ext_vector_type(4)));

#define FMA4(acc, Wv, Xv) acc += (Wv).x*(Xv).x + (Wv).y*(Xv).y + (Wv).z*(Xv).z + (Wv).w*(Xv).w

#if __has_builtin(__builtin_amdgcn_fdot2)
__device__ __forceinline__ float dot2f(h2 a, h2 b, float c) { return __builtin_amdgcn_fdot2(a, b, c, false); }
#else
__device__ __forceinline__ float dot2f(h2 a, h2 b, float c) { return c + (float)a[0]*(float)b[0] + (float)a[1]*(float)b[1]; }
#endif
__device__ __forceinline__ float sigm(float x) { return 1.f / (1.f + __expf(-x)); }
__device__ __forceinline__ float tanh_f(float x) { const float e = __expf(2.f * x); return 1.f - 2.f / (e + 1.f); }

// ---- packed (MFMA-fragment-order) f16 arenas in d_ws; offsets in halves ----
// frag layout: dst[((mt*KT + kt)*64 + lane)*8 + j] = src[mt*16 + (lane&15)][kt*32 + (lane>>4)*8 + j]
constexpr size_t P_W0  = 0;         // M=1024 K=512 rows=[wih0|whh0], row=g*256+cell
constexpr size_t P_W1  = 524288;    // M=1024 K=512
constexpr size_t P_SW1 = 1048576;   // M=256  K=512
constexpr size_t P_SW2 = 1179648;   // M=256  K=256
constexpr size_t P_VWO = 1245184;   // M=256  K=256  val_w cols 256..511 (out part)
constexpr size_t P_VWS = 1310720;   // M=256  K=256  val_w cols 0..255  (stack part)
constexpr size_t P_GW  = 1376256;   // [512] linear
constexpr size_t H_TOTAL = 1376768;
constexpr size_t F_BC0 = H_TOTAL / 2;   // [1024] b_ih0+b_hh0 (fp32)
constexpr size_t F_BC1 = F_BC0 + 1024;  // [1024]

// ===================== prologue: fragment-pack weights =====================
__global__ __launch_bounds__(256) void prep_kernel(
    const float* wih0, const float* whh0, const float* bih0, const float* bhh0,
    const float* wih1, const float* whh1, const float* bih1, const float* bhh1,
    const float* stw1, const float* stw2, const float* valw, const float* gatew,
    float* ws) {
  _Float16* hw = (_Float16*)ws;
  const int gt = blockIdx.x * blockDim.x + threadIdx.x;
  const int np = gridDim.x * blockDim.x;

  auto pack = [&](size_t off, int M, int K, auto src) {
    const int KT = K / 32;
    for (int i = gt; i < M * K; i += np) {
      const int j = i & 7, l = (i >> 3) & 63, rem = i >> 9;
      const int kt = rem % KT, mt = rem / KT;
      const int row = mt * 16 + (l & 15), col = kt * 32 + (l >> 4) * 8 + j;
      hw[off + i] = (_Float16)src(row, col);
    }
  };
  pack(P_W0, 1024, 512, [&](int r, int c) { return c < 256 ? wih0[(size_t)r * 256 + c] : whh0[(size_t)r * 256 + c - 256]; });
  pack(P_W1, 1024, 512, [&](int r, int c) { return c < 256 ? wih1[(size_t)r * 256 + c] : whh1[(size_t)r * 256 + c - 256]; });
  pack(P_SW1, 256, 512, [&](int r, int c) { return stw1[(size_t)r * 512 + c]; });
  pack(P_SW2, 256, 256, [&](int r, int c) { return stw2[(size_t)r * 256 + c]; });
  pack(P_VWO, 256, 256, [&](int r, int c) { return valw[(size_t)r * 512 + 256 + c]; });
  pack(P_VWS, 256, 256, [&](int r, int c) { return valw[(size_t)r * 512 + c]; });
  for (int i = gt; i < 512; i += np) hw[P_GW + i] = (_Float16)gatew[i];
  for (int i = gt; i < 1024; i += np) {
    ws[F_BC0 + i] = bih0[i] + bhh0[i];
    ws[F_BC1 + i] = bih1[i] + bhh1[i];
  }
}

// GEMV via MFMA: result rows = weight rows; x broadcast as all 16 B-columns.
// xA = first 256 k, xB = next 256 k (nullptr if K==256).
template <int KT, int NMT>
__device__ __forceinline__ void gemv_mfma(const _Float16* __restrict__ wp, int mt0,
                                          const _Float16* __restrict__ xA,
                                          const _Float16* __restrict__ xB,
                                          float* __restrict__ pre, int l) {
  const int lr = l & 15, lk = l >> 4;
  #pragma unroll
  for (int m = 0; m < NMT; ++m) {
    const int mt = mt0 + m;
    f32x4 c = {0.f, 0.f, 0.f, 0.f};
    #pragma unroll
    for (int kt = 0; kt < KT; ++kt) {
      const h8 a = *(const h8*)(wp + ((size_t)(mt * KT + kt) * 64 + l) * 8);
      const _Float16* xb = (kt < 8) ? (xA + kt * 32) : (xB + (kt - 8) * 32);
      const h8 x = *(const h8*)(xb + lk * 8);
      c = __builtin_amdgcn_mfma_f32_16x16x32_f16(a, x, c, 0, 0, 0);
    }
    if (lr == 0) *((f32x4*)&pre[mt * 16 + lk * 4]) = c;
  }
}

// ===================== recurrent scan: 1 WG (1024 thr = 16 waves) per batch row ==========
__global__ __launch_bounds__(1024) void rnn6_kernel(
    const int* __restrict__ tokens, const int* __restrict__ scope_idx,
    const int* __restrict__ is_id, const int* __restrict__ umask,
    const int* __restrict__ lengths, const float* __restrict__ emb,
    const float* __restrict__ stb1, const float* __restrict__ stb2,
    const float* __restrict__ gateb, const float* __restrict__ valb,
    const float* __restrict__ h0, const float* __restrict__ c0,
    const float* __restrict__ ws, float* __restrict__ out) {
  const int b = blockIdx.x, tid = threadIdx.x;
  const int len = lengths[b];
  const _Float16* hw = (const _Float16*)ws;
  const int w = tid >> 6, l = tid & 63;

  __shared__ __align__(16) _Float16 s_stkh[64][SPAD];  // f16 stack (rows 50..63 zero)
  __shared__ __align__(16) float    s_stk32[NS][NH];   // fp32 truth
  __shared__ __align__(16) float    s_pre[1024];
  __shared__ __align__(16) float    s_c[2][NH];
  __shared__ __align__(16) _Float16 s_h0h[2][NH], s_h1h[2][NH];
  __shared__ __align__(16) _Float16 s_embh[NH], s_z[NH], s_xin[NH];
  __shared__ __align__(16) float    s_vp[NH], s_vb[NH], s_b1[NH], s_b2[NH];
  __shared__ __align__(16) float    s_bc0[1024], s_bc1[1024];
  __shared__ __align__(16) _Float16 s_gw[512];
  __shared__ float s_gate[NS];
  __shared__ int   s_um[NS];
  __shared__ float s_gb;

  // ---- one-time init
  for (int i = tid; i < 64 * SPAD; i += 1024) ((_Float16*)s_stkh)[i] = (_Float16)0.f;
  for (int i = tid; i < NS * NH; i += 1024) ((float*)s_stk32)[i] = 0.f;
  s_bc0[tid] = ws[F_BC0 + tid];
  s_bc1[tid] = ws[F_BC1 + tid];
  if (tid < NH) {
    s_h0h[0][tid] = (_Float16)h0[b * NH + tid];
    s_h1h[0][tid] = (_Float16)h0[NB * NH + b * NH + tid];
    s_c[0][tid] = c0[b * NH + tid];
    s_c[1][tid] = c0[NB * NH + b * NH + tid];
    s_vb[tid] = valb[tid]; s_b1[tid] = stb1[tid]; s_b2[tid] = stb2[tid];
  }
  if (tid < 64) ((h8*)s_gw)[tid] = ((const h8*)(hw + P_GW))[tid];
  if (tid == 0) s_gb = gateb[0];
  __syncthreads();

  for (int t = 0; t < len; ++t) {
    const int p0 = t & 1, p1 = p0 ^ 1;
    const int tok  = tokens[b * NT + t];
    const int sx   = scope_idx[b * NT + t];
    const int isid = is_id[b * NT + t];

    // ---- A: emb -> LDS f16 (coalesced), umask
    if (tid < 64) {
      const float4 e = ((const float4*)(emb + (size_t)tok * NE))[tid];
      h4 v = { (_Float16)e.x, (_Float16)e.y, (_Float16)e.z, (_Float16)e.w };
      ((h4*)s_embh)[tid] = v;
    } else if (tid >= 64 && tid < 64 + NS) {
      s_um[tid - 64] = umask[((size_t)b * NT + t) * NS + (tid - 64)];
    }
    __syncthreads();

    if (isid) {
      // ---- B: z_pre = SW1 . [stk_row(sx); emb]   (16 waves x 1 tile)
      gemv_mfma<16, 1>(hw + P_SW1, w, &s_stkh[sx][0], s_embh, s_pre, l);
      __syncthreads();
      if (tid < 256) s_z[tid] = (_Float16)fmaxf(s_pre[tid] + s_b1[tid], 0.f);
      __syncthreads();
      // ---- C: xin = SW2 . z + b2
      gemv_mfma<8, 1>(hw + P_SW2, w, s_z, nullptr, s_pre, l);
      __syncthreads();
      if (tid < 256) s_xin[tid] = (_Float16)(s_pre[tid] + s_b2[tid]);
      __syncthreads();
    } else {
      if (tid < 32) ((h8*)s_xin)[tid] = ((const h8*)s_embh)[tid];
      __syncthreads();
    }

    // ---- D: LSTM0 pre-acts = W0 . [xin; h0(p0)]   (16 waves x 4 tiles)
    gemv_mfma<16, 4>(hw + P_W0, w * 4, s_xin, s_h0h[p0], s_pre, l);
    __syncthreads();
    if (tid < 256) {
      const int jc = tid;
      const float iv = s_pre[jc] + s_bc0[jc],        fv = s_pre[256 + jc] + s_bc0[256 + jc];
      const float gv = s_pre[512 + jc] + s_bc0[512 + jc], ov = s_pre[768 + jc] + s_bc0[768 + jc];
      const float c_ = sigm(fv) * s_c[0][jc] + sigm(iv) * tanh_f(gv);
      s_c[0][jc] = c_;
      s_h0h[p1][jc] = (_Float16)(sigm(ov) * tanh_f(c_));
    }
    __syncthreads();

    // ---- E: LSTM1 pre-acts = W1 . [h0(p1); h1(p0)]
    gemv_mfma<16, 4>(hw + P_W1, w * 4, s_h0h[p1], s_h1h[p0], s_pre, l);
    __syncthreads();
    if (tid < 256) {
      const int jc = tid;
      const float iv = s_pre[jc] + s_bc1[jc],        fv = s_pre[256 + jc] + s_bc1[256 + jc];
      const float gv = s_pre[512 + jc] + s_bc1[512 + jc], ov = s_pre[768 + jc] + s_bc1[768 + jc];
      const float c_ = sigm(fv) * s_c[1][jc] + sigm(iv) * tanh_f(gv);
      s_c[1][jc] = c_;
      const float h_ = sigm(ov) * tanh_f(c_);
      s_h1h[p1][jc] = (_Float16)h_;
      out[((size_t)b * NT + t) * NV + jc] = h_;   // feats (coalesced across 4 waves)
    }
    __syncthreads();

    // ---- F: vproj (waves 0-7) + slot gates (waves 8-15)
    if (w < 8) {
      const int lr = l & 15, lk = l >> 4;
      #pragma unroll
      for (int m = 0; m < 2; ++m) {
        const int mt = w * 2 + m;
        f32x4 c = {0.f, 0.f, 0.f, 0.f};
        #pragma unroll
        for (int kt = 0; kt < 8; ++kt) {
          const h8 a = *(const h8*)(hw + P_VWO + ((size_t)(mt * 8 + kt) * 64 + l) * 8);
          const h8 x = *(const h8*)(&s_h1h[p1][kt * 32 + lk * 8]);
          c = __builtin_amdgcn_mfma_f32_16x16x32_f16(a, x, c, 0, 0, 0);
        }
        if (lr == 0) {
          const f32x4 vb4 = *((const f32x4*)&s_vb[mt * 16 + lk * 4]);
          c += vb4;
          *((f32x4*)&s_vp[mt * 16 + lk * 4]) = c;
        }
      }
    } else {
      const int wp = w - 8;
      const h2* gs = (const h2*)s_gw;
      const h2* go = (const h2*)(s_gw + 256);
      const h2* oh = (const h2*)s_h1h[p1];
      float po = dot2f(go[2 * l], oh[2 * l], 0.f);
      po = dot2f(go[2 * l + 1], oh[2 * l + 1], po);
      for (int j = 0; j < 7; ++j) {
        const int s = wp + 8 * j;
        if (s < NS) {
          const h2* sr = (const h2*)s_stkh[s];
          float p = dot2f(gs[2 * l], sr[2 * l], po);
          p = dot2f(gs[2 * l + 1], sr[2 * l + 1], p);
          #pragma unroll
          for (int m = 1; m < 64; m <<= 1) p += __shfl_xor(p, m, 64);
          if (l == 0) s_gate[s] = (s_um[s] > 0) ? -1.f : sigm(p + s_gb);
        }
      }
    }
    __syncthreads();

    // ---- F4: stack GEMM on MFMA (A = stack LDS frags, B = packed VWS coalesced)
    {
      const int st = w >> 2, rq = w & 3;
      const int s0 = st * 16, lr = l & 15, lk = l >> 4;
      h8 af[8];
      #pragma unroll
      for (int kt = 0; kt < 8; ++kt)
        af[kt] = *(const h8*)&s_stkh[s0 + lr][kt * 32 + lk * 8];
      __syncthreads();  // all A-frags in regs before any wave overwrites stack
      #pragma unroll
      for (int rt4 = 0; rt4 < 4; ++rt4) {
        const int rt = rq * 4 + rt4;
        f32x4 c = {0.f, 0.f, 0.f, 0.f};
        #pragma unroll
        for (int kt = 0; kt < 8; ++kt) {
          const h8 bf = *(const h8*)(hw + P_VWS + ((size_t)(rt * 8 + kt) * 64 + l) * 8);
          c = __builtin_amdgcn_mfma_f32_16x16x32_f16(af[kt], bf, c, 0, 0, 0);
        }
        const int r = rt * 16 + lr;
        #pragma unroll
        for (int i = 0; i < 4; ++i) {
          const int s = s0 + lk * 4 + i;
          if (s < NS) {
            const float gv = s_gate[s];
            float nsv = 0.f;
            if (gv >= 0.f)
              nsv = s_stk32[s][r] * (1.f - gv) + gv * tanh_f(c[i] + s_vp[r]);
            s_stk32[s][r] = nsv;
            s_stkh[s][r]  = (_Float16)nsv;
          }
        }
      }
    }
    __syncthreads();
  }
}

// ===================== logits epilogue (feats live in out[b][t][0:256]) =====================
constexpr int TBR = 32;
__global__ __launch_bounds__(256) void logits_kernel(
    const float* __restrict__ w1, const float* __restrict__ b1,
    const float* __restrict__ w2, const float* __restrict__ b2,
    const int* __restrict__ lengths, float* __restrict__ out) {
  const int blk = blockIdx.x;
  const int b = blk >> 4;
  const int t0 = (blk & 15) * TBR;
  const int tid = threadIdx.x;
  const int len = lengths[b];
  __shared__ __align__(16) float s_fe[TBR][NH];
  __shared__ __align__(16) float s_hid[TBR][NH];

  for (int r = 0; r < TBR; ++r) {
    const int t = t0 + r;
    s_fe[r][tid] = (t < len) ? out[((size_t)b * NT + t) * NV + tid] : 0.f;
  }
  __syncthreads();
  for (int r = 0; r < TBR; ++r) {
    float acc = b1[tid];
    const float4* fr = (const float4*)s_fe[r];
    const float4* wr = (const float4*)(w1 + (size_t)tid * NH);
    #pragma unroll 8
    for (int k = 0; k < NH / 4; ++k) { float4 wv = wr[k]; float4 fv = fr[k]; FMA4(acc, wv, fv); }
    s_hid[r][tid] = fmaxf(acc, 0.f);
  }
  __syncthreads();
  for (int r = 0; r < TBR; ++r) {
    const int t = t0 + r;
    if (t >= len) {
      float4* orow = (float4*)(out + ((size_t)b * NT + t) * NV);
      const float4 m1 = make_float4(-1.f, -1.f, -1.f, -1.f);
      for (int i = tid; i < NV / 4; i += 256) orow[i] = m1;
    }
  }
  if (t0 >= len) return;
  for (int pass = 0; pass < (NV + 511) / 512; ++pass) {
    const int v0 = pass * 512 + tid * 2;
    if (v0 >= NV) continue;
    float acc0[TBR], acc1[TBR];
    #pragma unroll
    for (int r = 0; r < TBR; ++r) { acc0[r] = 0.f; acc1[r] = 0.f; }
    const float4* wa = (const float4*)(w2 + (size_t)v0 * NH);
    const float4* wb = (const float4*)(w2 + (size_t)(v0 + 1) * NH);
    for (int k = 0; k < NH / 4; ++k) {
      const float4 w0 = wa[k], w1v = wb[k];
      #pragma unroll
      for (int r = 0; r < TBR; ++r) {
        const float4 hx = *(const float4*)&s_hid[r][k * 4];
        acc0[r] += w0.x * hx.x + w0.y * hx.y + w0.z * hx.z + w0.w * hx.w;
        acc1[r] += w1v.x * hx.x + w1v.y * hx.y + w1v.z * hx.z + w1v.w * hx.w;
      }
    }
    const float bb0 = b2[v0], bb1 = b2[v0 + 1];
    for (int r = 0; r < TBR; ++r) {
      const int t = t0 + r;
      if (t < len) {
        float2 st = make_float2(acc0[r] + bb0, acc1[r] + bb1);
        *(float2*)(out + ((size_t)b * NT + t) * NV + v0) = st;
      }
    }
  }
}

extern "C" void kernel_launch(void* const* d_in, const int* in_sizes, int n_in,
                              void* d_out, int out_size, void* d_ws, size_t ws_size,
                              hipStream_t stream) {
  (void)in_sizes; (void)n_in; (void)out_size; (void)ws_size;
  const int* tokens    = (const int*)d_in[0];
  const int* scope_idx = (const int*)d_in[1];
  const int* is_id     = (const int*)d_in[2];
  const int* umask     = (const int*)d_in[3];
  const int* lengths   = (const int*)d_in[4];
  const float* emb   = (const float*)d_in[5];
  const float* wih0  = (const float*)d_in[6];  const float* whh0 = (const float*)d_in[7];
  const float* bih0  = (const float*)d_in[8];  const float* bhh0 = (const float*)d_in[9];
  const float* wih1  = (const float*)d_in[10]; const float* whh1 = (const float*)d_in[11];
  const float* bih1  = (const float*)d_in[12]; const float* bhh1 = (const float*)d_in[13];
  const float* stw1  = (const float*)d_in[14]; const float* stb1 = (const float*)d_in[15];
  const float* stw2  = (const float*)d_in[16]; const float* stb2 = (const float*)d_in[17];
  const float* gatew = (const float*)d_in[18]; const float* gateb = (const float*)d_in[19];
  const float* valw  = (const float*)d_in[20]; const float* valb  = (const float*)d_in[21];
  const float* outw1 = (const float*)d_in[22]; const float* outb1 = (const float*)d_in[23];
  const float* outw2 = (const float*)d_in[24]; const float* outb2 = (const float*)d_in[25];
  const float* h0 = (const float*)d_in[26];
  const float* c0 = (const float*)d_in[27];
  float* ws = (float*)d_ws;
  float* out = (float*)d_out;

  prep_kernel<<<dim3(256), dim3(256), 0, stream>>>(
      wih0, whh0, bih0, bhh0, wih1, whh1, bih1, bhh1, stw1, stw2, valw, gatew, ws);

  rnn6_kernel<<<dim3(NB), dim3(1024), 0, stream>>>(
      tokens, scope_idx, is_id, umask, lengths, emb,
      stb1, stb2, gateb, valb, h0, c0, ws, out);

  logits_kernel<<<dim3(NB * 16), dim3(256), 0, stream>>>(
      outw1, outb1, outw2, outb2, lengths, out);
}

// Round 8
// 42506.891 us; speedup vs baseline: 2.1108x; 1.1086x over previous
//
#include <hip/hip_runtime.h>
#include <math.h>

// Problem constants
constexpr int NB = 32, NT = 512, NH = 256, NE = 256, NS = 50, NV = 10000;
constexpr int SPAD = 264;   // padded stack row (f16 elems)

typedef _Float16 h2 __attribute__((ext_vector_type(2)));
typedef _Float16 h4 __attribute__((ext_vector_type(4)));
typedef _Float16 h8 __attribute__((ext_vector_type(8)));
typedef float f32x4 __attribute__((ext_vector_type(4)));

#define FMA4(acc, Wv, Xv) acc += (Wv).x*(Xv).x + (Wv).y*(Xv).y + (Wv).z*(Xv).z + (Wv).w*(Xv).w

#if __has_builtin(__builtin_amdgcn_fdot2)
__device__ __forceinline__ float dot2f(h2 a, h2 b, float c) { return __builtin_amdgcn_fdot2(a, b, c, false); }
#else
__device__ __forceinline__ float dot2f(h2 a, h2 b, float c) { return c + (float)a[0]*(float)b[0] + (float)a[1]*(float)b[1]; }
#endif
__device__ __forceinline__ float sigm(float x) { return 1.f / (1.f + __expf(-x)); }
__device__ __forceinline__ float tanh_f(float x) { const float e = __expf(2.f * x); return 1.f - 2.f / (e + 1.f); }

// ---- packed (MFMA-fragment-order) f16 arenas in d_ws; offsets in halves ----
// frag layout: dst[((mt*KT + kt)*64 + lane)*8 + j] = src[mt*16 + (lane&15)][kt*32 + (lane>>4)*8 + j]
constexpr size_t P_W0  = 0;         // M=1024 K=512 rows=[wih0|whh0], row=g*256+cell
constexpr size_t P_W1  = 524288;    // M=1024 K=512
constexpr size_t P_SW1 = 1048576;   // M=256  K=512
constexpr size_t P_SW2 = 1179648;   // M=256  K=256
constexpr size_t P_VWO = 1245184;   // M=256  K=256  val_w cols 256..511 (out part)
constexpr size_t P_VWS = 1310720;   // M=256  K=256  val_w cols 0..255  (stack part)
constexpr size_t P_GW  = 1376256;   // [512] linear
constexpr size_t H_TOTAL = 1376768;
constexpr size_t F_BC0 = H_TOTAL / 2;   // [1024] b_ih0+b_hh0 (fp32)
constexpr size_t F_BC1 = F_BC0 + 1024;  // [1024]

// ===================== prologue: fragment-pack weights =====================
__global__ __launch_bounds__(256) void prep_kernel(
    const float* wih0, const float* whh0, const float* bih0, const float* bhh0,
    const float* wih1, const float* whh1, const float* bih1, const float* bhh1,
    const float* stw1, const float* stw2, const float* valw, const float* gatew,
    float* ws) {
  _Float16* hw = (_Float16*)ws;
  const int gt = blockIdx.x * blockDim.x + threadIdx.x;
  const int np = gridDim.x * blockDim.x;

  auto pack = [&](size_t off, int M, int K, auto src) {
    const int KT = K / 32;
    for (int i = gt; i < M * K; i += np) {
      const int j = i & 7, l = (i >> 3) & 63, rem = i >> 9;
      const int kt = rem % KT, mt = rem / KT;
      const int row = mt * 16 + (l & 15), col = kt * 32 + (l >> 4) * 8 + j;
      hw[off + i] = (_Float16)src(row, col);
    }
  };
  pack(P_W0, 1024, 512, [&](int r, int c) { return c < 256 ? wih0[(size_t)r * 256 + c] : whh0[(size_t)r * 256 + c - 256]; });
  pack(P_W1, 1024, 512, [&](int r, int c) { return c < 256 ? wih1[(size_t)r * 256 + c] : whh1[(size_t)r * 256 + c - 256]; });
  pack(P_SW1, 256, 512, [&](int r, int c) { return stw1[(size_t)r * 512 + c]; });
  pack(P_SW2, 256, 256, [&](int r, int c) { return stw2[(size_t)r * 256 + c]; });
  pack(P_VWO, 256, 256, [&](int r, int c) { return valw[(size_t)r * 512 + 256 + c]; });
  pack(P_VWS, 256, 256, [&](int r, int c) { return valw[(size_t)r * 512 + c]; });
  for (int i = gt; i < 512; i += np) hw[P_GW + i] = (_Float16)gatew[i];
  for (int i = gt; i < 1024; i += np) {
    ws[F_BC0 + i] = bih0[i] + bhh0[i];
    ws[F_BC1 + i] = bih1[i] + bhh1[i];
  }
}

// GEMV via MFMA with 8-fragment double-buffered global prefetch.
// Weight frags consumed linearly f = 0..NMT*KT-1 from wp + mt0*KT frags onward.
template <int KT, int NMT>
__device__ __forceinline__ void gemv_mfma(const _Float16* __restrict__ wp, int mt0,
                                          const _Float16* __restrict__ xA,
                                          const _Float16* __restrict__ xB,
                                          float* __restrict__ pre, int l) {
  const int lr = l & 15, lk = l >> 4;
  constexpr int TOT = KT * NMT;
  const _Float16* base = wp + ((size_t)mt0 * KT * 64 + l) * 8;
  h8 a0[8], a1[8];
  #pragma unroll
  for (int i = 0; i < 8; ++i) a0[i] = *(const h8*)(base + (size_t)i * 512);
  f32x4 c = {0.f, 0.f, 0.f, 0.f};
  #pragma unroll
  for (int f0 = 0; f0 < TOT; f0 += 8) {
    h8* cur = ((f0 >> 3) & 1) ? a1 : a0;
    h8* nxt = ((f0 >> 3) & 1) ? a0 : a1;
    if (f0 + 8 < TOT) {
      #pragma unroll
      for (int i = 0; i < 8; ++i) nxt[i] = *(const h8*)(base + (size_t)(f0 + 8 + i) * 512);
    }
    #pragma unroll
    for (int i = 0; i < 8; ++i) {
      const int f = f0 + i, kt = f % KT;
      const _Float16* xb = (KT > 8) ? ((kt < 8) ? xA + kt * 32 : xB + (kt - 8) * 32)
                                    : (xA + kt * 32);
      const h8 x = *(const h8*)(xb + lk * 8);
      c = __builtin_amdgcn_mfma_f32_16x16x32_f16(cur[i], x, c, 0, 0, 0);
      if (kt == KT - 1) {
        if (lr == 0) *((f32x4*)&pre[(mt0 + f / KT) * 16 + lk * 4]) = c;
        c = (f32x4){0.f, 0.f, 0.f, 0.f};
      }
    }
  }
}

// ===================== recurrent scan: 1 WG (16 waves) per batch row =====================
// LDS 108KB -> exactly 1 WG/CU; declare 4 waves/EU so VGPR cap = 128 (deep load pipeline).
__global__ __launch_bounds__(1024, 4) void rnn7_kernel(
    const int* __restrict__ tokens, const int* __restrict__ scope_idx,
    const int* __restrict__ is_id, const int* __restrict__ umask,
    const int* __restrict__ lengths, const float* __restrict__ emb,
    const float* __restrict__ stb1, const float* __restrict__ stb2,
    const float* __restrict__ gateb, const float* __restrict__ valb,
    const float* __restrict__ h0, const float* __restrict__ c0,
    const float* __restrict__ ws, float* __restrict__ out) {
  const int b = blockIdx.x, tid = threadIdx.x;
  const int len = lengths[b];
  const _Float16* hw = (const _Float16*)ws;
  const int w = tid >> 6, l = tid & 63;

  __shared__ __align__(16) _Float16 s_stkh[64][SPAD];  // f16 stack (rows 50..63 zero)
  __shared__ __align__(16) float    s_stk32[NS][NH];   // fp32 truth
  __shared__ __align__(16) float    s_pre[1024];
  __shared__ __align__(16) float    s_c[2][NH];
  __shared__ __align__(16) _Float16 s_h0h[2][NH], s_h1h[2][NH];
  __shared__ __align__(16) _Float16 s_embh[NH], s_z[NH], s_xin[NH];
  __shared__ __align__(16) float    s_vp[NH], s_vb[NH], s_b1[NH], s_b2[NH];
  __shared__ __align__(16) float    s_bc0[1024], s_bc1[1024];
  __shared__ __align__(16) _Float16 s_gw[512];
  __shared__ float s_gate[NS];
  __shared__ int   s_um[NS];
  __shared__ float s_gb;

  // ---- one-time init
  for (int i = tid; i < 64 * SPAD; i += 1024) ((_Float16*)s_stkh)[i] = (_Float16)0.f;
  for (int i = tid; i < NS * NH; i += 1024) ((float*)s_stk32)[i] = 0.f;
  s_bc0[tid] = ws[F_BC0 + tid];
  s_bc1[tid] = ws[F_BC1 + tid];
  if (tid < NH) {
    s_h0h[0][tid] = (_Float16)h0[b * NH + tid];
    s_h1h[0][tid] = (_Float16)h0[NB * NH + b * NH + tid];
    s_c[0][tid] = c0[b * NH + tid];
    s_c[1][tid] = c0[NB * NH + b * NH + tid];
    s_vb[tid] = valb[tid]; s_b1[tid] = stb1[tid]; s_b2[tid] = stb2[tid];
  }
  if (tid < 64) ((h8*)s_gw)[tid] = ((const h8*)(hw + P_GW))[tid];
  if (tid == 0) s_gb = gateb[0];
  __syncthreads();

  for (int t = 0; t < len; ++t) {
    const int p0 = t & 1, p1 = p0 ^ 1;
    const int tok  = tokens[b * NT + t];
    const int sx   = scope_idx[b * NT + t];
    const int isid = is_id[b * NT + t];

    // ---- A: emb -> LDS f16, umask
    if (tid < 64) {
      const float4 e = ((const float4*)(emb + (size_t)tok * NE))[tid];
      h4 v = { (_Float16)e.x, (_Float16)e.y, (_Float16)e.z, (_Float16)e.w };
      ((h4*)s_embh)[tid] = v;
    } else if (tid >= 64 && tid < 64 + NS) {
      s_um[tid - 64] = umask[((size_t)b * NT + t) * NS + (tid - 64)];
    }
    __syncthreads();

    if (isid) {
      // ---- B: z_pre = SW1 . [stk_row(sx); emb]
      gemv_mfma<16, 1>(hw + P_SW1, w, &s_stkh[sx][0], s_embh, s_pre, l);
      __syncthreads();
      if (tid < 256) s_z[tid] = (_Float16)fmaxf(s_pre[tid] + s_b1[tid], 0.f);
      __syncthreads();
      // ---- C: xin = SW2 . z + b2
      gemv_mfma<8, 1>(hw + P_SW2, w, s_z, nullptr, s_pre, l);
      __syncthreads();
      if (tid < 256) s_xin[tid] = (_Float16)(s_pre[tid] + s_b2[tid]);
      __syncthreads();
    } else {
      if (tid < 32) ((h8*)s_xin)[tid] = ((const h8*)s_embh)[tid];
      __syncthreads();
    }

    // ---- D: LSTM0 pre-acts = W0 . [xin; h0(p0)]
    gemv_mfma<16, 4>(hw + P_W0, w * 4, s_xin, s_h0h[p0], s_pre, l);
    __syncthreads();
    if (tid < 256) {
      const int jc = tid;
      const float iv = s_pre[jc] + s_bc0[jc],        fv = s_pre[256 + jc] + s_bc0[256 + jc];
      const float gv = s_pre[512 + jc] + s_bc0[512 + jc], ov = s_pre[768 + jc] + s_bc0[768 + jc];
      const float c_ = sigm(fv) * s_c[0][jc] + sigm(iv) * tanh_f(gv);
      s_c[0][jc] = c_;
      s_h0h[p1][jc] = (_Float16)(sigm(ov) * tanh_f(c_));
    }
    __syncthreads();

    // ---- E: LSTM1 pre-acts = W1 . [h0(p1); h1(p0)]
    gemv_mfma<16, 4>(hw + P_W1, w * 4, s_h0h[p1], s_h1h[p0], s_pre, l);
    __syncthreads();
    if (tid < 256) {
      const int jc = tid;
      const float iv = s_pre[jc] + s_bc1[jc],        fv = s_pre[256 + jc] + s_bc1[256 + jc];
      const float gv = s_pre[512 + jc] + s_bc1[512 + jc], ov = s_pre[768 + jc] + s_bc1[768 + jc];
      const float c_ = sigm(fv) * s_c[1][jc] + sigm(iv) * tanh_f(gv);
      s_c[1][jc] = c_;
      const float h_ = sigm(ov) * tanh_f(c_);
      s_h1h[p1][jc] = (_Float16)h_;
      out[((size_t)b * NT + t) * NV + jc] = h_;   // feats
    }
    __syncthreads();

    // ---- F: vproj (waves 0-7, MFMA dbuf) + slot gates (waves 8-15)
    if (w < 8) {
      const int lr = l & 15, lk = l >> 4;
      const _Float16* base = hw + P_VWO + ((size_t)(w * 2) * 8 * 64 + l) * 8;
      h8 b0[8], b1[8];
      #pragma unroll
      for (int i = 0; i < 8; ++i) b0[i] = *(const h8*)(base + (size_t)i * 512);
      #pragma unroll
      for (int i = 0; i < 8; ++i) b1[i] = *(const h8*)(base + (size_t)(8 + i) * 512);
      #pragma unroll
      for (int m = 0; m < 2; ++m) {
        const int mt = w * 2 + m;
        const h8* cur = m ? b1 : b0;
        f32x4 c = {0.f, 0.f, 0.f, 0.f};
        #pragma unroll
        for (int kt = 0; kt < 8; ++kt) {
          const h8 x = *(const h8*)(&s_h1h[p1][kt * 32 + lk * 8]);
          c = __builtin_amdgcn_mfma_f32_16x16x32_f16(cur[kt], x, c, 0, 0, 0);
        }
        if (lr == 0) {
          const f32x4 vb4 = *((const f32x4*)&s_vb[mt * 16 + lk * 4]);
          c += vb4;
          *((f32x4*)&s_vp[mt * 16 + lk * 4]) = c;
        }
      }
    } else {
      const int wp = w - 8;
      const h2* gs = (const h2*)s_gw;
      const h2* go = (const h2*)(s_gw + 256);
      const h2* oh = (const h2*)s_h1h[p1];
      float po = dot2f(go[2 * l], oh[2 * l], 0.f);
      po = dot2f(go[2 * l + 1], oh[2 * l + 1], po);
      for (int j = 0; j < 7; ++j) {
        const int s = wp + 8 * j;
        if (s < NS) {
          const h2* sr = (const h2*)s_stkh[s];
          float p = dot2f(gs[2 * l], sr[2 * l], po);
          p = dot2f(gs[2 * l + 1], sr[2 * l + 1], p);
          #pragma unroll
          for (int m = 1; m < 64; m <<= 1) p += __shfl_xor(p, m, 64);
          if (l == 0) s_gate[s] = (s_um[s] > 0) ? -1.f : sigm(p + s_gb);
        }
      }
    }
    __syncthreads();

    // ---- F4: stack GEMM (A = stack LDS frags, B = packed VWS, dbuf prefetch)
    {
      const int st = w >> 2, rq = w & 3;
      const int s0 = st * 16, lr = l & 15, lk = l >> 4;
      const _Float16* base = hw + P_VWS + ((size_t)(rq * 4) * 8 * 64 + l) * 8;
      h8 af[8];
      #pragma unroll
      for (int kt = 0; kt < 8; ++kt)
        af[kt] = *(const h8*)&s_stkh[s0 + lr][kt * 32 + lk * 8];
      h8 b0[8], b1[8];
      #pragma unroll
      for (int i = 0; i < 8; ++i) b0[i] = *(const h8*)(base + (size_t)i * 512);
      __syncthreads();  // all A-frags in regs before any wave overwrites stack
      #pragma unroll
      for (int rt4 = 0; rt4 < 4; ++rt4) {
        const h8* cur = (rt4 & 1) ? b1 : b0;
        h8* nxt = (rt4 & 1) ? b0 : b1;
        if (rt4 < 3) {
          #pragma unroll
          for (int i = 0; i < 8; ++i)
            nxt[i] = *(const h8*)(base + (size_t)((rt4 + 1) * 8 + i) * 512);
        }
        const int rt = rq * 4 + rt4;
        f32x4 c = {0.f, 0.f, 0.f, 0.f};
        #pragma unroll
        for (int kt = 0; kt < 8; ++kt)
          c = __builtin_amdgcn_mfma_f32_16x16x32_f16(af[kt], cur[kt], c, 0, 0, 0);
        const int r = rt * 16 + lr;
        #pragma unroll
        for (int i = 0; i < 4; ++i) {
          const int s = s0 + lk * 4 + i;
          if (s < NS) {
            const float gv = s_gate[s];
            float nsv = 0.f;
            if (gv >= 0.f)
              nsv = s_stk32[s][r] * (1.f - gv) + gv * tanh_f(c[i] + s_vp[r]);
            s_stk32[s][r] = nsv;
            s_stkh[s][r]  = (_Float16)nsv;
          }
        }
      }
    }
    __syncthreads();
  }
}

// ===================== logits epilogue (feats live in out[b][t][0:256]) =====================
constexpr int TBR = 32;
__global__ __launch_bounds__(256) void logits_kernel(
    const float* __restrict__ w1, const float* __restrict__ b1,
    const float* __restrict__ w2, const float* __restrict__ b2,
    const int* __restrict__ lengths, float* __restrict__ out) {
  const int blk = blockIdx.x;
  const int b = blk >> 4;
  const int t0 = (blk & 15) * TBR;
  const int tid = threadIdx.x;
  const int len = lengths[b];
  __shared__ __align__(16) float s_fe[TBR][NH];
  __shared__ __align__(16) float s_hid[TBR][NH];

  for (int r = 0; r < TBR; ++r) {
    const int t = t0 + r;
    s_fe[r][tid] = (t < len) ? out[((size_t)b * NT + t) * NV + tid] : 0.f;
  }
  __syncthreads();
  for (int r = 0; r < TBR; ++r) {
    float acc = b1[tid];
    const float4* fr = (const float4*)s_fe[r];
    const float4* wr = (const float4*)(w1 + (size_t)tid * NH);
    #pragma unroll 8
    for (int k = 0; k < NH / 4; ++k) { float4 wv = wr[k]; float4 fv = fr[k]; FMA4(acc, wv, fv); }
    s_hid[r][tid] = fmaxf(acc, 0.f);
  }
  __syncthreads();
  for (int r = 0; r < TBR; ++r) {
    const int t = t0 + r;
    if (t >= len) {
      float4* orow = (float4*)(out + ((size_t)b * NT + t) * NV);
      const float4 m1 = make_float4(-1.f, -1.f, -1.f, -1.f);
      for (int i = tid; i < NV / 4; i += 256) orow[i] = m1;
    }
  }
  if (t0 >= len) return;
  for (int pass = 0; pass < (NV + 511) / 512; ++pass) {
    const int v0 = pass * 512 + tid * 2;
    if (v0 >= NV) continue;
    float acc0[TBR], acc1[TBR];
    #pragma unroll
    for (int r = 0; r < TBR; ++r) { acc0[r] = 0.f; acc1[r] = 0.f; }
    const float4* wa = (const float4*)(w2 + (size_t)v0 * NH);
    const float4* wb = (const float4*)(w2 + (size_t)(v0 + 1) * NH);
    for (int k = 0; k < NH / 4; ++k) {
      const float4 w0 = wa[k], w1v = wb[k];
      #pragma unroll
      for (int r = 0; r < TBR; ++r) {
        const float4 hx = *(const float4*)&s_hid[r][k * 4];
        acc0[r] += w0.x * hx.x + w0.y * hx.y + w0.z * hx.z + w0.w * hx.w;
        acc1[r] += w1v.x * hx.x + w1v.y * hx.y + w1v.z * hx.z + w1v.w * hx.w;
      }
    }
    const float bb0 = b2[v0], bb1 = b2[v0 + 1];
    for (int r = 0; r < TBR; ++r) {
      const int t = t0 + r;
      if (t < len) {
        float2 st = make_float2(acc0[r] + bb0, acc1[r] + bb1);
        *(float2*)(out + ((size_t)b * NT + t) * NV + v0) = st;
      }
    }
  }
}

extern "C" void kernel_launch(void* const* d_in, const int* in_sizes, int n_in,
                              void* d_out, int out_size, void* d_ws, size_t ws_size,
                              hipStream_t stream) {
  (void)in_sizes; (void)n_in; (void)out_size; (void)ws_size;
  const int* tokens    = (const int*)d_in[0];
  const int* scope_idx = (const int*)d_in[1];
  const int* is_id     = (const int*)d_in[2];
  const int* umask     = (const int*)d_in[3];
  const int* lengths   = (const int*)d_in[4];
  const float* emb   = (const float*)d_in[5];
  const float* wih0  = (const float*)d_in[6];  const float* whh0 = (const float*)d_in[7];
  const float* bih0  = (const float*)d_in[8];  const float* bhh0 = (const float*)d_in[9];
  const float* wih1  = (const float*)d_in[10]; const float* whh1 = (const float*)d_in[11];
  const float* bih1  = (const float*)d_in[12]; const float* bhh1 = (const float*)d_in[13];
  const float* stw1  = (const float*)d_in[14]; const float* stb1 = (const float*)d_in[15];
  const float* stw2  = (const float*)d_in[16]; const float* stb2 = (const float*)d_in[17];
  const float* gatew = (const float*)d_in[18]; const float* gateb = (const float*)d_in[19];
  const float* valw  = (const float*)d_in[20]; const float* valb  = (const float*)d_in[21];
  const float* outw1 = (const float*)d_in[22]; const float* outb1 = (const float*)d_in[23];
  const float* outw2 = (const float*)d_in[24]; const float* outb2 = (const float*)d_in[25];
  const float* h0 = (const float*)d_in[26];
  const float* c0 = (const float*)d_in[27];
  float* ws = (float*)d_ws;
  float* out = (float*)d_out;

  prep_kernel<<<dim3(256), dim3(256), 0, stream>>>(
      wih0, whh0, bih0, bhh0, wih1, whh1, bih1, bhh1, stw1, stw2, valw, gatew, ws);

  rnn7_kernel<<<dim3(NB), dim3(1024), 0, stream>>>(
      tokens, scope_idx, is_id, umask, lengths, emb,
      stb1, stb2, gateb, valb, h0, c0, ws, out);

  logits_kernel<<<dim3(NB * 16), dim3(256), 0, stream>>>(
      outw1, outb1, outw2, outb2, lengths, out);
}

// Round 10
// 39571.777 us; speedup vs baseline: 2.2673x; 1.0742x over previous
//
#include <hip/hip_runtime.h>
#include <math.h>

// Problem constants
constexpr int NB = 32, NT = 512, NH = 256, NE = 256, NS = 50, NV = 10000;
constexpr int SPAD = 264;   // padded stack row (f16 elems)

typedef _Float16 h2 __attribute__((ext_vector_type(2)));
typedef _Float16 h4 __attribute__((ext_vector_type(4)));
typedef _Float16 h8 __attribute__((ext_vector_type(8)));
typedef float f32x4 __attribute__((ext_vector_type(4)));

#define FMA4(acc, Wv, Xv) acc += (Wv).x*(Xv).x + (Wv).y*(Xv).y + (Wv).z*(Xv).z + (Wv).w*(Xv).w

#if __has_builtin(__builtin_amdgcn_fdot2)
__device__ __forceinline__ float dot2f(h2 a, h2 b, float c) { return __builtin_amdgcn_fdot2(a, b, c, false); }
#else
__device__ __forceinline__ float dot2f(h2 a, h2 b, float c) { return c + (float)a[0]*(float)b[0] + (float)a[1]*(float)b[1]; }
#endif
__device__ __forceinline__ float sigm(float x) { return 1.f / (1.f + __expf(-x)); }
__device__ __forceinline__ float tanh_f(float x) { const float e = __expf(2.f * x); return 1.f - 2.f / (e + 1.f); }

// ---- asm pipelined load primitives ----
// RULES (learned r9): consume a slot BEFORE re-issuing into it (C-level WAR enforces
// ordering); waits use constant counts; extra older/younger vmem ops only make the
// wait stricter, never looser.
__device__ __forceinline__ void gload16(h8& d, const _Float16* p) {
  asm volatile("global_load_dwordx4 %0, %1, off" : "=&v"(d) : "v"(p));
}
#define VWAIT4() asm volatile("s_waitcnt vmcnt(4)" ::: "memory")
#define VWAIT0() asm volatile("s_waitcnt vmcnt(0)" ::: "memory")
#define SBAR()   __builtin_amdgcn_sched_barrier(0)

// ---- packed (MFMA-fragment-order) f16 arenas in d_ws; offsets in halves ----
// frag layout: dst[((mt*KT + kt)*64 + lane)*8 + j] = src[mt*16 + (lane&15)][kt*32 + (lane>>4)*8 + j]
constexpr size_t P_W0  = 0;         // M=1024 K=512 rows=[wih0|whh0], row=g*256+cell
constexpr size_t P_W1  = 524288;    // M=1024 K=512
constexpr size_t P_SW1 = 1048576;   // M=256  K=512
constexpr size_t P_SW2 = 1179648;   // M=256  K=256
constexpr size_t P_VWO = 1245184;   // M=256  K=256  val_w cols 256..511 (out part)
constexpr size_t P_VWS = 1310720;   // M=256  K=256  val_w cols 0..255  (stack part)
constexpr size_t P_GW  = 1376256;   // [512] linear
constexpr size_t H_TOTAL = 1376768;
constexpr size_t F_BC0 = H_TOTAL / 2;   // [1024] b_ih0+b_hh0 (fp32)
constexpr size_t F_BC1 = F_BC0 + 1024;  // [1024]

// ===================== prologue: fragment-pack weights =====================
__global__ __launch_bounds__(256) void prep_kernel(
    const float* wih0, const float* whh0, const float* bih0, const float* bhh0,
    const float* wih1, const float* whh1, const float* bih1, const float* bhh1,
    const float* stw1, const float* stw2, const float* valw, const float* gatew,
    float* ws) {
  _Float16* hw = (_Float16*)ws;
  const int gt = blockIdx.x * blockDim.x + threadIdx.x;
  const int np = gridDim.x * blockDim.x;

  auto pack = [&](size_t off, int M, int K, auto src) {
    const int KT = K / 32;
    for (int i = gt; i < M * K; i += np) {
      const int j = i & 7, l = (i >> 3) & 63, rem = i >> 9;
      const int kt = rem % KT, mt = rem / KT;
      const int row = mt * 16 + (l & 15), col = kt * 32 + (l >> 4) * 8 + j;
      hw[off + i] = (_Float16)src(row, col);
    }
  };
  pack(P_W0, 1024, 512, [&](int r, int c) { return c < 256 ? wih0[(size_t)r * 256 + c] : whh0[(size_t)r * 256 + c - 256]; });
  pack(P_W1, 1024, 512, [&](int r, int c) { return c < 256 ? wih1[(size_t)r * 256 + c] : whh1[(size_t)r * 256 + c - 256]; });
  pack(P_SW1, 256, 512, [&](int r, int c) { return stw1[(size_t)r * 512 + c]; });
  pack(P_SW2, 256, 256, [&](int r, int c) { return stw2[(size_t)r * 256 + c]; });
  pack(P_VWO, 256, 256, [&](int r, int c) { return valw[(size_t)r * 512 + 256 + c]; });
  pack(P_VWS, 256, 256, [&](int r, int c) { return valw[(size_t)r * 512 + c]; });
  for (int i = gt; i < 512; i += np) hw[P_GW + i] = (_Float16)gatew[i];
  for (int i = gt; i < 1024; i += np) {
    ws[F_BC0 + i] = bih0[i] + bhh0[i];
    ws[F_BC1 + i] = bih1[i] + bhh1[i];
  }
}

// GEMV via MFMA, chunked(4) double-buffered asm pipeline with counted vmcnt.
template <int KT, int NMT>
__device__ __forceinline__ void gemv_pipe(const _Float16* __restrict__ wp, int mt0,
                                          const _Float16* __restrict__ xA,
                                          const _Float16* __restrict__ xB,
                                          float* __restrict__ pre, int l) {
  const int lr = l & 15, lk = l >> 4;
  constexpr int TOT = KT * NMT;      // 8 | 16 | 64 (multiple of 4)
  constexpr int NC  = TOT / 4;
  const _Float16* base = wp + ((size_t)mt0 * KT * 64 + (size_t)l) * 8;
  h8 A[4], B[4];
  #pragma unroll
  for (int i = 0; i < 4; ++i) gload16(A[i], base + (size_t)i * 512);
  if constexpr (NC > 1) {
    #pragma unroll
    for (int i = 0; i < 4; ++i) gload16(B[i], base + (size_t)(4 + i) * 512);
  }
  f32x4 c = {0.f, 0.f, 0.f, 0.f};
  #pragma unroll
  for (int ch = 0; ch < NC; ++ch) {
    h8* cur = (ch & 1) ? B : A;
    if (ch < NC - 1) VWAIT4(); else VWAIT0();
    SBAR();
    #pragma unroll
    for (int i = 0; i < 4; ++i) {
      const int f = ch * 4 + i;
      const int kt = f % KT;
      const _Float16* xb = (KT > 8) ? ((kt < 8) ? xA + kt * 32 : xB + (kt - 8) * 32)
                                    : (xA + kt * 32);
      const h8 x = *(const h8*)(xb + lk * 8);
      c = __builtin_amdgcn_mfma_f32_16x16x32_f16(cur[i], x, c, 0, 0, 0);
      if (kt == KT - 1) {
        if (lr == 0) *((f32x4*)&pre[(mt0 + f / KT) * 16 + lk * 4]) = c;
        c = (f32x4){0.f, 0.f, 0.f, 0.f};
      }
    }
    if (ch + 2 < NC) {   // re-issue this buffer AFTER consumption (WAR-ordered)
      #pragma unroll
      for (int i = 0; i < 4; ++i) gload16(cur[i], base + (size_t)((ch + 2) * 4 + i) * 512);
    }
  }
}

// ===================== recurrent scan: 1 WG (16 waves) per batch row =====================
__global__ __launch_bounds__(1024, 4) void rnn9_kernel(
    const int* __restrict__ tokens, const int* __restrict__ scope_idx,
    const int* __restrict__ is_id, const int* __restrict__ umask,
    const int* __restrict__ lengths, const float* __restrict__ emb,
    const float* __restrict__ stb1, const float* __restrict__ stb2,
    const float* __restrict__ gateb, const float* __restrict__ valb,
    const float* __restrict__ h0, const float* __restrict__ c0,
    const float* __restrict__ ws, float* __restrict__ out) {
  const int b = blockIdx.x, tid = threadIdx.x;
  const int len = lengths[b];
  const _Float16* hw = (const _Float16*)ws;
  const int w = tid >> 6, l = tid & 63;

  __shared__ __align__(16) _Float16 s_stkh[64][SPAD];  // f16 stack (rows 50..63 zero)
  __shared__ __align__(16) float    s_stk32[NS][NH];   // fp32 truth
  __shared__ __align__(16) float    s_pre[1024];
  __shared__ __align__(16) float    s_c[2][NH];
  __shared__ __align__(16) _Float16 s_h0h[2][NH], s_h1h[2][NH];
  __shared__ __align__(16) _Float16 s_embh[NH], s_z[NH], s_xin[NH];
  __shared__ __align__(16) float    s_vb[NH], s_b1[NH], s_b2[NH];
  __shared__ __align__(16) float    s_bc0[1024], s_bc1[1024];
  __shared__ __align__(16) _Float16 s_gw[512];
  __shared__ float s_gate[NS];
  __shared__ int   s_um[NS];
  __shared__ float s_gb;

  // ---- one-time init
  for (int i = tid; i < 64 * SPAD; i += 1024) ((_Float16*)s_stkh)[i] = (_Float16)0.f;
  for (int i = tid; i < NS * NH; i += 1024) ((float*)s_stk32)[i] = 0.f;
  s_bc0[tid] = ws[F_BC0 + tid];
  s_bc1[tid] = ws[F_BC1 + tid];
  if (tid < NH) {
    s_h0h[0][tid] = (_Float16)h0[b * NH + tid];
    s_h1h[0][tid] = (_Float16)h0[NB * NH + b * NH + tid];
    s_c[0][tid] = c0[b * NH + tid];
    s_c[1][tid] = c0[NB * NH + b * NH + tid];
    s_vb[tid] = valb[tid]; s_b1[tid] = stb1[tid]; s_b2[tid] = stb2[tid];
  }
  if (tid < 64) ((h8*)s_gw)[tid] = ((const h8*)(hw + P_GW))[tid];
  if (tid == 0) s_gb = gateb[0];
  __syncthreads();

  for (int t = 0; t < len; ++t) {
    const int p0 = t & 1, p1 = p0 ^ 1;
    const int tok  = tokens[b * NT + t];
    const int sx   = scope_idx[b * NT + t];
    const int isid = is_id[b * NT + t];

    // ---- A: emb -> LDS f16, umask
    if (tid < 64) {
      const float4 e = ((const float4*)(emb + (size_t)tok * NE))[tid];
      h4 v = { (_Float16)e.x, (_Float16)e.y, (_Float16)e.z, (_Float16)e.w };
      ((h4*)s_embh)[tid] = v;
    } else if (tid >= 64 && tid < 64 + NS) {
      s_um[tid - 64] = umask[((size_t)b * NT + t) * NS + (tid - 64)];
    }
    __syncthreads();

    if (isid) {
      // ---- B: z_pre = SW1 . [stk_row(sx); emb]
      gemv_pipe<16, 1>(hw + P_SW1, w, &s_stkh[sx][0], s_embh, s_pre, l);
      __syncthreads();
      if (tid < 256) s_z[tid] = (_Float16)fmaxf(s_pre[tid] + s_b1[tid], 0.f);
      __syncthreads();
      // ---- C: xin = SW2 . z + b2
      gemv_pipe<8, 1>(hw + P_SW2, w, s_z, s_z, s_pre, l);
      __syncthreads();
      if (tid < 256) s_xin[tid] = (_Float16)(s_pre[tid] + s_b2[tid]);
      __syncthreads();
    } else {
      if (tid < 32) ((h8*)s_xin)[tid] = ((const h8*)s_embh)[tid];
      __syncthreads();
    }

    // ---- D: LSTM0 pre-acts = W0 . [xin; h0(p0)]
    gemv_pipe<16, 4>(hw + P_W0, w * 4, s_xin, s_h0h[p0], s_pre, l);
    __syncthreads();
    if (tid < 256) {
      const int jc = tid;
      const float iv = s_pre[jc] + s_bc0[jc],        fv = s_pre[256 + jc] + s_bc0[256 + jc];
      const float gv = s_pre[512 + jc] + s_bc0[512 + jc], ov = s_pre[768 + jc] + s_bc0[768 + jc];
      const float c_ = sigm(fv) * s_c[0][jc] + sigm(iv) * tanh_f(gv);
      s_c[0][jc] = c_;
      s_h0h[p1][jc] = (_Float16)(sigm(ov) * tanh_f(c_));
    }
    __syncthreads();

    // ---- E: LSTM1 pre-acts = W1 . [h0(p1); h1(p0)]
    gemv_pipe<16, 4>(hw + P_W1, w * 4, s_h0h[p1], s_h1h[p0], s_pre, l);
    __syncthreads();
    if (tid < 256) {
      const int jc = tid;
      const float iv = s_pre[jc] + s_bc1[jc],        fv = s_pre[256 + jc] + s_bc1[256 + jc];
      const float gv = s_pre[512 + jc] + s_bc1[512 + jc], ov = s_pre[768 + jc] + s_bc1[768 + jc];
      const float c_ = sigm(fv) * s_c[1][jc] + sigm(iv) * tanh_f(gv);
      s_c[1][jc] = c_;
      const float h_ = sigm(ov) * tanh_f(c_);
      s_h1h[p1][jc] = (_Float16)h_;
      out[((size_t)b * NT + t) * NV + jc] = h_;   // feats
    }
    __syncthreads();

    // ---- F: vproj -> s_pre[0:256] (waves 0-7, pipelined) + slot gates (waves 8-15)
    if (w < 8) {
      gemv_pipe<8, 2>(hw + P_VWO, w * 2, s_h1h[p1], s_h1h[p1], s_pre, l);
    } else {
      const int wp = w - 8;
      const h2* gs = (const h2*)s_gw;
      const h2* go = (const h2*)(s_gw + 256);
      const h2* oh = (const h2*)s_h1h[p1];
      float po = dot2f(go[2 * l], oh[2 * l], 0.f);
      po = dot2f(go[2 * l + 1], oh[2 * l + 1], po);
      for (int j = 0; j < 7; ++j) {
        const int s = wp + 8 * j;
        if (s < NS) {
          const h2* sr = (const h2*)s_stkh[s];
          float p = dot2f(gs[2 * l], sr[2 * l], po);
          p = dot2f(gs[2 * l + 1], sr[2 * l + 1], p);
          #pragma unroll
          for (int m = 1; m < 64; m <<= 1) p += __shfl_xor(p, m, 64);
          if (l == 0) s_gate[s] = (s_um[s] > 0) ? -1.f : sigm(p + s_gb);
        }
      }
    }
    __syncthreads();

    // ---- F4: stack GEMM (A = stack LDS frags, B = packed VWS, chunked dbuf pipeline)
    {
      const int st = w >> 2, rq = w & 3;
      const int s0 = st * 16, lr = l & 15, lk = l >> 4;
      const _Float16* baseB = hw + P_VWS + ((size_t)(rq * 4) * 8 * 64 + (size_t)l) * 8;
      h8 af[8];
      #pragma unroll
      for (int kt = 0; kt < 8; ++kt)
        af[kt] = *(const h8*)&s_stkh[s0 + lr][kt * 32 + lk * 8];
      __syncthreads();  // all A-frags in regs before any wave overwrites stack
      h8 A4[4], B4[4];
      #pragma unroll
      for (int i = 0; i < 4; ++i) gload16(A4[i], baseB + (size_t)i * 512);
      #pragma unroll
      for (int i = 0; i < 4; ++i) gload16(B4[i], baseB + (size_t)(4 + i) * 512);
      f32x4 c = {0.f, 0.f, 0.f, 0.f};
      #pragma unroll
      for (int ch = 0; ch < 8; ++ch) {          // 32 frags, 4 per chunk
        h8* cur = (ch & 1) ? B4 : A4;
        if (ch < 7) VWAIT4(); else VWAIT0();
        SBAR();
        #pragma unroll
        for (int i = 0; i < 4; ++i) {
          const int f = ch * 4 + i, kt = f & 7;
          c = __builtin_amdgcn_mfma_f32_16x16x32_f16(af[kt], cur[i], c, 0, 0, 0);
          if (kt == 7) {
            const int rt = rq * 4 + (f >> 3);
            const int r = rt * 16 + lr;
            #pragma unroll
            for (int q = 0; q < 4; ++q) {
              const int s = s0 + lk * 4 + q;
              if (s < NS) {
                const float gv = s_gate[s];
                float nsv = 0.f;
                if (gv >= 0.f)
                  nsv = s_stk32[s][r] * (1.f - gv) + gv * tanh_f(c[q] + s_pre[r] + s_vb[r]);
                s_stk32[s][r] = nsv;
                s_stkh[s][r]  = (_Float16)nsv;
              }
            }
            c = (f32x4){0.f, 0.f, 0.f, 0.f};
          }
        }
        if (ch + 2 < 8) {
          #pragma unroll
          for (int i = 0; i < 4; ++i) gload16(cur[i], baseB + (size_t)((ch + 2) * 4 + i) * 512);
        }
      }
    }
    __syncthreads();
  }
}

// ===================== logits epilogue (feats live in out[b][t][0:256]) =====================
constexpr int TBR = 32;
__global__ __launch_bounds__(256) void logits_kernel(
    const float* __restrict__ w1, const float* __restrict__ b1,
    const float* __restrict__ w2, const float* __restrict__ b2,
    const int* __restrict__ lengths, float* __restrict__ out) {
  const int blk = blockIdx.x;
  const int b = blk >> 4;
  const int t0 = (blk & 15) * TBR;
  const int tid = threadIdx.x;
  const int len = lengths[b];
  __shared__ __align__(16) float s_fe[TBR][NH];
  __shared__ __align__(16) float s_hid[TBR][NH];

  for (int r = 0; r < TBR; ++r) {
    const int t = t0 + r;
    s_fe[r][tid] = (t < len) ? out[((size_t)b * NT + t) * NV + tid] : 0.f;
  }
  __syncthreads();
  for (int r = 0; r < TBR; ++r) {
    float acc = b1[tid];
    const float4* fr = (const float4*)s_fe[r];
    const float4* wr = (const float4*)(w1 + (size_t)tid * NH);
    #pragma unroll 8
    for (int k = 0; k < NH / 4; ++k) { float4 wv = wr[k]; float4 fv = fr[k]; FMA4(acc, wv, fv); }
    s_hid[r][tid] = fmaxf(acc, 0.f);
  }
  __syncthreads();
  for (int r = 0; r < TBR; ++r) {
    const int t = t0 + r;
    if (t >= len) {
      float4* orow = (float4*)(out + ((size_t)b * NT + t) * NV);
      const float4 m1 = make_float4(-1.f, -1.f, -1.f, -1.f);
      for (int i = tid; i < NV / 4; i += 256) orow[i] = m1;
    }
  }
  if (t0 >= len) return;
  for (int pass = 0; pass < (NV + 511) / 512; ++pass) {
    const int v0 = pass * 512 + tid * 2;
    if (v0 >= NV) continue;
    float acc0[TBR], acc1[TBR];
    #pragma unroll
    for (int r = 0; r < TBR; ++r) { acc0[r] = 0.f; acc1[r] = 0.f; }
    const float4* wa = (const float4*)(w2 + (size_t)v0 * NH);
    const float4* wb = (const float4*)(w2 + (size_t)(v0 + 1) * NH);
    for (int k = 0; k < NH / 4; ++k) {
      const float4 w0 = wa[k], w1v = wb[k];
      #pragma unroll
      for (int r = 0; r < TBR; ++r) {
        const float4 hx = *(const float4*)&s_hid[r][k * 4];
        acc0[r] += w0.x * hx.x + w0.y * hx.y + w0.z * hx.z + w0.w * hx.w;
        acc1[r] += w1v.x * hx.x + w1v.y * hx.y + w1v.z * hx.z + w1v.w * hx.w;
      }
    }
    const float bb0 = b2[v0], bb1 = b2[v0 + 1];
    for (int r = 0; r < TBR; ++r) {
      const int t = t0 + r;
      if (t < len) {
        float2 st = make_float2(acc0[r] + bb0, acc1[r] + bb1);
        *(float2*)(out + ((size_t)b * NT + t) * NV + v0) = st;
      }
    }
  }
}

extern "C" void kernel_launch(void* const* d_in, const int* in_sizes, int n_in,
                              void* d_out, int out_size, void* d_ws, size_t ws_size,
                              hipStream_t stream) {
  (void)in_sizes; (void)n_in; (void)out_size; (void)ws_size;
  const int* tokens    = (const int*)d_in[0];
  const int* scope_idx = (const int*)d_in[1];
  const int* is_id     = (const int*)d_in[2];
  const int* umask     = (const int*)d_in[3];
  const int* lengths   = (const int*)d_in[4];
  const float* emb   = (const float*)d_in[5];
  const float* wih0  = (const float*)d_in[6];  const float* whh0 = (const float*)d_in[7];
  const float* bih0  = (const float*)d_in[8];  const float* bhh0 = (const float*)d_in[9];
  const float* wih1  = (const float*)d_in[10]; const float* whh1 = (const float*)d_in[11];
  const float* bih1  = (const float*)d_in[12]; const float* bhh1 = (const float*)d_in[13];
  const float* stw1  = (const float*)d_in[14]; const float* stb1 = (const float*)d_in[15];
  const float* stw2  = (const float*)d_in[16]; const float* stb2 = (const float*)d_in[17];
  const float* gatew = (const float*)d_in[18]; const float* gateb = (const float*)d_in[19];
  const float* valw  = (const float*)d_in[20]; const float* valb  = (const float*)d_in[21];
  const float* outw1 = (const float*)d_in[22]; const float* outb1 = (const float*)d_in[23];
  const float* outw2 = (const float*)d_in[24]; const float* outb2 = (const float*)d_in[25];
  const float* h0 = (const float*)d_in[26];
  const float* c0 = (const float*)d_in[27];
  float* ws = (float*)d_ws;
  float* out = (float*)d_out;

  prep_kernel<<<dim3(256), dim3(256), 0, stream>>>(
      wih0, whh0, bih0, bhh0, wih1, whh1, bih1, bhh1, stw1, stw2, valw, gatew, ws);

  rnn9_kernel<<<dim3(NB), dim3(1024), 0, stream>>>(
      tokens, scope_idx, is_id, umask, lengths, emb,
      stb1, stb2, gateb, valb, h0, c0, ws, out);

  logits_kernel<<<dim3(NB * 16), dim3(256), 0, stream>>>(
      outw1, outb1, outw2, outb2, lengths, out);
}

// Round 11
// 23503.300 us; speedup vs baseline: 3.8174x; 1.6837x over previous
//
#include <hip/hip_runtime.h>
#include <math.h>

// Problem constants
constexpr int NB = 32, NT = 512, NH = 256, NE = 256, NS = 50, NV = 10000;
constexpr int SPAD = 264;   // padded stack row (f16 elems)

typedef _Float16 h2 __attribute__((ext_vector_type(2)));
typedef _Float16 h4 __attribute__((ext_vector_type(4)));
typedef _Float16 h8 __attribute__((ext_vector_type(8)));
typedef float f32x4 __attribute__((ext_vector_type(4)));

#define FMA4(acc, Wv, Xv) acc += (Wv).x*(Xv).x + (Wv).y*(Xv).y + (Wv).z*(Xv).z + (Wv).w*(Xv).w

#if __has_builtin(__builtin_amdgcn_fdot2)
__device__ __forceinline__ float dot2f(h2 a, h2 b, float c) { return __builtin_amdgcn_fdot2(a, b, c, false); }
#else
__device__ __forceinline__ float dot2f(h2 a, h2 b, float c) { return c + (float)a[0]*(float)b[0] + (float)a[1]*(float)b[1]; }
#endif
__device__ __forceinline__ float sigm(float x) { return 1.f / (1.f + __expf(-x)); }
__device__ __forceinline__ float tanh_f(float x) { const float e = __expf(2.f * x); return 1.f - 2.f / (e + 1.f); }

// ---- asm pipelined load primitives (r9 rules: consume-before-reissue, counted waits) ----
__device__ __forceinline__ void gload16(h8& d, const _Float16* p) {
  asm volatile("global_load_dwordx4 %0, %1, off" : "=&v"(d) : "v"(p));
}
#define VWAIT4() asm volatile("s_waitcnt vmcnt(4)" ::: "memory")
#define VWAIT0() asm volatile("s_waitcnt vmcnt(0)" ::: "memory")
#define SBAR()   __builtin_amdgcn_sched_barrier(0)

// ---- packed (MFMA-fragment-order) f16 arenas in d_ws; offsets in halves ----
constexpr size_t P_W0  = 0;         // M=1024 K=512 rows=[wih0|whh0], row=g*256+cell
constexpr size_t P_W1  = 524288;    // M=1024 K=512
constexpr size_t P_SW1 = 1048576;   // M=256  K=512
constexpr size_t P_SW2 = 1179648;   // M=256  K=256
constexpr size_t P_VWO = 1245184;   // M=256  K=256  val_w out part
constexpr size_t P_VWS = 1310720;   // M=256  K=256  val_w stack part
constexpr size_t P_GW  = 1376256;   // [512] linear
constexpr size_t H_TOTAL = 1376768;
constexpr size_t F_BC0 = H_TOTAL / 2;    // [1024] fp32
constexpr size_t F_BC1 = F_BC0 + 1024;   // [1024]
// quad-exchange slots (fp32, MALL-only traffic) + counters
constexpr size_t F_XB  = F_BC1 + 1024;   // [4][32][256]
constexpr size_t F_XD  = F_XB + 32768;   // [4][32][1024]
constexpr size_t F_XE  = F_XD + 131072;  // [4][32][1024]
constexpr size_t F_CTR = F_XE + 131072;  // u32 counters, 16-float stride per (phase,b)

// ===================== prologue: fragment-pack weights (unchanged, proven) ================
__global__ __launch_bounds__(256) void prep_kernel(
    const float* wih0, const float* whh0, const float* bih0, const float* bhh0,
    const float* wih1, const float* whh1, const float* bih1, const float* bhh1,
    const float* stw1, const float* stw2, const float* valw, const float* gatew,
    float* ws) {
  _Float16* hw = (_Float16*)ws;
  const int gt = blockIdx.x * blockDim.x + threadIdx.x;
  const int np = gridDim.x * blockDim.x;

  auto pack = [&](size_t off, int M, int K, auto src) {
    const int KT = K / 32;
    for (int i = gt; i < M * K; i += np) {
      const int j = i & 7, l = (i >> 3) & 63, rem = i >> 9;
      const int kt = rem % KT, mt = rem / KT;
      const int row = mt * 16 + (l & 15), col = kt * 32 + (l >> 4) * 8 + j;
      hw[off + i] = (_Float16)src(row, col);
    }
  };
  pack(P_W0, 1024, 512, [&](int r, int c) { return c < 256 ? wih0[(size_t)r * 256 + c] : whh0[(size_t)r * 256 + c - 256]; });
  pack(P_W1, 1024, 512, [&](int r, int c) { return c < 256 ? wih1[(size_t)r * 256 + c] : whh1[(size_t)r * 256 + c - 256]; });
  pack(P_SW1, 256, 512, [&](int r, int c) { return stw1[(size_t)r * 512 + c]; });
  pack(P_SW2, 256, 256, [&](int r, int c) { return stw2[(size_t)r * 256 + c]; });
  pack(P_VWO, 256, 256, [&](int r, int c) { return valw[(size_t)r * 512 + 256 + c]; });
  pack(P_VWS, 256, 256, [&](int r, int c) { return valw[(size_t)r * 512 + c]; });
  for (int i = gt; i < 512; i += np) hw[P_GW + i] = (_Float16)gatew[i];
  for (int i = gt; i < 1024; i += np) {
    ws[F_BC0 + i] = bih0[i] + bhh0[i];
    ws[F_BC1 + i] = bih1[i] + bhh1[i];
  }
}

// Full-K GEMV pipeline (unchanged from r10, proven correct)
template <int KT, int NMT>
__device__ __forceinline__ void gemv_pipe(const _Float16* __restrict__ wp, int mt0,
                                          const _Float16* __restrict__ xA,
                                          const _Float16* __restrict__ xB,
                                          float* __restrict__ pre, int l) {
  const int lr = l & 15, lk = l >> 4;
  constexpr int TOT = KT * NMT;
  constexpr int NC  = TOT / 4;
  const _Float16* base = wp + ((size_t)mt0 * KT * 64 + (size_t)l) * 8;
  h8 A[4], B[4];
  #pragma unroll
  for (int i = 0; i < 4; ++i) gload16(A[i], base + (size_t)i * 512);
  if constexpr (NC > 1) {
    #pragma unroll
    for (int i = 0; i < 4; ++i) gload16(B[i], base + (size_t)(4 + i) * 512);
  }
  f32x4 c = {0.f, 0.f, 0.f, 0.f};
  #pragma unroll
  for (int ch = 0; ch < NC; ++ch) {
    h8* cur = (ch & 1) ? B : A;
    if (ch < NC - 1) VWAIT4(); else VWAIT0();
    SBAR();
    #pragma unroll
    for (int i = 0; i < 4; ++i) {
      const int f = ch * 4 + i;
      const int kt = f % KT;
      const _Float16* xb = (KT > 8) ? ((kt < 8) ? xA + kt * 32 : xB + (kt - 8) * 32)
                                    : (xA + kt * 32);
      const h8 x = *(const h8*)(xb + lk * 8);
      c = __builtin_amdgcn_mfma_f32_16x16x32_f16(cur[i], x, c, 0, 0, 0);
      if (kt == KT - 1) {
        if (lr == 0) *((f32x4*)&pre[(mt0 + f / KT) * 16 + lk * 4]) = c;
        c = (f32x4){0.f, 0.f, 0.f, 0.f};
      }
    }
    if (ch + 2 < NC) {
      #pragma unroll
      for (int i = 0; i < 4; ++i) gload16(cur[i], base + (size_t)((ch + 2) * 4 + i) * 512);
    }
  }
}

// Partial-K GEMV: frags mt in [mt0,mt0+NMT), kt in [kt0,kt0+KTC). Writes PARTIAL sums.
template <int KT, int NMT, int KTC>
__device__ __forceinline__ void gemv_part(const _Float16* __restrict__ wp, int mt0, int kt0,
                                          const _Float16* __restrict__ xA,
                                          const _Float16* __restrict__ xB,
                                          float* __restrict__ pre, int l) {
  const int lr = l & 15, lk = l >> 4;
  constexpr int TOT = NMT * KTC;      // 4 or 16
  constexpr int NC  = TOT / 4;
  h8 A[4], B[4];
  auto addr = [&](int f) {
    const int mt = mt0 + f / KTC, kt = kt0 + f % KTC;
    return wp + ((size_t)(mt * KT + kt) * 64 + (size_t)l) * 8;
  };
  #pragma unroll
  for (int i = 0; i < 4; ++i) gload16(A[i], addr(i));
  if constexpr (NC > 1) {
    #pragma unroll
    for (int i = 0; i < 4; ++i) gload16(B[i], addr(4 + i));
  }
  f32x4 c = {0.f, 0.f, 0.f, 0.f};
  #pragma unroll
  for (int ch = 0; ch < NC; ++ch) {
    h8* cur = (ch & 1) ? B : A;
    if (ch < NC - 1) VWAIT4(); else VWAIT0();
    SBAR();
    #pragma unroll
    for (int i = 0; i < 4; ++i) {
      const int f = ch * 4 + i, ktl = f % KTC, kt = kt0 + ktl;
      const _Float16* xb = (KT > 8) ? ((kt < 8) ? xA + kt * 32 : xB + (kt - 8) * 32)
                                    : (xA + kt * 32);
      const h8 x = *(const h8*)(xb + lk * 8);
      c = __builtin_amdgcn_mfma_f32_16x16x32_f16(cur[i], x, c, 0, 0, 0);
      if (ktl == KTC - 1) {
        if (lr == 0) *((f32x4*)&pre[(mt0 + f / KTC) * 16 + lk * 4]) = c;
        c = (f32x4){0.f, 0.f, 0.f, 0.f};
      }
    }
    if (ch + 2 < NC) {
      #pragma unroll
      for (int i = 0; i < 4; ++i) gload16(cur[i], addr((ch + 2) * 4 + i));
    }
  }
}

// Quad partial-sum exchange: relaxed agent-scope atomics only (sc1/MALL path,
// no fences -> no L2 writeback/invalidate). Sum ALL 4 slots in fixed order so
// every replica computes bit-identical results.
__device__ __forceinline__ void xchg(float* base, unsigned* ctr, unsigned target,
                                     int q, int b, int n, float* s_pre, int tid) {
  unsigned* mine = (unsigned*)(base + ((size_t)q * NB + b) * n);
  for (int i = tid; i < n; i += 1024)
    __hip_atomic_store(mine + i, __float_as_uint(s_pre[i]), __ATOMIC_RELAXED, __HIP_MEMORY_SCOPE_AGENT);
  __syncthreads();                               // drains each wave's vmcnt before barrier
  if (tid == 0) {
    asm volatile("s_waitcnt vmcnt(0)" ::: "memory");
    __hip_atomic_fetch_add(ctr, 1u, __ATOMIC_RELAXED, __HIP_MEMORY_SCOPE_AGENT);
    while (__hip_atomic_load(ctr, __ATOMIC_RELAXED, __HIP_MEMORY_SCOPE_AGENT) < target)
      __builtin_amdgcn_s_sleep(1);
  }
  __syncthreads();
  for (int i = tid; i < n; i += 1024) {
    float s = 0.f;
    #pragma unroll
    for (int p = 0; p < 4; ++p) {
      unsigned* sp = (unsigned*)(base + ((size_t)p * NB + b) * n);
      s += __uint_as_float(__hip_atomic_load(sp + i, __ATOMIC_RELAXED, __HIP_MEMORY_SCOPE_AGENT));
    }
    s_pre[i] = s;
  }
  __syncthreads();
}

// ============== recurrent scan: QUAD of WGs per batch row (128 WGs total) ==============
// b = bid&31, q = bid>>5. B/D/E split K-wise 4-ways (partial sums exchanged via MALL);
// C/vproj/gates/F4 replicated; all state replicated bit-identically in each WG's LDS.
__global__ __launch_bounds__(1024, 4) void rnn10_kernel(
    const int* __restrict__ tokens, const int* __restrict__ scope_idx,
    const int* __restrict__ is_id, const int* __restrict__ umask,
    const int* __restrict__ lengths, const float* __restrict__ emb,
    const float* __restrict__ stb1, const float* __restrict__ stb2,
    const float* __restrict__ gateb, const float* __restrict__ valb,
    const float* __restrict__ h0, const float* __restrict__ c0,
    float* __restrict__ ws, float* __restrict__ out) {
  const int bid = blockIdx.x, tid = threadIdx.x;
  const int b = bid & 31, q = bid >> 5;
  const int len = lengths[b];
  const _Float16* hw = (const _Float16*)ws;
  const int w = tid >> 6, l = tid & 63;
  float* xb_slot = ws + F_XB;
  float* xd_slot = ws + F_XD;
  float* xe_slot = ws + F_XE;
  unsigned* ctrb = (unsigned*)(ws + F_CTR) + (0 * NB + b) * 16;
  unsigned* ctrd = (unsigned*)(ws + F_CTR) + (1 * NB + b) * 16;
  unsigned* ctre = (unsigned*)(ws + F_CTR) + (2 * NB + b) * 16;

  __shared__ __align__(16) _Float16 s_stkh[64][SPAD];
  __shared__ __align__(16) float    s_stk32[NS][NH];
  __shared__ __align__(16) float    s_pre[1024];
  __shared__ __align__(16) float    s_c[2][NH];
  __shared__ __align__(16) _Float16 s_h0h[2][NH], s_h1h[2][NH];
  __shared__ __align__(16) _Float16 s_embh[NH], s_z[NH], s_xin[NH];
  __shared__ __align__(16) float    s_vb[NH], s_b1[NH], s_b2[NH];
  __shared__ __align__(16) float    s_bc0[1024], s_bc1[1024];
  __shared__ __align__(16) _Float16 s_gw[512];
  __shared__ float s_gate[NS];
  __shared__ int   s_um[NS];
  __shared__ float s_gb;

  // ---- one-time init (replicated)
  for (int i = tid; i < 64 * SPAD; i += 1024) ((_Float16*)s_stkh)[i] = (_Float16)0.f;
  for (int i = tid; i < NS * NH; i += 1024) ((float*)s_stk32)[i] = 0.f;
  s_bc0[tid] = ws[F_BC0 + tid];
  s_bc1[tid] = ws[F_BC1 + tid];
  if (tid < NH) {
    s_h0h[0][tid] = (_Float16)h0[b * NH + tid];
    s_h1h[0][tid] = (_Float16)h0[NB * NH + b * NH + tid];
    s_c[0][tid] = c0[b * NH + tid];
    s_c[1][tid] = c0[NB * NH + b * NH + tid];
    s_vb[tid] = valb[tid]; s_b1[tid] = stb1[tid]; s_b2[tid] = stb2[tid];
  }
  if (tid < 64) ((h8*)s_gw)[tid] = ((const h8*)(hw + P_GW))[tid];
  if (tid == 0) s_gb = gateb[0];
  __syncthreads();

  unsigned epB = 0;

  for (int t = 0; t < len; ++t) {
    const int p0 = t & 1, p1 = p0 ^ 1;
    const int tok  = tokens[b * NT + t];
    const int sx   = scope_idx[b * NT + t];
    const int isid = is_id[b * NT + t];

    // ---- A: emb -> LDS f16, umask (replicated)
    if (tid < 64) {
      const float4 e = ((const float4*)(emb + (size_t)tok * NE))[tid];
      h4 v = { (_Float16)e.x, (_Float16)e.y, (_Float16)e.z, (_Float16)e.w };
      ((h4*)s_embh)[tid] = v;
    } else if (tid >= 64 && tid < 64 + NS) {
      s_um[tid - 64] = umask[((size_t)b * NT + t) * NS + (tid - 64)];
    }
    __syncthreads();

    if (isid) {
      // ---- B (K-split): partial z over kt [q*4, q*4+4)
      gemv_part<16, 1, 4>(hw + P_SW1, w, q * 4, &s_stkh[sx][0], s_embh, s_pre, l);
      __syncthreads();
      ++epB;
      xchg(xb_slot, ctrb, 4u * epB, q, b, 256, s_pre, tid);
      if (tid < 256) s_z[tid] = (_Float16)fmaxf(s_pre[tid] + s_b1[tid], 0.f);
      __syncthreads();
      // ---- C: full (replicated)
      gemv_pipe<8, 1>(hw + P_SW2, w, s_z, s_z, s_pre, l);
      __syncthreads();
      if (tid < 256) s_xin[tid] = (_Float16)(s_pre[tid] + s_b2[tid]);
      __syncthreads();
    } else {
      if (tid < 32) ((h8*)s_xin)[tid] = ((const h8*)s_embh)[tid];
      __syncthreads();
    }

    // ---- D (K-split): partial LSTM0 pre-acts, kt quarter
    gemv_part<16, 4, 4>(hw + P_W0, w * 4, q * 4, s_xin, s_h0h[p0], s_pre, l);
    __syncthreads();
    xchg(xd_slot, ctrd, 4u * (unsigned)(t + 1), q, b, 1024, s_pre, tid);
    if (tid < 256) {
      const int jc = tid;
      const float iv = s_pre[jc] + s_bc0[jc],        fv = s_pre[256 + jc] + s_bc0[256 + jc];
      const float gv = s_pre[512 + jc] + s_bc0[512 + jc], ov = s_pre[768 + jc] + s_bc0[768 + jc];
      const float c_ = sigm(fv) * s_c[0][jc] + sigm(iv) * tanh_f(gv);
      s_c[0][jc] = c_;
      s_h0h[p1][jc] = (_Float16)(sigm(ov) * tanh_f(c_));
    }
    __syncthreads();

    // ---- E (K-split): partial LSTM1 pre-acts
    gemv_part<16, 4, 4>(hw + P_W1, w * 4, q * 4, s_h0h[p1], s_h1h[p0], s_pre, l);
    __syncthreads();
    xchg(xe_slot, ctre, 4u * (unsigned)(t + 1), q, b, 1024, s_pre, tid);
    if (tid < 256) {
      const int jc = tid;
      const float iv = s_pre[jc] + s_bc1[jc],        fv = s_pre[256 + jc] + s_bc1[256 + jc];
      const float gv = s_pre[512 + jc] + s_bc1[512 + jc], ov = s_pre[768 + jc] + s_bc1[768 + jc];
      const float c_ = sigm(fv) * s_c[1][jc] + sigm(iv) * tanh_f(gv);
      s_c[1][jc] = c_;
      const float h_ = sigm(ov) * tanh_f(c_);
      s_h1h[p1][jc] = (_Float16)h_;
      if (q == 0) out[((size_t)b * NT + t) * NV + jc] = h_;   // feats (one writer)
    }
    __syncthreads();

    // ---- F: vproj (waves 0-7) + slot gates (waves 8-15)  (replicated)
    if (w < 8) {
      gemv_pipe<8, 2>(hw + P_VWO, w * 2, s_h1h[p1], s_h1h[p1], s_pre, l);
    } else {
      const int wp = w - 8;
      const h2* gs = (const h2*)s_gw;
      const h2* go = (const h2*)(s_gw + 256);
      const h2* oh = (const h2*)s_h1h[p1];
      float po = dot2f(go[2 * l], oh[2 * l], 0.f);
      po = dot2f(go[2 * l + 1], oh[2 * l + 1], po);
      for (int j = 0; j < 7; ++j) {
        const int s = wp + 8 * j;
        if (s < NS) {
          const h2* sr = (const h2*)s_stkh[s];
          float p = dot2f(gs[2 * l], sr[2 * l], po);
          p = dot2f(gs[2 * l + 1], sr[2 * l + 1], p);
          #pragma unroll
          for (int m = 1; m < 64; m <<= 1) p += __shfl_xor(p, m, 64);
          if (l == 0) s_gate[s] = (s_um[s] > 0) ? -1.f : sigm(p + s_gb);
        }
      }
    }
    __syncthreads();

    // ---- F4: stack GEMM (replicated; chunked dbuf pipeline, unchanged from r10)
    {
      const int st = w >> 2, rq = w & 3;
      const int s0 = st * 16, lr = l & 15, lk = l >> 4;
      const _Float16* baseB = hw + P_VWS + ((size_t)(rq * 4) * 8 * 64 + (size_t)l) * 8;
      h8 af[8];
      #pragma unroll
      for (int kt = 0; kt < 8; ++kt)
        af[kt] = *(const h8*)&s_stkh[s0 + lr][kt * 32 + lk * 8];
      __syncthreads();  // all A-frags in regs before any wave overwrites stack
      h8 A4[4], B4[4];
      #pragma unroll
      for (int i = 0; i < 4; ++i) gload16(A4[i], baseB + (size_t)i * 512);
      #pragma unroll
      for (int i = 0; i < 4; ++i) gload16(B4[i], baseB + (size_t)(4 + i) * 512);
      f32x4 c = {0.f, 0.f, 0.f, 0.f};
      #pragma unroll
      for (int ch = 0; ch < 8; ++ch) {
        h8* cur = (ch & 1) ? B4 : A4;
        if (ch < 7) VWAIT4(); else VWAIT0();
        SBAR();
        #pragma unroll
        for (int i = 0; i < 4; ++i) {
          const int f = ch * 4 + i, kt = f & 7;
          c = __builtin_amdgcn_mfma_f32_16x16x32_f16(af[kt], cur[i], c, 0, 0, 0);
          if (kt == 7) {
            const int rt = rq * 4 + (f >> 3);
            const int r = rt * 16 + lr;
            #pragma unroll
            for (int qq = 0; qq < 4; ++qq) {
              const int s = s0 + lk * 4 + qq;
              if (s < NS) {
                const float gv = s_gate[s];
                float nsv = 0.f;
                if (gv >= 0.f)
                  nsv = s_stk32[s][r] * (1.f - gv) + gv * tanh_f(c[qq] + s_pre[r] + s_vb[r]);
                s_stk32[s][r] = nsv;
                s_stkh[s][r]  = (_Float16)nsv;
              }
            }
            c = (f32x4){0.f, 0.f, 0.f, 0.f};
          }
        }
        if (ch + 2 < 8) {
          #pragma unroll
          for (int i = 0; i < 4; ++i) gload16(cur[i], baseB + (size_t)((ch + 2) * 4 + i) * 512);
        }
      }
    }
    __syncthreads();
  }
}

// ===================== logits epilogue (feats live in out[b][t][0:256]) =====================
constexpr int TBR = 32;
__global__ __launch_bounds__(256) void logits_kernel(
    const float* __restrict__ w1, const float* __restrict__ b1,
    const float* __restrict__ w2, const float* __restrict__ b2,
    const int* __restrict__ lengths, float* __restrict__ out) {
  const int blk = blockIdx.x;
  const int b = blk >> 4;
  const int t0 = (blk & 15) * TBR;
  const int tid = threadIdx.x;
  const int len = lengths[b];
  __shared__ __align__(16) float s_fe[TBR][NH];
  __shared__ __align__(16) float s_hid[TBR][NH];

  for (int r = 0; r < TBR; ++r) {
    const int t = t0 + r;
    s_fe[r][tid] = (t < len) ? out[((size_t)b * NT + t) * NV + tid] : 0.f;
  }
  __syncthreads();
  for (int r = 0; r < TBR; ++r) {
    float acc = b1[tid];
    const float4* fr = (const float4*)s_fe[r];
    const float4* wr = (const float4*)(w1 + (size_t)tid * NH);
    #pragma unroll 8
    for (int k = 0; k < NH / 4; ++k) { float4 wv = wr[k]; float4 fv = fr[k]; FMA4(acc, wv, fv); }
    s_hid[r][tid] = fmaxf(acc, 0.f);
  }
  __syncthreads();
  for (int r = 0; r < TBR; ++r) {
    const int t = t0 + r;
    if (t >= len) {
      float4* orow = (float4*)(out + ((size_t)b * NT + t) * NV);
      const float4 m1 = make_float4(-1.f, -1.f, -1.f, -1.f);
      for (int i = tid; i < NV / 4; i += 256) orow[i] = m1;
    }
  }
  if (t0 >= len) return;
  for (int pass = 0; pass < (NV + 511) / 512; ++pass) {
    const int v0 = pass * 512 + tid * 2;
    if (v0 >= NV) continue;
    float acc0[TBR], acc1[TBR];
    #pragma unroll
    for (int r = 0; r < TBR; ++r) { acc0[r] = 0.f; acc1[r] = 0.f; }
    const float4* wa = (const float4*)(w2 + (size_t)v0 * NH);
    const float4* wb = (const float4*)(w2 + (size_t)(v0 + 1) * NH);
    for (int k = 0; k < NH / 4; ++k) {
      const float4 w0 = wa[k], w1v = wb[k];
      #pragma unroll
      for (int r = 0; r < TBR; ++r) {
        const float4 hx = *(const float4*)&s_hid[r][k * 4];
        acc0[r] += w0.x * hx.x + w0.y * hx.y + w0.z * hx.z + w0.w * hx.w;
        acc1[r] += w1v.x * hx.x + w1v.y * hx.y + w1v.z * hx.z + w1v.w * hx.w;
      }
    }
    const float bb0 = b2[v0], bb1 = b2[v0 + 1];
    for (int r = 0; r < TBR; ++r) {
      const int t = t0 + r;
      if (t < len) {
        float2 st = make_float2(acc0[r] + bb0, acc1[r] + bb1);
        *(float2*)(out + ((size_t)b * NT + t) * NV + v0) = st;
      }
    }
  }
}

extern "C" void kernel_launch(void* const* d_in, const int* in_sizes, int n_in,
                              void* d_out, int out_size, void* d_ws, size_t ws_size,
                              hipStream_t stream) {
  (void)in_sizes; (void)n_in; (void)out_size; (void)ws_size;
  const int* tokens    = (const int*)d_in[0];
  const int* scope_idx = (const int*)d_in[1];
  const int* is_id     = (const int*)d_in[2];
  const int* umask     = (const int*)d_in[3];
  const int* lengths   = (const int*)d_in[4];
  const float* emb   = (const float*)d_in[5];
  const float* wih0  = (const float*)d_in[6];  const float* whh0 = (const float*)d_in[7];
  const float* bih0  = (const float*)d_in[8];  const float* bhh0 = (const float*)d_in[9];
  const float* wih1  = (const float*)d_in[10]; const float* whh1 = (const float*)d_in[11];
  const float* bih1  = (const float*)d_in[12]; const float* bhh1 = (const float*)d_in[13];
  const float* stw1  = (const float*)d_in[14]; const float* stb1 = (const float*)d_in[15];
  const float* stw2  = (const float*)d_in[16]; const float* stb2 = (const float*)d_in[17];
  const float* gatew = (const float*)d_in[18]; const float* gateb = (const float*)d_in[19];
  const float* valw  = (const float*)d_in[20]; const float* valb  = (const float*)d_in[21];
  const float* outw1 = (const float*)d_in[22]; const float* outb1 = (const float*)d_in[23];
  const float* outw2 = (const float*)d_in[24]; const float* outb2 = (const float*)d_in[25];
  const float* h0 = (const float*)d_in[26];
  const float* c0 = (const float*)d_in[27];
  float* ws = (float*)d_ws;
  float* out = (float*)d_out;

  // reset quad-sync counters (each launch; graph replay includes this)
  (void)hipMemsetAsync(ws + F_CTR, 0, 3 * NB * 16 * 4, stream);

  prep_kernel<<<dim3(256), dim3(256), 0, stream>>>(
      wih0, whh0, bih0, bhh0, wih1, whh1, bih1, bhh1, stw1, stw2, valw, gatew, ws);

  rnn10_kernel<<<dim3(128), dim3(1024), 0, stream>>>(
      tokens, scope_idx, is_id, umask, lengths, emb,
      stb1, stb2, gateb, valb, h0, c0, ws, out);

  logits_kernel<<<dim3(NB * 16), dim3(256), 0, stream>>>(
      outw1, outb1, outw2, outb2, lengths, out);
}

// Round 12
// 23239.719 us; speedup vs baseline: 3.8607x; 1.0113x over previous
//
#include <hip/hip_runtime.h>
#include <math.h>

// Problem constants
constexpr int NB = 32, NT = 512, NH = 256, NE = 256, NS = 50, NV = 10000;
constexpr int SPAD = 264;   // padded stack row (f16 elems)

typedef _Float16 h2 __attribute__((ext_vector_type(2)));
typedef _Float16 h4 __attribute__((ext_vector_type(4)));
typedef _Float16 h8 __attribute__((ext_vector_type(8)));
typedef float f32x4 __attribute__((ext_vector_type(4)));

#define FMA4(acc, Wv, Xv) acc += (Wv).x*(Xv).x + (Wv).y*(Xv).y + (Wv).z*(Xv).z + (Wv).w*(Xv).w

#if __has_builtin(__builtin_amdgcn_fdot2)
__device__ __forceinline__ float dot2f(h2 a, h2 b, float c) { return __builtin_amdgcn_fdot2(a, b, c, false); }
#else
__device__ __forceinline__ float dot2f(h2 a, h2 b, float c) { return c + (float)a[0]*(float)b[0] + (float)a[1]*(float)b[1]; }
#endif
__device__ __forceinline__ float sigm(float x) { return 1.f / (1.f + __expf(-x)); }
__device__ __forceinline__ float tanh_f(float x) { const float e = __expf(2.f * x); return 1.f - 2.f / (e + 1.f); }

// ---- asm pipelined load primitives (r9 rules: consume-before-reissue, counted waits) ----
__device__ __forceinline__ void gload16(h8& d, const _Float16* p) {
  asm volatile("global_load_dwordx4 %0, %1, off" : "=&v"(d) : "v"(p));
}
#define VWAIT4() asm volatile("s_waitcnt vmcnt(4)" ::: "memory")
#define VWAIT0() asm volatile("s_waitcnt vmcnt(0)" ::: "memory")
#define SBAR()   __builtin_amdgcn_sched_barrier(0)

// ---- packed (MFMA-fragment-order) f16 arenas in d_ws; offsets in halves ----
constexpr size_t P_W0  = 0;         // M=1024 K=512 rows=[wih0|whh0], row=g*256+cell
constexpr size_t P_W1  = 524288;    // M=1024 K=512
constexpr size_t P_SW1 = 1048576;   // M=256  K=512
constexpr size_t P_SW2 = 1179648;   // M=256  K=256
constexpr size_t P_VWO = 1245184;   // M=256  K=256  val_w out part
constexpr size_t P_VWS = 1310720;   // M=256  K=256  val_w stack part
constexpr size_t P_GW  = 1376256;   // [512] linear
constexpr size_t H_TOTAL = 1376768;
constexpr size_t F_BC0 = H_TOTAL / 2;    // [1024] fp32
constexpr size_t F_BC1 = F_BC0 + 1024;   // [1024]
// quad-exchange slots (fp32, MALL-only traffic) + counters
constexpr size_t F_XB  = F_BC1 + 1024;   // [4][32][256]
constexpr size_t F_XD  = F_XB + 32768;   // [4][32][1024]
constexpr size_t F_XE  = F_XD + 131072;  // [4][32][1024]
constexpr size_t F_CTR = F_XE + 131072;  // u32 counters, 16-float stride per (phase,b)

// ===================== prologue: fragment-pack weights (unchanged, proven) ================
__global__ __launch_bounds__(256) void prep_kernel(
    const float* wih0, const float* whh0, const float* bih0, const float* bhh0,
    const float* wih1, const float* whh1, const float* bih1, const float* bhh1,
    const float* stw1, const float* stw2, const float* valw, const float* gatew,
    float* ws) {
  _Float16* hw = (_Float16*)ws;
  const int gt = blockIdx.x * blockDim.x + threadIdx.x;
  const int np = gridDim.x * blockDim.x;

  auto pack = [&](size_t off, int M, int K, auto src) {
    const int KT = K / 32;
    for (int i = gt; i < M * K; i += np) {
      const int j = i & 7, l = (i >> 3) & 63, rem = i >> 9;
      const int kt = rem % KT, mt = rem / KT;
      const int row = mt * 16 + (l & 15), col = kt * 32 + (l >> 4) * 8 + j;
      hw[off + i] = (_Float16)src(row, col);
    }
  };
  pack(P_W0, 1024, 512, [&](int r, int c) { return c < 256 ? wih0[(size_t)r * 256 + c] : whh0[(size_t)r * 256 + c - 256]; });
  pack(P_W1, 1024, 512, [&](int r, int c) { return c < 256 ? wih1[(size_t)r * 256 + c] : whh1[(size_t)r * 256 + c - 256]; });
  pack(P_SW1, 256, 512, [&](int r, int c) { return stw1[(size_t)r * 512 + c]; });
  pack(P_SW2, 256, 256, [&](int r, int c) { return stw2[(size_t)r * 256 + c]; });
  pack(P_VWO, 256, 256, [&](int r, int c) { return valw[(size_t)r * 512 + 256 + c]; });
  pack(P_VWS, 256, 256, [&](int r, int c) { return valw[(size_t)r * 512 + c]; });
  for (int i = gt; i < 512; i += np) hw[P_GW + i] = (_Float16)gatew[i];
  for (int i = gt; i < 1024; i += np) {
    ws[F_BC0 + i] = bih0[i] + bhh0[i];
    ws[F_BC1 + i] = bih1[i] + bhh1[i];
  }
}

// Full-K GEMV pipeline (proven)
template <int KT, int NMT>
__device__ __forceinline__ void gemv_pipe(const _Float16* __restrict__ wp, int mt0,
                                          const _Float16* __restrict__ xA,
                                          const _Float16* __restrict__ xB,
                                          float* __restrict__ pre, int l) {
  const int lr = l & 15, lk = l >> 4;
  constexpr int TOT = KT * NMT;
  constexpr int NC  = TOT / 4;
  const _Float16* base = wp + ((size_t)mt0 * KT * 64 + (size_t)l) * 8;
  h8 A[4], B[4];
  #pragma unroll
  for (int i = 0; i < 4; ++i) gload16(A[i], base + (size_t)i * 512);
  if constexpr (NC > 1) {
    #pragma unroll
    for (int i = 0; i < 4; ++i) gload16(B[i], base + (size_t)(4 + i) * 512);
  }
  f32x4 c = {0.f, 0.f, 0.f, 0.f};
  #pragma unroll
  for (int ch = 0; ch < NC; ++ch) {
    h8* cur = (ch & 1) ? B : A;
    if (ch < NC - 1) VWAIT4(); else VWAIT0();
    SBAR();
    #pragma unroll
    for (int i = 0; i < 4; ++i) {
      const int f = ch * 4 + i;
      const int kt = f % KT;
      const _Float16* xb = (KT > 8) ? ((kt < 8) ? xA + kt * 32 : xB + (kt - 8) * 32)
                                    : (xA + kt * 32);
      const h8 x = *(const h8*)(xb + lk * 8);
      c = __builtin_amdgcn_mfma_f32_16x16x32_f16(cur[i], x, c, 0, 0, 0);
      if (kt == KT - 1) {
        if (lr == 0) *((f32x4*)&pre[(mt0 + f / KT) * 16 + lk * 4]) = c;
        c = (f32x4){0.f, 0.f, 0.f, 0.f};
      }
    }
    if (ch + 2 < NC) {
      #pragma unroll
      for (int i = 0; i < 4; ++i) gload16(cur[i], base + (size_t)((ch + 2) * 4 + i) * 512);
    }
  }
}

// Partial-K GEMV: frags mt in [mt0,mt0+NMT), kt in [kt0,kt0+KTC). Writes PARTIAL sums.
template <int KT, int NMT, int KTC>
__device__ __forceinline__ void gemv_part(const _Float16* __restrict__ wp, int mt0, int kt0,
                                          const _Float16* __restrict__ xA,
                                          const _Float16* __restrict__ xB,
                                          float* __restrict__ pre, int l) {
  const int lr = l & 15, lk = l >> 4;
  constexpr int TOT = NMT * KTC;      // 4 or 16
  constexpr int NC  = TOT / 4;
  h8 A[4], B[4];
  auto addr = [&](int f) {
    const int mt = mt0 + f / KTC, kt = kt0 + f % KTC;
    return wp + ((size_t)(mt * KT + kt) * 64 + (size_t)l) * 8;
  };
  #pragma unroll
  for (int i = 0; i < 4; ++i) gload16(A[i], addr(i));
  if constexpr (NC > 1) {
    #pragma unroll
    for (int i = 0; i < 4; ++i) gload16(B[i], addr(4 + i));
  }
  f32x4 c = {0.f, 0.f, 0.f, 0.f};
  #pragma unroll
  for (int ch = 0; ch < NC; ++ch) {
    h8* cur = (ch & 1) ? B : A;
    if (ch < NC - 1) VWAIT4(); else VWAIT0();
    SBAR();
    #pragma unroll
    for (int i = 0; i < 4; ++i) {
      const int f = ch * 4 + i, ktl = f % KTC, kt = kt0 + ktl;
      const _Float16* xb = (KT > 8) ? ((kt < 8) ? xA + kt * 32 : xB + (kt - 8) * 32)
                                    : (xA + kt * 32);
      const h8 x = *(const h8*)(xb + lk * 8);
      c = __builtin_amdgcn_mfma_f32_16x16x32_f16(cur[i], x, c, 0, 0, 0);
      if (ktl == KTC - 1) {
        if (lr == 0) *((f32x4*)&pre[(mt0 + f / KTC) * 16 + lk * 4]) = c;
        c = (f32x4){0.f, 0.f, 0.f, 0.f};
      }
    }
    if (ch + 2 < NC) {
      #pragma unroll
      for (int i = 0; i < 4; ++i) gload16(cur[i], addr((ch + 2) * 4 + i));
    }
  }
}

// Quad partial-sum exchange: relaxed agent-scope atomics only (no fences -> no L2
// writeback/invalidate). Sum ALL 4 slots in fixed order -> bit-identical replicas.
__device__ __forceinline__ void xchg(float* base, unsigned* ctr, unsigned target,
                                     int q, int b, int n, float* s_pre, int tid) {
  unsigned* mine = (unsigned*)(base + ((size_t)q * NB + b) * n);
  for (int i = tid; i < n; i += 1024)
    __hip_atomic_store(mine + i, __float_as_uint(s_pre[i]), __ATOMIC_RELAXED, __HIP_MEMORY_SCOPE_AGENT);
  __syncthreads();                               // drains each wave's vmcnt before barrier
  if (tid == 0) {
    asm volatile("s_waitcnt vmcnt(0)" ::: "memory");
    __hip_atomic_fetch_add(ctr, 1u, __ATOMIC_RELAXED, __HIP_MEMORY_SCOPE_AGENT);
    while (__hip_atomic_load(ctr, __ATOMIC_RELAXED, __HIP_MEMORY_SCOPE_AGENT) < target)
      __builtin_amdgcn_s_sleep(1);
  }
  __syncthreads();
  for (int i = tid; i < n; i += 1024) {
    float s = 0.f;
    #pragma unroll
    for (int p = 0; p < 4; ++p) {
      unsigned* sp = (unsigned*)(base + ((size_t)p * NB + b) * n);
      s += __uint_as_float(__hip_atomic_load(sp + i, __ATOMIC_RELAXED, __HIP_MEMORY_SCOPE_AGENT));
    }
    s_pre[i] = s;
  }
  __syncthreads();
}

// ============== recurrent scan: QUAD of WGs per batch row (128 WGs total) ==============
// XCD-ALIGNED mapping (r12): b = bid>>2, q = bid&3. With round-robin bid%8 -> XCD,
// quad members land on 4 consecutive XCDs and each XCD serves exactly ONE q-quarter
// of the split arenas -> per-XCD L2 footprint ~0.94 MB (fits 4 MB) -> no thrash.
__global__ __launch_bounds__(1024, 4) void rnn11_kernel(
    const int* __restrict__ tokens, const int* __restrict__ scope_idx,
    const int* __restrict__ is_id, const int* __restrict__ umask,
    const int* __restrict__ lengths, const float* __restrict__ emb,
    const float* __restrict__ stb1, const float* __restrict__ stb2,
    const float* __restrict__ gateb, const float* __restrict__ valb,
    const float* __restrict__ h0, const float* __restrict__ c0,
    float* __restrict__ ws, float* __restrict__ out) {
  const int bid = blockIdx.x, tid = threadIdx.x;
  const int b = bid >> 2, q = bid & 3;   // XCD-aligned quad mapping
  const int len = lengths[b];
  const _Float16* hw = (const _Float16*)ws;
  const int w = tid >> 6, l = tid & 63;
  float* xb_slot = ws + F_XB;
  float* xd_slot = ws + F_XD;
  float* xe_slot = ws + F_XE;
  unsigned* ctrb = (unsigned*)(ws + F_CTR) + (0 * NB + b) * 16;
  unsigned* ctrd = (unsigned*)(ws + F_CTR) + (1 * NB + b) * 16;
  unsigned* ctre = (unsigned*)(ws + F_CTR) + (2 * NB + b) * 16;

  __shared__ __align__(16) _Float16 s_stkh[64][SPAD];
  __shared__ __align__(16) float    s_stk32[NS][NH];
  __shared__ __align__(16) float    s_pre[1024];
  __shared__ __align__(16) float    s_c[2][NH];
  __shared__ __align__(16) _Float16 s_h0h[2][NH], s_h1h[2][NH];
  __shared__ __align__(16) _Float16 s_embh[NH], s_z[NH], s_xin[NH];
  __shared__ __align__(16) float    s_vb[NH], s_b1[NH], s_b2[NH];
  __shared__ __align__(16) float    s_bc0[1024], s_bc1[1024];
  __shared__ __align__(16) _Float16 s_gw[512];
  __shared__ float s_gate[NS];
  __shared__ int   s_um[NS];
  __shared__ float s_gb;

  // ---- one-time init (replicated)
  for (int i = tid; i < 64 * SPAD; i += 1024) ((_Float16*)s_stkh)[i] = (_Float16)0.f;
  for (int i = tid; i < NS * NH; i += 1024) ((float*)s_stk32)[i] = 0.f;
  s_bc0[tid] = ws[F_BC0 + tid];
  s_bc1[tid] = ws[F_BC1 + tid];
  if (tid < NH) {
    s_h0h[0][tid] = (_Float16)h0[b * NH + tid];
    s_h1h[0][tid] = (_Float16)h0[NB * NH + b * NH + tid];
    s_c[0][tid] = c0[b * NH + tid];
    s_c[1][tid] = c0[NB * NH + b * NH + tid];
    s_vb[tid] = valb[tid]; s_b1[tid] = stb1[tid]; s_b2[tid] = stb2[tid];
  }
  if (tid < 64) ((h8*)s_gw)[tid] = ((const h8*)(hw + P_GW))[tid];
  if (tid == 0) s_gb = gateb[0];
  __syncthreads();

  unsigned epB = 0;

  for (int t = 0; t < len; ++t) {
    const int p0 = t & 1, p1 = p0 ^ 1;
    const int tok  = tokens[b * NT + t];
    const int sx   = scope_idx[b * NT + t];
    const int isid = is_id[b * NT + t];

    // ---- A: emb -> LDS f16, umask (replicated)
    if (tid < 64) {
      const float4 e = ((const float4*)(emb + (size_t)tok * NE))[tid];
      h4 v = { (_Float16)e.x, (_Float16)e.y, (_Float16)e.z, (_Float16)e.w };
      ((h4*)s_embh)[tid] = v;
    } else if (tid >= 64 && tid < 64 + NS) {
      s_um[tid - 64] = umask[((size_t)b * NT + t) * NS + (tid - 64)];
    }
    __syncthreads();

    if (isid) {
      // ---- B (K-split): partial z over kt [q*4, q*4+4)
      gemv_part<16, 1, 4>(hw + P_SW1, w, q * 4, &s_stkh[sx][0], s_embh, s_pre, l);
      __syncthreads();
      ++epB;
      xchg(xb_slot, ctrb, 4u * epB, q, b, 256, s_pre, tid);
      if (tid < 256) s_z[tid] = (_Float16)fmaxf(s_pre[tid] + s_b1[tid], 0.f);
      __syncthreads();
      // ---- C: full (replicated)
      gemv_pipe<8, 1>(hw + P_SW2, w, s_z, s_z, s_pre, l);
      __syncthreads();
      if (tid < 256) s_xin[tid] = (_Float16)(s_pre[tid] + s_b2[tid]);
      __syncthreads();
    } else {
      if (tid < 32) ((h8*)s_xin)[tid] = ((const h8*)s_embh)[tid];
      __syncthreads();
    }

    // ---- D (K-split): partial LSTM0 pre-acts, kt quarter
    gemv_part<16, 4, 4>(hw + P_W0, w * 4, q * 4, s_xin, s_h0h[p0], s_pre, l);
    __syncthreads();
    xchg(xd_slot, ctrd, 4u * (unsigned)(t + 1), q, b, 1024, s_pre, tid);
    if (tid < 256) {
      const int jc = tid;
      const float iv = s_pre[jc] + s_bc0[jc],        fv = s_pre[256 + jc] + s_bc0[256 + jc];
      const float gv = s_pre[512 + jc] + s_bc0[512 + jc], ov = s_pre[768 + jc] + s_bc0[768 + jc];
      const float c_ = sigm(fv) * s_c[0][jc] + sigm(iv) * tanh_f(gv);
      s_c[0][jc] = c_;
      s_h0h[p1][jc] = (_Float16)(sigm(ov) * tanh_f(c_));
    }
    __syncthreads();

    // ---- E (K-split): partial LSTM1 pre-acts
    gemv_part<16, 4, 4>(hw + P_W1, w * 4, q * 4, s_h0h[p1], s_h1h[p0], s_pre, l);
    __syncthreads();
    xchg(xe_slot, ctre, 4u * (unsigned)(t + 1), q, b, 1024, s_pre, tid);
    if (tid < 256) {
      const int jc = tid;
      const float iv = s_pre[jc] + s_bc1[jc],        fv = s_pre[256 + jc] + s_bc1[256 + jc];
      const float gv = s_pre[512 + jc] + s_bc1[512 + jc], ov = s_pre[768 + jc] + s_bc1[768 + jc];
      const float c_ = sigm(fv) * s_c[1][jc] + sigm(iv) * tanh_f(gv);
      s_c[1][jc] = c_;
      const float h_ = sigm(ov) * tanh_f(c_);
      s_h1h[p1][jc] = (_Float16)h_;
      if (q == 0) out[((size_t)b * NT + t) * NV + jc] = h_;   // feats (one writer)
    }
    __syncthreads();

    // ---- F: vproj (waves 0-7) + slot gates (waves 8-15)  (replicated)
    if (w < 8) {
      gemv_pipe<8, 2>(hw + P_VWO, w * 2, s_h1h[p1], s_h1h[p1], s_pre, l);
    } else {
      const int wp = w - 8;
      const h2* gs = (const h2*)s_gw;
      const h2* go = (const h2*)(s_gw + 256);
      const h2* oh = (const h2*)s_h1h[p1];
      float po = dot2f(go[2 * l], oh[2 * l], 0.f);
      po = dot2f(go[2 * l + 1], oh[2 * l + 1], po);
      for (int j = 0; j < 7; ++j) {
        const int s = wp + 8 * j;
        if (s < NS) {
          const h2* sr = (const h2*)s_stkh[s];
          float p = dot2f(gs[2 * l], sr[2 * l], po);
          p = dot2f(gs[2 * l + 1], sr[2 * l + 1], p);
          #pragma unroll
          for (int m = 1; m < 64; m <<= 1) p += __shfl_xor(p, m, 64);
          if (l == 0) s_gate[s] = (s_um[s] > 0) ? -1.f : sigm(p + s_gb);
        }
      }
    }
    __syncthreads();

    // ---- F4: stack GEMM (replicated; chunked dbuf pipeline, proven)
    {
      const int st = w >> 2, rq = w & 3;
      const int s0 = st * 16, lr = l & 15, lk = l >> 4;
      const _Float16* baseB = hw + P_VWS + ((size_t)(rq * 4) * 8 * 64 + (size_t)l) * 8;
      h8 af[8];
      #pragma unroll
      for (int kt = 0; kt < 8; ++kt)
        af[kt] = *(const h8*)&s_stkh[s0 + lr][kt * 32 + lk * 8];
      __syncthreads();  // all A-frags in regs before any wave overwrites stack
      h8 A4[4], B4[4];
      #pragma unroll
      for (int i = 0; i < 4; ++i) gload16(A4[i], baseB + (size_t)i * 512);
      #pragma unroll
      for (int i = 0; i < 4; ++i) gload16(B4[i], baseB + (size_t)(4 + i) * 512);
      f32x4 c = {0.f, 0.f, 0.f, 0.f};
      #pragma unroll
      for (int ch = 0; ch < 8; ++ch) {
        h8* cur = (ch & 1) ? B4 : A4;
        if (ch < 7) VWAIT4(); else VWAIT0();
        SBAR();
        #pragma unroll
        for (int i = 0; i < 4; ++i) {
          const int f = ch * 4 + i, kt = f & 7;
          c = __builtin_amdgcn_mfma_f32_16x16x32_f16(af[kt], cur[i], c, 0, 0, 0);
          if (kt == 7) {
            const int rt = rq * 4 + (f >> 3);
            const int r = rt * 16 + lr;
            #pragma unroll
            for (int qq = 0; qq < 4; ++qq) {
              const int s = s0 + lk * 4 + qq;
              if (s < NS) {
                const float gv = s_gate[s];
                float nsv = 0.f;
                if (gv >= 0.f)
                  nsv = s_stk32[s][r] * (1.f - gv) + gv * tanh_f(c[qq] + s_pre[r] + s_vb[r]);
                s_stk32[s][r] = nsv;
                s_stkh[s][r]  = (_Float16)nsv;
              }
            }
            c = (f32x4){0.f, 0.f, 0.f, 0.f};
          }
        }
        if (ch + 2 < 8) {
          #pragma unroll
          for (int i = 0; i < 4; ++i) gload16(cur[i], baseB + (size_t)((ch + 2) * 4 + i) * 512);
        }
      }
    }
    __syncthreads();
  }
}

// ===================== logits epilogue (feats live in out[b][t][0:256]) =====================
constexpr int TBR = 32;
__global__ __launch_bounds__(256) void logits_kernel(
    const float* __restrict__ w1, const float* __restrict__ b1,
    const float* __restrict__ w2, const float* __restrict__ b2,
    const int* __restrict__ lengths, float* __restrict__ out) {
  const int blk = blockIdx.x;
  const int b = blk >> 4;
  const int t0 = (blk & 15) * TBR;
  const int tid = threadIdx.x;
  const int len = lengths[b];
  __shared__ __align__(16) float s_fe[TBR][NH];
  __shared__ __align__(16) float s_hid[TBR][NH];

  for (int r = 0; r < TBR; ++r) {
    const int t = t0 + r;
    s_fe[r][tid] = (t < len) ? out[((size_t)b * NT + t) * NV + tid] : 0.f;
  }
  __syncthreads();
  for (int r = 0; r < TBR; ++r) {
    float acc = b1[tid];
    const float4* fr = (const float4*)s_fe[r];
    const float4* wr = (const float4*)(w1 + (size_t)tid * NH);
    #pragma unroll 8
    for (int k = 0; k < NH / 4; ++k) { float4 wv = wr[k]; float4 fv = fr[k]; FMA4(acc, wv, fv); }
    s_hid[r][tid] = fmaxf(acc, 0.f);
  }
  __syncthreads();
  for (int r = 0; r < TBR; ++r) {
    const int t = t0 + r;
    if (t >= len) {
      float4* orow = (float4*)(out + ((size_t)b * NT + t) * NV);
      const float4 m1 = make_float4(-1.f, -1.f, -1.f, -1.f);
      for (int i = tid; i < NV / 4; i += 256) orow[i] = m1;
    }
  }
  if (t0 >= len) return;
  for (int pass = 0; pass < (NV + 511) / 512; ++pass) {
    const int v0 = pass * 512 + tid * 2;
    if (v0 >= NV) continue;
    float acc0[TBR], acc1[TBR];
    #pragma unroll
    for (int r = 0; r < TBR; ++r) { acc0[r] = 0.f; acc1[r] = 0.f; }
    const float4* wa = (const float4*)(w2 + (size_t)v0 * NH);
    const float4* wb = (const float4*)(w2 + (size_t)(v0 + 1) * NH);
    for (int k = 0; k < NH / 4; ++k) {
      const float4 w0 = wa[k], w1v = wb[k];
      #pragma unroll
      for (int r = 0; r < TBR; ++r) {
        const float4 hx = *(const float4*)&s_hid[r][k * 4];
        acc0[r] += w0.x * hx.x + w0.y * hx.y + w0.z * hx.z + w0.w * hx.w;
        acc1[r] += w1v.x * hx.x + w1v.y * hx.y + w1v.z * hx.z + w1v.w * hx.w;
      }
    }
    const float bb0 = b2[v0], bb1 = b2[v0 + 1];
    for (int r = 0; r < TBR; ++r) {
      const int t = t0 + r;
      if (t < len) {
        float2 st = make_float2(acc0[r] + bb0, acc1[r] + bb1);
        *(float2*)(out + ((size_t)b * NT + t) * NV + v0) = st;
      }
    }
  }
}

extern "C" void kernel_launch(void* const* d_in, const int* in_sizes, int n_in,
                              void* d_out, int out_size, void* d_ws, size_t ws_size,
                              hipStream_t stream) {
  (void)in_sizes; (void)n_in; (void)out_size; (void)ws_size;
  const int* tokens    = (const int*)d_in[0];
  const int* scope_idx = (const int*)d_in[1];
  const int* is_id     = (const int*)d_in[2];
  const int* umask     = (const int*)d_in[3];
  const int* lengths   = (const int*)d_in[4];
  const float* emb   = (const float*)d_in[5];
  const float* wih0  = (const float*)d_in[6];  const float* whh0 = (const float*)d_in[7];
  const float* bih0  = (const float*)d_in[8];  const float* bhh0 = (const float*)d_in[9];
  const float* wih1  = (const float*)d_in[10]; const float* whh1 = (const float*)d_in[11];
  const float* bih1  = (const float*)d_in[12]; const float* bhh1 = (const float*)d_in[13];
  const float* stw1  = (const float*)d_in[14]; const float* stb1 = (const float*)d_in[15];
  const float* stw2  = (const float*)d_in[16]; const float* stb2 = (const float*)d_in[17];
  const float* gatew = (const float*)d_in[18]; const float* gateb = (const float*)d_in[19];
  const float* valw  = (const float*)d_in[20]; const float* valb  = (const float*)d_in[21];
  const float* outw1 = (const float*)d_in[22]; const float* outb1 = (const float*)d_in[23];
  const float* outw2 = (const float*)d_in[24]; const float* outb2 = (const float*)d_in[25];
  const float* h0 = (const float*)d_in[26];
  const float* c0 = (const float*)d_in[27];
  float* ws = (float*)d_ws;
  float* out = (float*)d_out;

  // reset quad-sync counters (each launch; graph replay includes this)
  (void)hipMemsetAsync(ws + F_CTR, 0, 3 * NB * 16 * 4, stream);

  prep_kernel<<<dim3(256), dim3(256), 0, stream>>>(
      wih0, whh0, bih0, bhh0, wih1, whh1, bih1, bhh1, stw1, stw2, valw, gatew, ws);

  rnn11_kernel<<<dim3(128), dim3(1024), 0, stream>>>(
      tokens, scope_idx, is_id, umask, lengths, emb,
      stb1, stb2, gateb, valb, h0, c0, ws, out);

  logits_kernel<<<dim3(NB * 16), dim3(256), 0, stream>>>(
      outw1, outb1, outw2, outb2, lengths, out);
}

// Round 13
// 17118.135 us; speedup vs baseline: 5.2414x; 1.3576x over previous
//
#include <hip/hip_runtime.h>
#include <math.h>

// Problem constants
constexpr int NB = 32, NT = 512, NH = 256, NE = 256, NS = 50, NV = 10000;
constexpr int SPAD = 264;   // padded stack row (f16 elems)

typedef _Float16 h2 __attribute__((ext_vector_type(2)));
typedef _Float16 h4 __attribute__((ext_vector_type(4)));
typedef _Float16 h8 __attribute__((ext_vector_type(8)));
typedef float f32x4 __attribute__((ext_vector_type(4)));

#define FMA4(acc, Wv, Xv) acc += (Wv).x*(Xv).x + (Wv).y*(Xv).y + (Wv).z*(Xv).z + (Wv).w*(Xv).w

#if __has_builtin(__builtin_amdgcn_fdot2)
__device__ __forceinline__ float dot2f(h2 a, h2 b, float c) { return __builtin_amdgcn_fdot2(a, b, c, false); }
#else
__device__ __forceinline__ float dot2f(h2 a, h2 b, float c) { return c + (float)a[0]*(float)b[0] + (float)a[1]*(float)b[1]; }
#endif
__device__ __forceinline__ float sigm(float x) { return 1.f / (1.f + __expf(-x)); }
__device__ __forceinline__ float tanh_f(float x) { const float e = __expf(2.f * x); return 1.f - 2.f / (e + 1.f); }

// ---- asm pipelined load primitives (r9 rules: consume-before-reissue, counted waits) ----
__device__ __forceinline__ void gload16(h8& d, const _Float16* p) {
  asm volatile("global_load_dwordx4 %0, %1, off" : "=&v"(d) : "v"(p));
}
#define VWAIT4() asm volatile("s_waitcnt vmcnt(4)" ::: "memory")
#define VWAIT0() asm volatile("s_waitcnt vmcnt(0)" ::: "memory")
#define SBAR()   __builtin_amdgcn_sched_barrier(0)

// ---- packed (MFMA-fragment-order) f16 arenas in d_ws; offsets in halves ----
// W0/W1 rows are PERMUTED so quad q owns all 4 gates of cells [q*64, q*64+64):
//   packed row r -> original row g*256 + q*64 + jcl, with q=r>>8, g=(r>>6)&3, jcl=r&63.
constexpr size_t P_W0  = 0;         // M=1024 K=512 (permuted rows)
constexpr size_t P_W1  = 524288;    // M=1024 K=512 (permuted rows)
constexpr size_t P_SW1 = 1048576;   // M=256  K=512
constexpr size_t P_SW2 = 1179648;   // M=256  K=256
constexpr size_t P_VWO = 1245184;   // M=256  K=256  val_w out part
constexpr size_t P_VWS = 1310720;   // M=256  K=256  val_w stack part
constexpr size_t P_GW  = 1376256;   // [512] linear
constexpr size_t H_TOTAL = 1376768;
constexpr size_t F_BC0 = H_TOTAL / 2;    // [1024] fp32 (ORIGINAL row order)
constexpr size_t F_BC1 = F_BC0 + 1024;   // [1024]
// exchange slots + counters/flags
constexpr size_t F_XB  = F_BC1 + 1024;   // [4][32][256]  B partial sums (K-split, isid only)
constexpr size_t F_XD  = F_XB + 32768;   // [4][32][1024] D h-slices (only 64 words used/slot)
constexpr size_t F_XE  = F_XD + 131072;  // [4][32][1024] E h-slices
constexpr size_t F_CTR = F_XE + 131072;  // u32: [32][16] B counters, then flags [2][32][4][16]

// ===================== prologue: fragment-pack weights =====================
__global__ __launch_bounds__(256) void prep_kernel(
    const float* wih0, const float* whh0, const float* bih0, const float* bhh0,
    const float* wih1, const float* whh1, const float* bih1, const float* bhh1,
    const float* stw1, const float* stw2, const float* valw, const float* gatew,
    float* ws) {
  _Float16* hw = (_Float16*)ws;
  const int gt = blockIdx.x * blockDim.x + threadIdx.x;
  const int np = gridDim.x * blockDim.x;

  auto pack = [&](size_t off, int M, int K, auto src) {
    const int KT = K / 32;
    for (int i = gt; i < M * K; i += np) {
      const int j = i & 7, l = (i >> 3) & 63, rem = i >> 9;
      const int kt = rem % KT, mt = rem / KT;
      const int row = mt * 16 + (l & 15), col = kt * 32 + (l >> 4) * 8 + j;
      hw[off + i] = (_Float16)src(row, col);
    }
  };
  auto lstm_perm = [](int r) {
    const int q = r >> 8, g = (r >> 6) & 3, jcl = r & 63;
    return g * 256 + q * 64 + jcl;
  };
  pack(P_W0, 1024, 512, [&](int r, int c) {
    const int o = lstm_perm(r);
    return c < 256 ? wih0[(size_t)o * 256 + c] : whh0[(size_t)o * 256 + c - 256];
  });
  pack(P_W1, 1024, 512, [&](int r, int c) {
    const int o = lstm_perm(r);
    return c < 256 ? wih1[(size_t)o * 256 + c] : whh1[(size_t)o * 256 + c - 256];
  });
  pack(P_SW1, 256, 512, [&](int r, int c) { return stw1[(size_t)r * 512 + c]; });
  pack(P_SW2, 256, 256, [&](int r, int c) { return stw2[(size_t)r * 256 + c]; });
  pack(P_VWO, 256, 256, [&](int r, int c) { return valw[(size_t)r * 512 + 256 + c]; });
  pack(P_VWS, 256, 256, [&](int r, int c) { return valw[(size_t)r * 512 + c]; });
  for (int i = gt; i < 512; i += np) hw[P_GW + i] = (_Float16)gatew[i];
  for (int i = gt; i < 1024; i += np) {
    ws[F_BC0 + i] = bih0[i] + bhh0[i];
    ws[F_BC1 + i] = bih1[i] + bhh1[i];
  }
}

// Full-K GEMV pipeline (proven). mtw = output tile base (local write index).
template <int KT, int NMT>
__device__ __forceinline__ void gemv_pipe(const _Float16* __restrict__ wp, int mt0, int mtw,
                                          const _Float16* __restrict__ xA,
                                          const _Float16* __restrict__ xB,
                                          float* __restrict__ pre, int l) {
  const int lr = l & 15, lk = l >> 4;
  constexpr int TOT = KT * NMT;
  constexpr int NC  = TOT / 4;
  const _Float16* base = wp + ((size_t)mt0 * KT * 64 + (size_t)l) * 8;
  h8 A[4], B[4];
  #pragma unroll
  for (int i = 0; i < 4; ++i) gload16(A[i], base + (size_t)i * 512);
  if constexpr (NC > 1) {
    #pragma unroll
    for (int i = 0; i < 4; ++i) gload16(B[i], base + (size_t)(4 + i) * 512);
  }
  f32x4 c = {0.f, 0.f, 0.f, 0.f};
  #pragma unroll
  for (int ch = 0; ch < NC; ++ch) {
    h8* cur = (ch & 1) ? B : A;
    if (ch < NC - 1) VWAIT4(); else VWAIT0();
    SBAR();
    #pragma unroll
    for (int i = 0; i < 4; ++i) {
      const int f = ch * 4 + i;
      const int kt = f % KT;
      const _Float16* xb = (KT > 8) ? ((kt < 8) ? xA + kt * 32 : xB + (kt - 8) * 32)
                                    : (xA + kt * 32);
      const h8 x = *(const h8*)(xb + lk * 8);
      c = __builtin_amdgcn_mfma_f32_16x16x32_f16(cur[i], x, c, 0, 0, 0);
      if (kt == KT - 1) {
        if (lr == 0) *((f32x4*)&pre[(mtw + f / KT) * 16 + lk * 4]) = c;
        c = (f32x4){0.f, 0.f, 0.f, 0.f};
      }
    }
    if (ch + 2 < NC) {
      #pragma unroll
      for (int i = 0; i < 4; ++i) gload16(cur[i], base + (size_t)((ch + 2) * 4 + i) * 512);
    }
  }
}

// Partial-K GEMV (B phase only; proven)
template <int KT, int NMT, int KTC>
__device__ __forceinline__ void gemv_part(const _Float16* __restrict__ wp, int mt0, int kt0,
                                          const _Float16* __restrict__ xA,
                                          const _Float16* __restrict__ xB,
                                          float* __restrict__ pre, int l) {
  const int lr = l & 15, lk = l >> 4;
  constexpr int TOT = NMT * KTC;
  constexpr int NC  = TOT / 4;
  h8 A[4], B[4];
  auto addr = [&](int f) {
    const int mt = mt0 + f / KTC, kt = kt0 + f % KTC;
    return wp + ((size_t)(mt * KT + kt) * 64 + (size_t)l) * 8;
  };
  #pragma unroll
  for (int i = 0; i < 4; ++i) gload16(A[i], addr(i));
  if constexpr (NC > 1) {
    #pragma unroll
    for (int i = 0; i < 4; ++i) gload16(B[i], addr(4 + i));
  }
  f32x4 c = {0.f, 0.f, 0.f, 0.f};
  #pragma unroll
  for (int ch = 0; ch < NC; ++ch) {
    h8* cur = (ch & 1) ? B : A;
    if (ch < NC - 1) VWAIT4(); else VWAIT0();
    SBAR();
    #pragma unroll
    for (int i = 0; i < 4; ++i) {
      const int f = ch * 4 + i, ktl = f % KTC, kt = kt0 + ktl;
      const _Float16* xb = (KT > 8) ? ((kt < 8) ? xA + kt * 32 : xB + (kt - 8) * 32)
                                    : (xA + kt * 32);
      const h8 x = *(const h8*)(xb + lk * 8);
      c = __builtin_amdgcn_mfma_f32_16x16x32_f16(cur[i], x, c, 0, 0, 0);
      if (ktl == KTC - 1) {
        if (lr == 0) *((f32x4*)&pre[(mt0 + f / KTC) * 16 + lk * 4]) = c;
        c = (f32x4){0.f, 0.f, 0.f, 0.f};
      }
    }
    if (ch + 2 < NC) {
      #pragma unroll
      for (int i = 0; i < 4; ++i) gload16(cur[i], addr((ch + 2) * 4 + i));
    }
  }
}

// Quad partial-sum exchange for B (proven; counter-based, isid only)
__device__ __forceinline__ void xchg(float* base, unsigned* ctr, unsigned target,
                                     int q, int b, int n, float* s_pre, int tid) {
  unsigned* mine = (unsigned*)(base + ((size_t)q * NB + b) * n);
  for (int i = tid; i < n; i += 1024)
    __hip_atomic_store(mine + i, __float_as_uint(s_pre[i]), __ATOMIC_RELAXED, __HIP_MEMORY_SCOPE_AGENT);
  __syncthreads();
  if (tid == 0) {
    asm volatile("s_waitcnt vmcnt(0)" ::: "memory");
    __hip_atomic_fetch_add(ctr, 1u, __ATOMIC_RELAXED, __HIP_MEMORY_SCOPE_AGENT);
    while (__hip_atomic_load(ctr, __ATOMIC_RELAXED, __HIP_MEMORY_SCOPE_AGENT) < target)
      __builtin_amdgcn_s_sleep(1);
  }
  __syncthreads();
  for (int i = tid; i < n; i += 1024) {
    float s = 0.f;
    #pragma unroll
    for (int p = 0; p < 4; ++p) {
      unsigned* sp = (unsigned*)(base + ((size_t)p * NB + b) * n);
      s += __uint_as_float(__hip_atomic_load(sp + i, __ATOMIC_RELAXED, __HIP_MEMORY_SCOPE_AGENT));
    }
    s_pre[i] = s;
  }
  __syncthreads();
}

// ============== recurrent scan: QUAD of WGs per batch row, M-split D/E ==============
__global__ __launch_bounds__(1024, 4) void rnn12_kernel(
    const int* __restrict__ tokens, const int* __restrict__ scope_idx,
    const int* __restrict__ is_id, const int* __restrict__ umask,
    const int* __restrict__ lengths, const float* __restrict__ emb,
    const float* __restrict__ stb1, const float* __restrict__ stb2,
    const float* __restrict__ gateb, const float* __restrict__ valb,
    const float* __restrict__ h0, const float* __restrict__ c0,
    float* __restrict__ ws, float* __restrict__ out) {
  const int bid = blockIdx.x, tid = threadIdx.x;
  const int b = bid >> 2, q = bid & 3;   // XCD-aligned quad mapping (r12)
  const int len = lengths[b];
  const _Float16* hw = (const _Float16*)ws;
  const int w = tid >> 6, l = tid & 63;
  float* xb_slot = ws + F_XB;
  unsigned* xd = (unsigned*)(ws + F_XD);
  unsigned* xe = (unsigned*)(ws + F_XE);
  unsigned* ctrb  = (unsigned*)(ws + F_CTR) + b * 16;
  unsigned* flags = (unsigned*)(ws + F_CTR) + 512;   // [2][32][4][16]
  unsigned* flagD = flags + ((0 * NB + b) * 4 + q) * 16;
  unsigned* flagE = flags + ((1 * NB + b) * 4 + q) * 16;

  __shared__ __align__(16) _Float16 s_stkh[64][SPAD];
  __shared__ __align__(16) float    s_stk32[NS][NH];
  __shared__ __align__(16) float    s_pre[1024];
  __shared__ __align__(16) float    s_hf[256];
  __shared__ __align__(16) float    s_c[2][NH];
  __shared__ __align__(16) _Float16 s_h0h[2][NH], s_h1h[2][NH];
  __shared__ __align__(16) _Float16 s_embh[NH], s_z[NH], s_xin[NH];
  __shared__ __align__(16) float    s_vb[NH], s_b1[NH], s_b2[NH];
  __shared__ __align__(16) float    s_bc0[1024], s_bc1[1024];
  __shared__ __align__(16) _Float16 s_gw[512];
  __shared__ float s_gate[NS];
  __shared__ int   s_um[NS];
  __shared__ float s_gb;

  // ---- one-time init (replicated)
  for (int i = tid; i < 64 * SPAD; i += 1024) ((_Float16*)s_stkh)[i] = (_Float16)0.f;
  for (int i = tid; i < NS * NH; i += 1024) ((float*)s_stk32)[i] = 0.f;
  s_bc0[tid] = ws[F_BC0 + tid];
  s_bc1[tid] = ws[F_BC1 + tid];
  if (tid < NH) {
    s_h0h[0][tid] = (_Float16)h0[b * NH + tid];
    s_h1h[0][tid] = (_Float16)h0[NB * NH + b * NH + tid];
    s_c[0][tid] = c0[b * NH + tid];
    s_c[1][tid] = c0[NB * NH + b * NH + tid];
    s_vb[tid] = valb[tid]; s_b1[tid] = stb1[tid]; s_b2[tid] = stb2[tid];
  }
  if (tid < 64) ((h8*)s_gw)[tid] = ((const h8*)(hw + P_GW))[tid];
  if (tid == 0) s_gb = gateb[0];
  __syncthreads();

  unsigned epB = 0;

  for (int t = 0; t < len; ++t) {
    const int p0 = t & 1, p1 = p0 ^ 1;
    const int tok  = tokens[b * NT + t];
    const int sx   = scope_idx[b * NT + t];
    const int isid = is_id[b * NT + t];
    const unsigned stamp = (unsigned)(t + 1);

    // ---- A: emb -> LDS f16, umask (replicated)
    if (tid < 64) {
      const float4 e = ((const float4*)(emb + (size_t)tok * NE))[tid];
      h4 v = { (_Float16)e.x, (_Float16)e.y, (_Float16)e.z, (_Float16)e.w };
      ((h4*)s_embh)[tid] = v;
    } else if (tid >= 64 && tid < 64 + NS) {
      s_um[tid - 64] = umask[((size_t)b * NT + t) * NS + (tid - 64)];
    }
    __syncthreads();

    if (isid) {
      // ---- B (K-split, proven): partial z over kt [q*4, q*4+4)
      gemv_part<16, 1, 4>(hw + P_SW1, w, q * 4, &s_stkh[sx][0], s_embh, s_pre, l);
      __syncthreads();
      ++epB;
      xchg(xb_slot, ctrb, 4u * epB, q, b, 256, s_pre, tid);
      if (tid < 256) s_z[tid] = (_Float16)fmaxf(s_pre[tid] + s_b1[tid], 0.f);
      __syncthreads();
      // ---- C: full (replicated)
      gemv_pipe<8, 1>(hw + P_SW2, w, w, s_z, s_z, s_pre, l);
      __syncthreads();
      if (tid < 256) s_xin[tid] = (_Float16)(s_pre[tid] + s_b2[tid]);
      __syncthreads();
    } else {
      if (tid < 32) ((h8*)s_xin)[tid] = ((const h8*)s_embh)[tid];
      __syncthreads();
    }

    // ---- D (M-split): full-K pre-acts for quad's 256 permuted rows
    gemv_pipe<16, 1>(hw + P_W0, q * 16 + w, w, s_xin, s_h0h[p0], s_pre, l);
    __syncthreads();
    if (tid < 64) {   // owner nonlinearity: cells q*64 + jcl (wave 0)
      const int jcl = tid, cell = q * 64 + jcl;
      const float iv = s_pre[jcl]       + s_bc0[cell];
      const float fv = s_pre[64 + jcl]  + s_bc0[256 + cell];
      const float gv = s_pre[128 + jcl] + s_bc0[512 + cell];
      const float ov = s_pre[192 + jcl] + s_bc0[768 + cell];
      const float c_ = sigm(fv) * s_c[0][cell] + sigm(iv) * tanh_f(gv);
      s_c[0][cell] = c_;
      const float h_ = sigm(ov) * tanh_f(c_);
      __hip_atomic_store(xd + ((size_t)q * NB + b) * 1024 + jcl, __float_as_uint(h_),
                         __ATOMIC_RELAXED, __HIP_MEMORY_SCOPE_AGENT);
    }
    if (tid < 64) { VWAIT0(); }                         // wave0 drains its slice stores
    if (tid == 0)
      __hip_atomic_store(flagD, stamp, __ATOMIC_RELAXED, __HIP_MEMORY_SCOPE_AGENT);
    if (tid < 4) {
      unsigned* f = flags + ((0 * NB + b) * 4 + tid) * 16;
      while (__hip_atomic_load(f, __ATOMIC_RELAXED, __HIP_MEMORY_SCOPE_AGENT) < stamp)
        __builtin_amdgcn_s_sleep(1);
    }
    __syncthreads();
    if (tid < 256) {   // gather h0 (f32 -> f16, identical conversion in all replicas)
      const unsigned v = __hip_atomic_load(xd + ((size_t)(tid >> 6) * NB + b) * 1024 + (tid & 63),
                                           __ATOMIC_RELAXED, __HIP_MEMORY_SCOPE_AGENT);
      s_h0h[p1][tid] = (_Float16)__uint_as_float(v);
    }
    __syncthreads();

    // ---- E (M-split): same pattern on W1
    gemv_pipe<16, 1>(hw + P_W1, q * 16 + w, w, s_h0h[p1], s_h1h[p0], s_pre, l);
    __syncthreads();
    if (tid < 64) {
      const int jcl = tid, cell = q * 64 + jcl;
      const float iv = s_pre[jcl]       + s_bc1[cell];
      const float fv = s_pre[64 + jcl]  + s_bc1[256 + cell];
      const float gv = s_pre[128 + jcl] + s_bc1[512 + cell];
      const float ov = s_pre[192 + jcl] + s_bc1[768 + cell];
      const float c_ = sigm(fv) * s_c[1][cell] + sigm(iv) * tanh_f(gv);
      s_c[1][cell] = c_;
      const float h_ = sigm(ov) * tanh_f(c_);
      __hip_atomic_store(xe + ((size_t)q * NB + b) * 1024 + jcl, __float_as_uint(h_),
                         __ATOMIC_RELAXED, __HIP_MEMORY_SCOPE_AGENT);
    }
    if (tid < 64) { VWAIT0(); }
    if (tid == 0)
      __hip_atomic_store(flagE, stamp, __ATOMIC_RELAXED, __HIP_MEMORY_SCOPE_AGENT);
    if (tid < 4) {
      unsigned* f = flags + ((1 * NB + b) * 4 + tid) * 16;
      while (__hip_atomic_load(f, __ATOMIC_RELAXED, __HIP_MEMORY_SCOPE_AGENT) < stamp)
        __builtin_amdgcn_s_sleep(1);
    }
    __syncthreads();
    if (tid < 256) {
      const unsigned v = __hip_atomic_load(xe + ((size_t)(tid >> 6) * NB + b) * 1024 + (tid & 63),
                                           __ATOMIC_RELAXED, __HIP_MEMORY_SCOPE_AGENT);
      const float h_ = __uint_as_float(v);
      s_hf[tid] = h_;
      s_h1h[p1][tid] = (_Float16)h_;
    }
    __syncthreads();
    if (q == 0 && tid < 64)   // feats (f32, one writer)
      ((float4*)(out + ((size_t)b * NT + t) * NV))[tid] = ((const float4*)s_hf)[tid];

    // ---- F: vproj (waves 0-7) + slot gates (waves 8-15)  (replicated)
    if (w < 8) {
      gemv_pipe<8, 2>(hw + P_VWO, w * 2, w * 2, s_h1h[p1], s_h1h[p1], s_pre, l);
    } else {
      const int wp = w - 8;
      const h2* gs = (const h2*)s_gw;
      const h2* go = (const h2*)(s_gw + 256);
      const h2* oh = (const h2*)s_h1h[p1];
      float po = dot2f(go[2 * l], oh[2 * l], 0.f);
      po = dot2f(go[2 * l + 1], oh[2 * l + 1], po);
      for (int j = 0; j < 7; ++j) {
        const int s = wp + 8 * j;
        if (s < NS) {
          const h2* sr = (const h2*)s_stkh[s];
          float p = dot2f(gs[2 * l], sr[2 * l], po);
          p = dot2f(gs[2 * l + 1], sr[2 * l + 1], p);
          #pragma unroll
          for (int m = 1; m < 64; m <<= 1) p += __shfl_xor(p, m, 64);
          if (l == 0) s_gate[s] = (s_um[s] > 0) ? -1.f : sigm(p + s_gb);
        }
      }
    }
    __syncthreads();

    // ---- F4: stack GEMM, de-duplicated (wave w -> mt=w; B resident, A per-st from LDS)
    {
      const int lr = l & 15, lk = l >> 4;
      const int r = w * 16 + lr;
      const _Float16* baseB = hw + P_VWS + ((size_t)(w * 8) * 64 + (size_t)l) * 8;
      h8 bf0[4], bf1[4];
      #pragma unroll
      for (int i = 0; i < 4; ++i) gload16(bf0[i], baseB + (size_t)i * 512);
      #pragma unroll
      for (int i = 0; i < 4; ++i) gload16(bf1[i], baseB + (size_t)(4 + i) * 512);
      const float vpr = s_pre[r] + s_vb[r];
      float nsv[4][4];
      #pragma unroll
      for (int st = 0; st < 4; ++st) {
        h8 af[8];
        #pragma unroll
        for (int kt = 0; kt < 8; ++kt)
          af[kt] = *(const h8*)&s_stkh[st * 16 + lr][kt * 32 + lk * 8];
        if (st == 0) { VWAIT4(); SBAR(); }
        f32x4 c = {0.f, 0.f, 0.f, 0.f};
        #pragma unroll
        for (int kt = 0; kt < 4; ++kt)
          c = __builtin_amdgcn_mfma_f32_16x16x32_f16(af[kt], bf0[kt], c, 0, 0, 0);
        if (st == 0) { VWAIT0(); SBAR(); }
        #pragma unroll
        for (int kt = 4; kt < 8; ++kt)
          c = __builtin_amdgcn_mfma_f32_16x16x32_f16(af[kt], bf1[kt - 4], c, 0, 0, 0);
        #pragma unroll
        for (int i = 0; i < 4; ++i) {
          const int s = st * 16 + lk * 4 + i;
          float ns = 0.f;
          if (s < NS) {
            const float gv = s_gate[s];
            if (gv >= 0.f) ns = s_stk32[s][r] * (1.f - gv) + gv * tanh_f(c[i] + vpr);
          }
          nsv[st][i] = ns;
        }
      }
      __syncthreads();   // all reads of stack/gates complete before any write
      #pragma unroll
      for (int st = 0; st < 4; ++st) {
        #pragma unroll
        for (int i = 0; i < 4; ++i) {
          const int s = st * 16 + lk * 4 + i;
          if (s < NS) { s_stk32[s][r] = nsv[st][i]; s_stkh[s][r] = (_Float16)nsv[st][i]; }
        }
      }
    }
    __syncthreads();
  }
}

// ===================== logits epilogue (feats live in out[b][t][0:256]) =====================
constexpr int TBR = 32;
__global__ __launch_bounds__(256) void logits_kernel(
    const float* __restrict__ w1, const float* __restrict__ b1,
    const float* __restrict__ w2, const float* __restrict__ b2,
    const int* __restrict__ lengths, float* __restrict__ out) {
  const int blk = blockIdx.x;
  const int b = blk >> 4;
  const int t0 = (blk & 15) * TBR;
  const int tid = threadIdx.x;
  const int len = lengths[b];
  __shared__ __align__(16) float s_fe[TBR][NH];
  __shared__ __align__(16) float s_hid[TBR][NH];

  for (int r = 0; r < TBR; ++r) {
    const int t = t0 + r;
    s_fe[r][tid] = (t < len) ? out[((size_t)b * NT + t) * NV + tid] : 0.f;
  }
  __syncthreads();
  for (int r = 0; r < TBR; ++r) {
    float acc = b1[tid];
    const float4* fr = (const float4*)s_fe[r];
    const float4* wr = (const float4*)(w1 + (size_t)tid * NH);
    #pragma unroll 8
    for (int k = 0; k < NH / 4; ++k) { float4 wv = wr[k]; float4 fv = fr[k]; FMA4(acc, wv, fv); }
    s_hid[r][tid] = fmaxf(acc, 0.f);
  }
  __syncthreads();
  for (int r = 0; r < TBR; ++r) {
    const int t = t0 + r;
    if (t >= len) {
      float4* orow = (float4*)(out + ((size_t)b * NT + t) * NV);
      const float4 m1 = make_float4(-1.f, -1.f, -1.f, -1.f);
      for (int i = tid; i < NV / 4; i += 256) orow[i] = m1;
    }
  }
  if (t0 >= len) return;
  for (int pass = 0; pass < (NV + 511) / 512; ++pass) {
    const int v0 = pass * 512 + tid * 2;
    if (v0 >= NV) continue;
    float acc0[TBR], acc1[TBR];
    #pragma unroll
    for (int r = 0; r < TBR; ++r) { acc0[r] = 0.f; acc1[r] = 0.f; }
    const float4* wa = (const float4*)(w2 + (size_t)v0 * NH);
    const float4* wb = (const float4*)(w2 + (size_t)(v0 + 1) * NH);
    for (int k = 0; k < NH / 4; ++k) {
      const float4 w0 = wa[k], w1v = wb[k];
      #pragma unroll
      for (int r = 0; r < TBR; ++r) {
        const float4 hx = *(const float4*)&s_hid[r][k * 4];
        acc0[r] += w0.x * hx.x + w0.y * hx.y + w0.z * hx.z + w0.w * hx.w;
        acc1[r] += w1v.x * hx.x + w1v.y * hx.y + w1v.z * hx.z + w1v.w * hx.w;
      }
    }
    const float bb0 = b2[v0], bb1 = b2[v0 + 1];
    for (int r = 0; r < TBR; ++r) {
      const int t = t0 + r;
      if (t < len) {
        float2 st = make_float2(acc0[r] + bb0, acc1[r] + bb1);
        *(float2*)(out + ((size_t)b * NT + t) * NV + v0) = st;
      }
    }
  }
}

extern "C" void kernel_launch(void* const* d_in, const int* in_sizes, int n_in,
                              void* d_out, int out_size, void* d_ws, size_t ws_size,
                              hipStream_t stream) {
  (void)in_sizes; (void)n_in; (void)out_size; (void)ws_size;
  const int* tokens    = (const int*)d_in[0];
  const int* scope_idx = (const int*)d_in[1];
  const int* is_id     = (const int*)d_in[2];
  const int* umask     = (const int*)d_in[3];
  const int* lengths   = (const int*)d_in[4];
  const float* emb   = (const float*)d_in[5];
  const float* wih0  = (const float*)d_in[6];  const float* whh0 = (const float*)d_in[7];
  const float* bih0  = (const float*)d_in[8];  const float* bhh0 = (const float*)d_in[9];
  const float* wih1  = (const float*)d_in[10]; const float* whh1 = (const float*)d_in[11];
  const float* bih1  = (const float*)d_in[12]; const float* bhh1 = (const float*)d_in[13];
  const float* stw1  = (const float*)d_in[14]; const float* stb1 = (const float*)d_in[15];
  const float* stw2  = (const float*)d_in[16]; const float* stb2 = (const float*)d_in[17];
  const float* gatew = (const float*)d_in[18]; const float* gateb = (const float*)d_in[19];
  const float* valw  = (const float*)d_in[20]; const float* valb  = (const float*)d_in[21];
  const float* outw1 = (const float*)d_in[22]; const float* outb1 = (const float*)d_in[23];
  const float* outw2 = (const float*)d_in[24]; const float* outb2 = (const float*)d_in[25];
  const float* h0 = (const float*)d_in[26];
  const float* c0 = (const float*)d_in[27];
  float* ws = (float*)d_ws;
  float* out = (float*)d_out;

  // reset B counters + D/E flags (each launch; graph replay includes this)
  (void)hipMemsetAsync(ws + F_CTR, 0, (512 + 2 * 32 * 4 * 16) * 4, stream);

  prep_kernel<<<dim3(256), dim3(256), 0, stream>>>(
      wih0, whh0, bih0, bhh0, wih1, whh1, bih1, bhh1, stw1, stw2, valw, gatew, ws);

  rnn12_kernel<<<dim3(128), dim3(1024), 0, stream>>>(
      tokens, scope_idx, is_id, umask, lengths, emb,
      stb1, stb2, gateb, valb, h0, c0, ws, out);

  logits_kernel<<<dim3(NB * 16), dim3(256), 0, stream>>>(
      outw1, outb1, outw2, outb2, lengths, out);
}